// Round 1
// 686.087 us; speedup vs baseline: 1.9590x; 1.9590x over previous
//
#include <hip/hip_runtime.h>
#include <stdint.h>

#define NBATCH 512
#define NE 32
#define NA 36
#define BAS 32
#define KD 128
#define ED 128
#define HK 64
#define HO 128
#define NT 3

#define XST 132   // xs stride (f32): 132*4B -> 4-bank row skew
#define ZST 132   // zsb stride (u16): kills the 4-way quad conflict of stride-128
#define AST 136   // zaccb/h2b stride (u16): 272B rows, 16B-aligned b128 reads
#define HBS 72    // per-wave H-transpose stride (u16)

typedef uint16_t u16;
typedef uint32_t u32;
using bfrag = __attribute__((ext_vector_type(8))) short;  // 8 bf16 = 4 VGPRs
using f32x4 = __attribute__((ext_vector_type(4))) float;

#define MFMA(a, b, c) __builtin_amdgcn_mfma_f32_16x16x32_bf16(a, b, c, 0, 0, 0)

__device__ __forceinline__ short ftob(float f) {
    u32 x = __float_as_uint(f);
    u32 r = x + 0x7fffu + ((x >> 16) & 1u); // RNE
    return (short)(r >> 16);
}
__device__ __forceinline__ float bf2f(u16 u) {
    return __uint_as_float(((u32)u) << 16);
}
__device__ __forceinline__ bfrag cvt8(float4 a, float4 c) {
    bfrag r;
    r[0] = ftob(a.x); r[1] = ftob(a.y); r[2] = ftob(a.z); r[3] = ftob(a.w);
    r[4] = ftob(c.x); r[5] = ftob(c.y); r[6] = ftob(c.z); r[7] = ftob(c.w);
    return r;
}
// 8 consecutive f32 (global or LDS) -> bf16 A/B fragment
__device__ __forceinline__ bfrag ldf_frag(const float* p) {
    float4 a = *(const float4*)p;
    float4 c = *(const float4*)(p + 4);
    return cvt8(a, c);
}
// softplus(x) - log(2), numerically stable
__device__ __forceinline__ float ssp_f(float x) {
    float ax = fabsf(x);
    return fmaxf(x, 0.0f) + __logf(1.0f + __expf(-ax)) - 0.6931471805599453f;
}

// One block per batch element; 512 threads = 8 waves.
// Frag conventions (guide §3, m89/m91-verified):
//   A: lane&15 = m, (lane>>4)*8+j = k   |  B: lane&15 = n, (lane>>4)*8+j = k
//   C/D: col = lane&15 (n), row = (lane>>4)*4 + reg (m)
// Weights are [out][in] row-major == B[n][k] directly: no transposes anywhere.
//
// Pair loop: wave w OWNS electrons e = 4w..4w+3 (per-e, 3 padded 16-pair
// tiles). z[e][k] accumulates in registers (zreg[8]); cross-quad butterfly
// (__shfl_xor 16/32) then ONE non-atomic LDS write. No LDS atomics anywhere
// (the old per-tile 32x atomicAdd(float)->CAS-loop storm was the stall).
// db loads are distance-1 double-buffered (prefetch next tile during compute).
__global__ __launch_bounds__(512, 4) void schnet_mfma(
    const float* __restrict__ db_g,   // dists_basis (512,32,36,32)
    const float* __restrict__ ee_g,   // embedding_elec (32,128)
    const float* __restrict__ en_g,   // embedding_nuc (4,128)
    const float* __restrict__ w1_g,   // kernel_w1 (3,64,32)
    const float* __restrict__ b1_g,   // kernel_b1 (3,64)
    const float* __restrict__ w2_g,   // kernel_w2 (3,128,64)
    const float* __restrict__ b2_g,   // kernel_b2 (3,128)
    const float* __restrict__ win_g,  // embed_in_w (3,128,128)
    const float* __restrict__ wo1_g,  // embed_out_w1 (3,128,128)
    const float* __restrict__ bo1_g,  // embed_out_b1 (3,128)
    const float* __restrict__ wo2_g,  // embed_out_w2 (3,128,128)
    const float* __restrict__ bo2_g,  // embed_out_b2 (3,128)
    float* __restrict__ out_g)        // (512,32,128) f32
{
    __shared__ __align__(16) float xs[NE * XST];      // residual, f32 (16.9 KB)
    __shared__ __align__(16) u16 zaccb[NE * AST];     // z, bf16 (8.7 KB)
    __shared__ __align__(16) u16 zsb[NA * ZST];       // zs, bf16 (9.5 KB)
    __shared__ __align__(16) u16 arena[8 * 16 * HBS]; // Hb | h2b (18.4 KB)
    u16* h2b = arena;                                 // 32*AST*2 = 8.7KB <= arena

    const int tid = threadIdx.x;
    const int b = blockIdx.x;
    const int w = tid >> 6;   // wave 0..7
    const int l = tid & 63;
    const int lm = l & 15;    // m/n lane index
    const int lq = l >> 4;    // quad 0..3

    // ---- init: xs <- embedding_elec (f32), zsb nuc rows <- embedding_nuc ----
    {
        int idx = tid * 8;
        float4 v0 = *(const float4*)(ee_g + idx);
        float4 v1 = *(const float4*)(ee_g + idx + 4);
        int row = idx >> 7, col = idx & 127;
        *(float4*)&xs[row * XST + col] = v0;
        *(float4*)&xs[row * XST + col + 4] = v1;
    }
    if (tid < 64) {
        int idx = tid * 8;
        int row = NE + (idx >> 7), col = idx & 127;
        float4 v0 = *(const float4*)(en_g + idx);
        float4 v1 = *(const float4*)(en_g + idx + 4);
        float f[8] = {v0.x, v0.y, v0.z, v0.w, v1.x, v1.y, v1.z, v1.w};
#pragma unroll
        for (int i = 0; i < 8; i++) zsb[row * ZST + col + i] = (u16)ftob(f[i]);
    }
    __syncthreads();

    for (int t = 0; t < NT; t++) {
        // ---- per-t weight fragments (registers; loads issued early, used
        //      in the pair loop ~2k cycles later -> latency fully hidden) ----
        bfrag w1f[4], w2f[8][2];
        float b1v[4], b2v[8];
#pragma unroll
        for (int n = 0; n < 4; n++) {
            w1f[n] = ldf_frag(w1_g + (size_t)(t * HK + n * 16 + lm) * BAS + lq * 8);
            b1v[n] = b1_g[t * HK + n * 16 + lm];
        }
#pragma unroll
        for (int n = 0; n < 8; n++) {
#pragma unroll
            for (int s = 0; s < 2; s++)
                w2f[n][s] = ldf_frag(w2_g + (size_t)(t * KD + n * 16 + lm) * HK + s * 32 + lq * 8);
            b2v[n] = b2_g[t * KD + n * 16 + lm];
        }

        // ---- phase A: zs[e][k] = xs . win^T   (M=32,N=128,K=128) ----
        {
            bfrag wb[4];
#pragma unroll
            for (int ks = 0; ks < 4; ks++)
                wb[ks] = ldf_frag(win_g + (size_t)(t * KD + w * 16 + lm) * ED + ks * 32 + lq * 8);
            f32x4 c[2];
            c[0] = (f32x4){0.f, 0.f, 0.f, 0.f};
            c[1] = (f32x4){0.f, 0.f, 0.f, 0.f};
#pragma unroll
            for (int m = 0; m < 2; m++)
#pragma unroll
                for (int ks = 0; ks < 4; ks++) {
                    bfrag a = ldf_frag(&xs[(m * 16 + lm) * XST + ks * 32 + lq * 8]);
                    c[m] = MFMA(a, wb[ks], c[m]);
                }
#pragma unroll
            for (int m = 0; m < 2; m++)
#pragma unroll
                for (int r = 0; r < 4; r++)
                    zsb[(m * 16 + lq * 4 + r) * ZST + w * 16 + lm] = (u16)ftob(c[m][r]);
        }
        __syncthreads();

        // ---- pair loop: wave w owns e = 4w..4w+3; 3 padded tiles per e ----
        {
            u16* hb = arena + w * (16 * HBS); // wave-private H transpose buffer
            float4 raw[2][2];                 // db prefetch double-buffer
            {   // prologue: issue (le=0, T=0)
                const int e0 = w * 4;
                int jj = lm;                  // T=0: jj=lm <= 15, no clamp
                int j = jj + (jj >= e0);
                const float* p = db_g + ((size_t)(b * NE + e0) * NA + j) * BAS + lq * 8;
                raw[0][0] = *(const float4*)p;
                raw[0][1] = *(const float4*)(p + 4);
            }
#pragma unroll
            for (int le = 0; le < 4; le++) {
                const int e = w * 4 + le;
                float zreg[8] = {0.f, 0.f, 0.f, 0.f, 0.f, 0.f, 0.f, 0.f};
#pragma unroll
                for (int T = 0; T < 3; T++) {
                    const int par = (le * 3 + T) & 1;   // compile-time under unroll
                    bfrag ad = cvt8(raw[par][0], raw[par][1]);
                    // prefetch next tile (last iteration issues a harmless
                    // clamped dummy load; values unused)
                    {
                        const int nT = (T == 2) ? 0 : T + 1;
                        int ne2 = (T == 2) ? e + 1 : e;
                        if (ne2 > NE - 1) ne2 = NE - 1;
                        int jj = nT * 16 + lm;
                        if (jj > NA - 2) jj = NA - 2;   // clamp pad rows -> 34
                        int j = jj + (jj >= ne2);
                        const float* p = db_g + ((size_t)(b * NE + ne2) * NA + j) * BAS + lq * 8;
                        raw[par ^ 1][0] = *(const float4*)p;
                        raw[par ^ 1][1] = *(const float4*)(p + 4);
                    }
                    // GEMM1: H = ssp(db . w1^T + b1)  (16x64, K=32)
                    f32x4 c1[4];
#pragma unroll
                    for (int n = 0; n < 4; n++) {
                        f32x4 z = {0.f, 0.f, 0.f, 0.f};
                        c1[n] = MFMA(ad, w1f[n], z);
                    }
                    // C-layout -> A-layout transpose via wave-private LDS
#pragma unroll
                    for (int n = 0; n < 4; n++)
#pragma unroll
                        for (int r = 0; r < 4; r++)
                            hb[(lq * 4 + r) * HBS + n * 16 + lm] =
                                (u16)ftob(ssp_f(c1[n][r] + b1v[n]));
                    bfrag a20 = *(const bfrag*)&hb[lm * HBS + lq * 8];
                    bfrag a21 = *(const bfrag*)&hb[lm * HBS + 32 + lq * 8];
                    // GEMM2 (Ws = H . w2^T, 16x128, K=64) + register consume
#pragma unroll
                    for (int n = 0; n < 8; n++) {
                        f32x4 c2 = {0.f, 0.f, 0.f, 0.f};
                        c2 = MFMA(a20, w2f[n][0], c2);
                        c2 = MFMA(a21, w2f[n][1], c2);
                        const int k = n * 16 + lm;
#pragma unroll
                        for (int r = 0; r < 4; r++) {
                            const int lp = T * 16 + lq * 4 + r;
                            if (T < 2) {          // rows 0..31: always valid
                                int jr = lp + (lp >= e);
                                zreg[n] += (c2[r] + b2v[n]) * bf2f(zsb[jr * ZST + k]);
                            } else {              // rows 32..47: valid iff lp<35
                                int jjc = (lp < 35) ? lp : 34;
                                int jr = jjc + (jjc >= e);
                                float val = (c2[r] + b2v[n]) * bf2f(zsb[jr * ZST + k]);
                                zreg[n] += (lp < 35) ? val : 0.f;
                            }
                        }
                    }
                }
                // butterfly-reduce over lq (lanes ^16, ^32 share lm) + write
#pragma unroll
                for (int n = 0; n < 8; n++) {
                    float v = zreg[n];
                    v += __shfl_xor(v, 16, 64);
                    v += __shfl_xor(v, 32, 64);
                    zreg[n] = v;
                }
                if (lq == 0) {
#pragma unroll
                    for (int n = 0; n < 8; n++)
                        zaccb[e * AST + n * 16 + lm] = (u16)ftob(zreg[n]);
                }
            }
        }
        __syncthreads();

        // ---- D1: h2 = ssp(z . wo1^T + bo1)  (M=32,N=128,K=128), A from bf16 ----
        {
            bfrag wb[4];
#pragma unroll
            for (int ks = 0; ks < 4; ks++)
                wb[ks] = ldf_frag(wo1_g + (size_t)(t * HO + w * 16 + lm) * KD + ks * 32 + lq * 8);
            float bo1v = bo1_g[t * HO + w * 16 + lm];
            f32x4 c[2];
            c[0] = (f32x4){0.f, 0.f, 0.f, 0.f};
            c[1] = (f32x4){0.f, 0.f, 0.f, 0.f};
#pragma unroll
            for (int m = 0; m < 2; m++)
#pragma unroll
                for (int ks = 0; ks < 4; ks++) {
                    bfrag a = *(const bfrag*)&zaccb[(m * 16 + lm) * AST + ks * 32 + lq * 8];
                    c[m] = MFMA(a, wb[ks], c[m]);
                }
#pragma unroll
            for (int m = 0; m < 2; m++)
#pragma unroll
                for (int r = 0; r < 4; r++)
                    h2b[(m * 16 + lq * 4 + r) * AST + w * 16 + lm] =
                        (u16)ftob(ssp_f(c[m][r] + bo1v));
        }
        __syncthreads();

        // ---- D2: xs += h2 . wo2^T + bo2  (M=32,N=128,K=128), A from bf16 ----
        {
            bfrag wb[4];
#pragma unroll
            for (int ks = 0; ks < 4; ks++)
                wb[ks] = ldf_frag(wo2_g + (size_t)(t * ED + w * 16 + lm) * HO + ks * 32 + lq * 8);
            float bo2v = bo2_g[t * ED + w * 16 + lm];
            f32x4 c[2];
            c[0] = (f32x4){0.f, 0.f, 0.f, 0.f};
            c[1] = (f32x4){0.f, 0.f, 0.f, 0.f};
#pragma unroll
            for (int m = 0; m < 2; m++)
#pragma unroll
                for (int ks = 0; ks < 4; ks++) {
                    bfrag a = *(const bfrag*)&h2b[(m * 16 + lm) * AST + ks * 32 + lq * 8];
                    c[m] = MFMA(a, wb[ks], c[m]);
                }
#pragma unroll
            for (int m = 0; m < 2; m++)
#pragma unroll
                for (int r = 0; r < 4; r++) {
                    int row = m * 16 + lq * 4 + r, col = w * 16 + lm;
                    xs[row * XST + col] += c[m][r] + bo2v;
                }
        }
        __syncthreads();
    }

    // ---- write out (f32, coalesced float4) ----
#pragma unroll
    for (int ii = 0; ii < 2; ii++) {
        int idx = (ii * 512 + tid) * 4;
        int row = idx >> 7, col = idx & 127;
        *(float4*)&out_g[(size_t)b * (NE * ED) + idx] = *(const float4*)&xs[row * XST + col];
    }
}

extern "C" void kernel_launch(void* const* d_in, const int* in_sizes, int n_in,
                              void* d_out, int out_size, void* d_ws, size_t ws_size,
                              hipStream_t stream) {
    schnet_mfma<<<NBATCH, 512, 0, stream>>>(
        (const float*)d_in[0], (const float*)d_in[1], (const float*)d_in[2],
        (const float*)d_in[3], (const float*)d_in[4], (const float*)d_in[5],
        (const float*)d_in[6], (const float*)d_in[7], (const float*)d_in[8],
        (const float*)d_in[9], (const float*)d_in[10], (const float*)d_in[11],
        (float*)d_out);
}

// Round 2
// 327.209 us; speedup vs baseline: 4.1075x; 2.0968x over previous
//
#include <hip/hip_runtime.h>
#include <stdint.h>

#define NBATCH 512
#define NE 32
#define NA 36
#define BAS 32
#define KD 128
#define ED 128
#define HK 64
#define HO 128
#define NT 3

#define XST 132   // xs stride (f32): 132*4B -> 4-bank row skew
#define ZST 132   // zsb stride (u16): kills the 4-way quad conflict of stride-128
#define AST 136   // zaccb/h2b stride (u16): 272B rows, 16B-aligned b128 reads
#define HBS 72    // per-wave H-transpose stride (u16)
#define W2S 72    // w2 LDS stride (u16): 144B rows, 16B-aligned, +4 banks/row

typedef uint16_t u16;
typedef uint32_t u32;
using bfrag = __attribute__((ext_vector_type(8))) short;  // 8 bf16 = 4 VGPRs
using f32x4 = __attribute__((ext_vector_type(4))) float;

#define MFMA(a, b, c) __builtin_amdgcn_mfma_f32_16x16x32_bf16(a, b, c, 0, 0, 0)

__device__ __forceinline__ short ftob(float f) {
    u32 x = __float_as_uint(f);
    u32 r = x + 0x7fffu + ((x >> 16) & 1u); // RNE
    return (short)(r >> 16);
}
__device__ __forceinline__ float bf2f(u16 u) {
    return __uint_as_float(((u32)u) << 16);
}
__device__ __forceinline__ bfrag cvt8(float4 a, float4 c) {
    bfrag r;
    r[0] = ftob(a.x); r[1] = ftob(a.y); r[2] = ftob(a.z); r[3] = ftob(a.w);
    r[4] = ftob(c.x); r[5] = ftob(c.y); r[6] = ftob(c.z); r[7] = ftob(c.w);
    return r;
}
// 8 consecutive f32 (global or LDS) -> bf16 A/B fragment
__device__ __forceinline__ bfrag ldf_frag(const float* p) {
    float4 a = *(const float4*)p;
    float4 c = *(const float4*)(p + 4);
    return cvt8(a, c);
}
// softplus(x) - log(2), numerically stable
__device__ __forceinline__ float ssp_f(float x) {
    float ax = fabsf(x);
    return fmaxf(x, 0.0f) + __logf(1.0f + __expf(-ax)) - 0.6931471805599453f;
}

// One block per batch element; 512 threads = 8 waves.
// Frag conventions (guide §3, m89/m91-verified):
//   A: lane&15 = m, (lane>>4)*8+j = k   |  B: lane&15 = n, (lane>>4)*8+j = k
//   C/D: col = lane&15 (n), row = (lane>>4)*4 + reg (m)
// Weights are [out][in] row-major == B[n][k] directly: no transposes anywhere.
//
// Pair loop: wave w OWNS electrons e = 4w..4w+3 (per-e, 3 padded 16-pair
// tiles). z[e][k] accumulates in registers (zreg[8]); cross-quad butterfly
// (__shfl_xor 16/32) then ONE non-atomic LDS write. No LDS atomics.
// db loads are distance-1 double-buffered (prefetch next tile during compute).
//
// R2 fix: w2 fragments moved regs -> LDS (w2b). Last round the persistent set
// (w1f+w2f+zreg+raw ~150 VGPR) blew the launch_bounds(512,4) cap of 128 and
// spilled ~1.6 GB/dispatch to scratch (WRITE_SIZE 820 MB vs 8 MB of output).
// w2 is wave-invariant, so LDS staging dedups 64 VGPRs at the cost of 16
// ds_read_b128/tile (2-way-max bank aliasing at stride 72 u16 = free).
__global__ __launch_bounds__(512, 4) void schnet_mfma(
    const float* __restrict__ db_g,   // dists_basis (512,32,36,32)
    const float* __restrict__ ee_g,   // embedding_elec (32,128)
    const float* __restrict__ en_g,   // embedding_nuc (4,128)
    const float* __restrict__ w1_g,   // kernel_w1 (3,64,32)
    const float* __restrict__ b1_g,   // kernel_b1 (3,64)
    const float* __restrict__ w2_g,   // kernel_w2 (3,128,64)
    const float* __restrict__ b2_g,   // kernel_b2 (3,128)
    const float* __restrict__ win_g,  // embed_in_w (3,128,128)
    const float* __restrict__ wo1_g,  // embed_out_w1 (3,128,128)
    const float* __restrict__ bo1_g,  // embed_out_b1 (3,128)
    const float* __restrict__ wo2_g,  // embed_out_w2 (3,128,128)
    const float* __restrict__ bo2_g,  // embed_out_b2 (3,128)
    float* __restrict__ out_g)        // (512,32,128) f32
{
    __shared__ __align__(16) float xs[NE * XST];      // residual, f32 (16.9 KB)
    __shared__ __align__(16) u16 zaccb[NE * AST];     // z, bf16 (8.7 KB)
    __shared__ __align__(16) u16 zsb[NA * ZST];       // zs, bf16 (9.5 KB)
    __shared__ __align__(16) u16 arena[8 * 16 * HBS]; // Hb | h2b (18.4 KB)
    __shared__ __align__(16) u16 w2b[KD * W2S];       // w2, bf16 (18.4 KB)
    u16* h2b = arena;                                 // 32*AST*2 = 8.7KB <= arena

    const int tid = threadIdx.x;
    const int b = blockIdx.x;
    const int w = tid >> 6;   // wave 0..7
    const int l = tid & 63;
    const int lm = l & 15;    // m/n lane index
    const int lq = l >> 4;    // quad 0..3

    // ---- init: xs <- embedding_elec (f32), zsb nuc rows <- embedding_nuc ----
    {
        int idx = tid * 8;
        float4 v0 = *(const float4*)(ee_g + idx);
        float4 v1 = *(const float4*)(ee_g + idx + 4);
        int row = idx >> 7, col = idx & 127;
        *(float4*)&xs[row * XST + col] = v0;
        *(float4*)&xs[row * XST + col + 4] = v1;
    }
    if (tid < 64) {
        int idx = tid * 8;
        int row = NE + (idx >> 7), col = idx & 127;
        float4 v0 = *(const float4*)(en_g + idx);
        float4 v1 = *(const float4*)(en_g + idx + 4);
        float f[8] = {v0.x, v0.y, v0.z, v0.w, v1.x, v1.y, v1.z, v1.w};
#pragma unroll
        for (int i = 0; i < 8; i++) zsb[row * ZST + col + i] = (u16)ftob(f[i]);
    }
    __syncthreads();

    for (int t = 0; t < NT; t++) {
        // ---- stage w2 (t,128,64) -> LDS bf16; consumed after next barrier ----
        {
            int idx = tid * 16;
            int row = idx >> 6, col = idx & 63;
            const float* p = w2_g + (size_t)(t * KD + row) * HK + col;
            bfrag v0 = ldf_frag(p);
            bfrag v1 = ldf_frag(p + 8);
            *(bfrag*)&w2b[row * W2S + col] = v0;
            *(bfrag*)&w2b[row * W2S + col + 8] = v1;
        }

        // ---- per-t small weight fragments (registers) ----
        bfrag w1f[4];
        float b1v[4], b2v[8];
#pragma unroll
        for (int n = 0; n < 4; n++) {
            w1f[n] = ldf_frag(w1_g + (size_t)(t * HK + n * 16 + lm) * BAS + lq * 8);
            b1v[n] = b1_g[t * HK + n * 16 + lm];
        }
#pragma unroll
        for (int n = 0; n < 8; n++) b2v[n] = b2_g[t * KD + n * 16 + lm];

        // ---- phase A: zs[e][k] = xs . win^T   (M=32,N=128,K=128) ----
        {
            bfrag wb[4];
#pragma unroll
            for (int ks = 0; ks < 4; ks++)
                wb[ks] = ldf_frag(win_g + (size_t)(t * KD + w * 16 + lm) * ED + ks * 32 + lq * 8);
            f32x4 c[2];
            c[0] = (f32x4){0.f, 0.f, 0.f, 0.f};
            c[1] = (f32x4){0.f, 0.f, 0.f, 0.f};
#pragma unroll
            for (int m = 0; m < 2; m++)
#pragma unroll
                for (int ks = 0; ks < 4; ks++) {
                    bfrag a = ldf_frag(&xs[(m * 16 + lm) * XST + ks * 32 + lq * 8]);
                    c[m] = MFMA(a, wb[ks], c[m]);
                }
#pragma unroll
            for (int m = 0; m < 2; m++)
#pragma unroll
                for (int r = 0; r < 4; r++)
                    zsb[(m * 16 + lq * 4 + r) * ZST + w * 16 + lm] = (u16)ftob(c[m][r]);
        }
        __syncthreads();

        // ---- pair loop: wave w owns e = 4w..4w+3; 3 padded tiles per e ----
        {
            u16* hb = arena + w * (16 * HBS); // wave-private H transpose buffer
            float4 raw[2][2];                 // db prefetch double-buffer
            {   // prologue: issue (le=0, T=0)
                const int e0 = w * 4;
                int jj = lm;                  // T=0: jj=lm <= 15, no clamp
                int j = jj + (jj >= e0);
                const float* p = db_g + ((size_t)(b * NE + e0) * NA + j) * BAS + lq * 8;
                raw[0][0] = *(const float4*)p;
                raw[0][1] = *(const float4*)(p + 4);
            }
#pragma unroll
            for (int le = 0; le < 4; le++) {
                const int e = w * 4 + le;
                float zreg[8] = {0.f, 0.f, 0.f, 0.f, 0.f, 0.f, 0.f, 0.f};
#pragma unroll
                for (int T = 0; T < 3; T++) {
                    const int par = (le * 3 + T) & 1;   // compile-time under unroll
                    bfrag ad = cvt8(raw[par][0], raw[par][1]);
                    // prefetch next tile (last iteration issues a harmless
                    // clamped dummy load; values unused)
                    {
                        const int nT = (T == 2) ? 0 : T + 1;
                        int ne2 = (T == 2) ? e + 1 : e;
                        if (ne2 > NE - 1) ne2 = NE - 1;
                        int jj = nT * 16 + lm;
                        if (jj > NA - 2) jj = NA - 2;   // clamp pad rows -> 34
                        int j = jj + (jj >= ne2);
                        const float* p = db_g + ((size_t)(b * NE + ne2) * NA + j) * BAS + lq * 8;
                        raw[par ^ 1][0] = *(const float4*)p;
                        raw[par ^ 1][1] = *(const float4*)(p + 4);
                    }
                    // GEMM1: H = ssp(db . w1^T + b1)  (16x64, K=32)
                    f32x4 c1[4];
#pragma unroll
                    for (int n = 0; n < 4; n++) {
                        f32x4 z = {0.f, 0.f, 0.f, 0.f};
                        c1[n] = MFMA(ad, w1f[n], z);
                    }
                    // C-layout -> A-layout transpose via wave-private LDS
#pragma unroll
                    for (int n = 0; n < 4; n++)
#pragma unroll
                        for (int r = 0; r < 4; r++)
                            hb[(lq * 4 + r) * HBS + n * 16 + lm] =
                                (u16)ftob(ssp_f(c1[n][r] + b1v[n]));
                    bfrag a20 = *(const bfrag*)&hb[lm * HBS + lq * 8];
                    bfrag a21 = *(const bfrag*)&hb[lm * HBS + 32 + lq * 8];
                    // GEMM2 (Ws = H . w2^T, 16x128, K=64) + register consume
#pragma unroll
                    for (int n = 0; n < 8; n++) {
                        bfrag wf0 = *(const bfrag*)&w2b[(n * 16 + lm) * W2S + lq * 8];
                        bfrag wf1 = *(const bfrag*)&w2b[(n * 16 + lm) * W2S + 32 + lq * 8];
                        f32x4 c2 = {0.f, 0.f, 0.f, 0.f};
                        c2 = MFMA(a20, wf0, c2);
                        c2 = MFMA(a21, wf1, c2);
                        const int k = n * 16 + lm;
#pragma unroll
                        for (int r = 0; r < 4; r++) {
                            const int lp = T * 16 + lq * 4 + r;
                            if (T < 2) {          // rows 0..31: always valid
                                int jr = lp + (lp >= e);
                                zreg[n] += (c2[r] + b2v[n]) * bf2f(zsb[jr * ZST + k]);
                            } else {              // rows 32..47: valid iff lp<35
                                int jjc = (lp < 35) ? lp : 34;
                                int jr = jjc + (jjc >= e);
                                float val = (c2[r] + b2v[n]) * bf2f(zsb[jr * ZST + k]);
                                zreg[n] += (lp < 35) ? val : 0.f;
                            }
                        }
                    }
                }
                // butterfly-reduce over lq (lanes ^16, ^32 share lm) + write
#pragma unroll
                for (int n = 0; n < 8; n++) {
                    float v = zreg[n];
                    v += __shfl_xor(v, 16, 64);
                    v += __shfl_xor(v, 32, 64);
                    zreg[n] = v;
                }
                if (lq == 0) {
#pragma unroll
                    for (int n = 0; n < 8; n++)
                        zaccb[e * AST + n * 16 + lm] = (u16)ftob(zreg[n]);
                }
            }
        }
        __syncthreads();

        // ---- D1: h2 = ssp(z . wo1^T + bo1)  (M=32,N=128,K=128), A from bf16 ----
        {
            bfrag wb[4];
#pragma unroll
            for (int ks = 0; ks < 4; ks++)
                wb[ks] = ldf_frag(wo1_g + (size_t)(t * HO + w * 16 + lm) * KD + ks * 32 + lq * 8);
            float bo1v = bo1_g[t * HO + w * 16 + lm];
            f32x4 c[2];
            c[0] = (f32x4){0.f, 0.f, 0.f, 0.f};
            c[1] = (f32x4){0.f, 0.f, 0.f, 0.f};
#pragma unroll
            for (int m = 0; m < 2; m++)
#pragma unroll
                for (int ks = 0; ks < 4; ks++) {
                    bfrag a = *(const bfrag*)&zaccb[(m * 16 + lm) * AST + ks * 32 + lq * 8];
                    c[m] = MFMA(a, wb[ks], c[m]);
                }
#pragma unroll
            for (int m = 0; m < 2; m++)
#pragma unroll
                for (int r = 0; r < 4; r++)
                    h2b[(m * 16 + lq * 4 + r) * AST + w * 16 + lm] =
                        (u16)ftob(ssp_f(c[m][r] + bo1v));
        }
        __syncthreads();

        // ---- D2: xs += h2 . wo2^T + bo2  (M=32,N=128,K=128), A from bf16 ----
        {
            bfrag wb[4];
#pragma unroll
            for (int ks = 0; ks < 4; ks++)
                wb[ks] = ldf_frag(wo2_g + (size_t)(t * ED + w * 16 + lm) * HO + ks * 32 + lq * 8);
            float bo2v = bo2_g[t * ED + w * 16 + lm];
            f32x4 c[2];
            c[0] = (f32x4){0.f, 0.f, 0.f, 0.f};
            c[1] = (f32x4){0.f, 0.f, 0.f, 0.f};
#pragma unroll
            for (int m = 0; m < 2; m++)
#pragma unroll
                for (int ks = 0; ks < 4; ks++) {
                    bfrag a = *(const bfrag*)&h2b[(m * 16 + lm) * AST + ks * 32 + lq * 8];
                    c[m] = MFMA(a, wb[ks], c[m]);
                }
#pragma unroll
            for (int m = 0; m < 2; m++)
#pragma unroll
                for (int r = 0; r < 4; r++) {
                    int row = m * 16 + lq * 4 + r, col = w * 16 + lm;
                    xs[row * XST + col] += c[m][r] + bo2v;
                }
        }
        __syncthreads();
    }

    // ---- write out (f32, coalesced float4) ----
#pragma unroll
    for (int ii = 0; ii < 2; ii++) {
        int idx = (ii * 512 + tid) * 4;
        int row = idx >> 7, col = idx & 127;
        *(float4*)&out_g[(size_t)b * (NE * ED) + idx] = *(const float4*)&xs[row * XST + col];
    }
}

extern "C" void kernel_launch(void* const* d_in, const int* in_sizes, int n_in,
                              void* d_out, int out_size, void* d_ws, size_t ws_size,
                              hipStream_t stream) {
    schnet_mfma<<<NBATCH, 512, 0, stream>>>(
        (const float*)d_in[0], (const float*)d_in[1], (const float*)d_in[2],
        (const float*)d_in[3], (const float*)d_in[4], (const float*)d_in[5],
        (const float*)d_in[6], (const float*)d_in[7], (const float*)d_in[8],
        (const float*)d_in[9], (const float*)d_in[10], (const float*)d_in[11],
        (float*)d_out);
}

// Round 3
// 297.513 us; speedup vs baseline: 4.5175x; 1.0998x over previous
//
#include <hip/hip_runtime.h>
#include <stdint.h>

#define NBATCH 512
#define NE 32
#define NA 36
#define BAS 32
#define KD 128
#define ED 128
#define HK 64
#define HO 128
#define NT 3

#define XST 132   // xs stride (f32): 132*4B -> 4-bank row skew
#define ZST 132   // zsb stride (u16): kills the 4-way quad conflict of stride-128
#define AST 136   // zaccb/h2b stride (u16): 272B rows, 16B-aligned b128 reads
#define HBS 72    // per-wave H-transpose stride (u16)

typedef uint16_t u16;
typedef uint32_t u32;
using bfrag = __attribute__((ext_vector_type(8))) short;  // 8 bf16 = 4 VGPRs
using f32x4 = __attribute__((ext_vector_type(4))) float;

#define MFMA(a, b, c) __builtin_amdgcn_mfma_f32_16x16x32_bf16(a, b, c, 0, 0, 0)

__device__ __forceinline__ short ftob(float f) {
    u32 x = __float_as_uint(f);
    u32 r = x + 0x7fffu + ((x >> 16) & 1u); // RNE
    return (short)(r >> 16);
}
__device__ __forceinline__ float bf2f(u16 u) {
    return __uint_as_float(((u32)u) << 16);
}
__device__ __forceinline__ bfrag cvt8(float4 a, float4 c) {
    bfrag r;
    r[0] = ftob(a.x); r[1] = ftob(a.y); r[2] = ftob(a.z); r[3] = ftob(a.w);
    r[4] = ftob(c.x); r[5] = ftob(c.y); r[6] = ftob(c.z); r[7] = ftob(c.w);
    return r;
}
// 8 consecutive f32 (global or LDS) -> bf16 A/B fragment
__device__ __forceinline__ bfrag ldf_frag(const float* p) {
    float4 a = *(const float4*)p;
    float4 c = *(const float4*)(p + 4);
    return cvt8(a, c);
}
// softplus(x) - log(2), numerically stable
__device__ __forceinline__ float ssp_f(float x) {
    float ax = fabsf(x);
    return fmaxf(x, 0.0f) + __logf(1.0f + __expf(-ax)) - 0.6931471805599453f;
}

// One block per batch element; 512 threads = 8 waves.
// Frag conventions (guide §3, m89/m91-verified):
//   A: lane&15 = m, (lane>>4)*8+j = k   |  B: lane&15 = n, (lane>>4)*8+j = k
//   C/D: col = lane&15 (n), row = (lane>>4)*4 + reg (m)
// Weights are [out][in] row-major == B[n][k] directly: no transposes anywhere.
//
// Pair loop: wave w OWNS electrons e = 4w..4w+3. z[e][k] accumulates in
// registers (zreg[8]); cross-quad butterfly then ONE non-atomic LDS write.
//
// R3 fixes (target: residual ~200 MB/dispatch scratch spill + w2b conflicts):
//  - le is a RUNTIME loop (unroll 1): R2's 12x full unroll ballooned live
//    ranges; with 8 interleaved GEMM2 n-iters the peak live set was >128
//    VGPRs -> ~113 MB scratch writes (WRITE_SIZE 121.6 MB vs 8.4 MB output).
//  - GEMM2 split into two 4-n halves fenced with sched_barrier(0): indices
//    stay compile-time (no scratch, rule #20) but scheduler can only
//    interleave 4 n's of transients (wf+c2) at a time.
//  - db prefetch shrunk to a single rotating nxt pair (8 regs, distance-1).
//  - w2 stored in FRAGMENT-LINEAR LDS layout w2x[(n*2+s)*64+lane][8]:
//    ds_read_b128 is per-lane linear -> conflict-free (R2's stride-72 rows
//    put 8 lanes on the same 4-bank group; conflicts went 3.6M->13M).
__global__ __launch_bounds__(512, 4) void schnet_mfma(
    const float* __restrict__ db_g,   // dists_basis (512,32,36,32)
    const float* __restrict__ ee_g,   // embedding_elec (32,128)
    const float* __restrict__ en_g,   // embedding_nuc (4,128)
    const float* __restrict__ w1_g,   // kernel_w1 (3,64,32)
    const float* __restrict__ b1_g,   // kernel_b1 (3,64)
    const float* __restrict__ w2_g,   // kernel_w2 (3,128,64)
    const float* __restrict__ b2_g,   // kernel_b2 (3,128)
    const float* __restrict__ win_g,  // embed_in_w (3,128,128)
    const float* __restrict__ wo1_g,  // embed_out_w1 (3,128,128)
    const float* __restrict__ bo1_g,  // embed_out_b1 (3,128)
    const float* __restrict__ wo2_g,  // embed_out_w2 (3,128,128)
    const float* __restrict__ bo2_g,  // embed_out_b2 (3,128)
    float* __restrict__ out_g)        // (512,32,128) f32
{
    __shared__ __align__(16) float xs[NE * XST];      // residual, f32 (16.9 KB)
    __shared__ __align__(16) u16 zaccb[NE * AST];     // z, bf16 (8.7 KB)
    __shared__ __align__(16) u16 zsb[NA * ZST];       // zs, bf16 (9.5 KB)
    __shared__ __align__(16) u16 arena[8 * 16 * HBS]; // Hb | h2b (18.4 KB)
    __shared__ __align__(16) u16 w2x[8 * 2 * 64 * 8]; // w2 frag-linear (16 KB)
    u16* h2b = arena;                                 // 32*AST*2 = 8.7KB <= arena

    const int tid = threadIdx.x;
    const int b = blockIdx.x;
    const int w = tid >> 6;   // wave 0..7
    const int l = tid & 63;
    const int lm = l & 15;    // m/n lane index
    const int lq = l >> 4;    // quad 0..3

    // ---- init: xs <- embedding_elec (f32), zsb nuc rows <- embedding_nuc ----
    {
        int idx = tid * 8;
        float4 v0 = *(const float4*)(ee_g + idx);
        float4 v1 = *(const float4*)(ee_g + idx + 4);
        int row = idx >> 7, col = idx & 127;
        *(float4*)&xs[row * XST + col] = v0;
        *(float4*)&xs[row * XST + col + 4] = v1;
    }
    if (tid < 64) {
        int idx = tid * 8;
        int row = NE + (idx >> 7), col = idx & 127;
        float4 v0 = *(const float4*)(en_g + idx);
        float4 v1 = *(const float4*)(en_g + idx + 4);
        float f[8] = {v0.x, v0.y, v0.z, v0.w, v1.x, v1.y, v1.z, v1.w};
#pragma unroll
        for (int i = 0; i < 8; i++) zsb[row * ZST + col + i] = (u16)ftob(f[i]);
    }
    __syncthreads();

    for (int t = 0; t < NT; t++) {
        // ---- stage w2 -> LDS in fragment-linear layout (consumed after
        //      the next barrier). unit u=(n,s,lane): lane l holds
        //      w2[n*16+(l&15)][s*32+(l>>4)*8 .. +7] as one 16B bfrag. ----
#pragma unroll
        for (int uu = 0; uu < 2; uu++) {
            int u = tid + uu * 512;
            int n = u >> 7, s = (u >> 6) & 1, lane = u & 63;
            int lmm = lane & 15, lqq = lane >> 4;
            const float* p = w2_g + (size_t)(t * KD + n * 16 + lmm) * HK + s * 32 + lqq * 8;
            *(bfrag*)&w2x[u * 8] = ldf_frag(p);
        }

        // ---- per-t small weight fragments (registers) ----
        bfrag w1f[4];
        float b1v[4], b2v[8];
#pragma unroll
        for (int n = 0; n < 4; n++) {
            w1f[n] = ldf_frag(w1_g + (size_t)(t * HK + n * 16 + lm) * BAS + lq * 8);
            b1v[n] = b1_g[t * HK + n * 16 + lm];
        }
#pragma unroll
        for (int n = 0; n < 8; n++) b2v[n] = b2_g[t * KD + n * 16 + lm];

        // ---- phase A: zs[e][k] = xs . win^T   (M=32,N=128,K=128) ----
        {
            bfrag wb[4];
#pragma unroll
            for (int ks = 0; ks < 4; ks++)
                wb[ks] = ldf_frag(win_g + (size_t)(t * KD + w * 16 + lm) * ED + ks * 32 + lq * 8);
            f32x4 c[2];
            c[0] = (f32x4){0.f, 0.f, 0.f, 0.f};
            c[1] = (f32x4){0.f, 0.f, 0.f, 0.f};
#pragma unroll
            for (int m = 0; m < 2; m++)
#pragma unroll
                for (int ks = 0; ks < 4; ks++) {
                    bfrag a = ldf_frag(&xs[(m * 16 + lm) * XST + ks * 32 + lq * 8]);
                    c[m] = MFMA(a, wb[ks], c[m]);
                }
#pragma unroll
            for (int m = 0; m < 2; m++)
#pragma unroll
                for (int r = 0; r < 4; r++)
                    zsb[(m * 16 + lq * 4 + r) * ZST + w * 16 + lm] = (u16)ftob(c[m][r]);
        }
        __syncthreads();

        // ---- pair loop: wave w owns e = 4w..4w+3; 3 padded tiles per e ----
        {
            u16* hb = arena + w * (16 * HBS); // wave-private H transpose buffer
            float4 nxt0, nxt1;                // rotating distance-1 prefetch
            {   // prologue: issue (le=0, T=0)
                const int e0 = w * 4;
                int jj = lm;                  // T=0: jj=lm <= 15, no clamp
                int j = jj + (jj >= e0);
                const float* p = db_g + ((size_t)(b * NE + e0) * NA + j) * BAS + lq * 8;
                nxt0 = *(const float4*)p;
                nxt1 = *(const float4*)(p + 4);
            }
#pragma unroll 1
            for (int le = 0; le < 4; le++) {
                const int e = w * 4 + le;
                float zreg[8] = {0.f, 0.f, 0.f, 0.f, 0.f, 0.f, 0.f, 0.f};
#pragma unroll
                for (int T = 0; T < 3; T++) {
                    float4 cur0 = nxt0, cur1 = nxt1;
                    // issue next-tile prefetch (last tile issues a harmless
                    // clamped dummy load; values unused)
                    {
                        const int nT = (T == 2) ? 0 : T + 1;
                        int ne2 = (T == 2) ? e + 1 : e;
                        if (ne2 > NE - 1) ne2 = NE - 1;
                        int jj = nT * 16 + lm;
                        if (jj > NA - 2) jj = NA - 2;   // clamp pad rows -> 34
                        int j = jj + (jj >= ne2);
                        const float* p = db_g + ((size_t)(b * NE + ne2) * NA + j) * BAS + lq * 8;
                        nxt0 = *(const float4*)p;
                        nxt1 = *(const float4*)(p + 4);
                    }
                    bfrag ad = cvt8(cur0, cur1);
                    // GEMM1: H = ssp(db . w1^T + b1)  (16x64, K=32)
                    f32x4 c1[4];
#pragma unroll
                    for (int n = 0; n < 4; n++) {
                        f32x4 z = {0.f, 0.f, 0.f, 0.f};
                        c1[n] = MFMA(ad, w1f[n], z);
                    }
                    // C-layout -> A-layout transpose via wave-private LDS
#pragma unroll
                    for (int n = 0; n < 4; n++)
#pragma unroll
                        for (int r = 0; r < 4; r++)
                            hb[(lq * 4 + r) * HBS + n * 16 + lm] =
                                (u16)ftob(ssp_f(c1[n][r] + b1v[n]));
                    bfrag a20 = *(const bfrag*)&hb[lm * HBS + lq * 8];
                    bfrag a21 = *(const bfrag*)&hb[lm * HBS + 32 + lq * 8];
                    __builtin_amdgcn_sched_barrier(0);
                    // GEMM2 (Ws = H . w2^T, 16x128, K=64) + register consume,
                    // in two 4-n halves to bound live transients.
#pragma unroll
                    for (int n = 0; n < 4; n++) {
                        bfrag wf0 = *(const bfrag*)&w2x[(n * 128 + l) * 8];
                        bfrag wf1 = *(const bfrag*)&w2x[(n * 128 + 64 + l) * 8];
                        f32x4 c2 = {0.f, 0.f, 0.f, 0.f};
                        c2 = MFMA(a20, wf0, c2);
                        c2 = MFMA(a21, wf1, c2);
                        const int k = n * 16 + lm;
#pragma unroll
                        for (int r = 0; r < 4; r++) {
                            const int lp = T * 16 + lq * 4 + r;
                            if (T < 2) {
                                int jr = lp + (lp >= e);
                                zreg[n] += (c2[r] + b2v[n]) * bf2f(zsb[jr * ZST + k]);
                            } else {
                                int jjc = (lp < 35) ? lp : 34;
                                int jr = jjc + (jjc >= e);
                                float val = (c2[r] + b2v[n]) * bf2f(zsb[jr * ZST + k]);
                                zreg[n] += (lp < 35) ? val : 0.f;
                            }
                        }
                    }
                    __builtin_amdgcn_sched_barrier(0);
#pragma unroll
                    for (int n = 4; n < 8; n++) {
                        bfrag wf0 = *(const bfrag*)&w2x[(n * 128 + l) * 8];
                        bfrag wf1 = *(const bfrag*)&w2x[(n * 128 + 64 + l) * 8];
                        f32x4 c2 = {0.f, 0.f, 0.f, 0.f};
                        c2 = MFMA(a20, wf0, c2);
                        c2 = MFMA(a21, wf1, c2);
                        const int k = n * 16 + lm;
#pragma unroll
                        for (int r = 0; r < 4; r++) {
                            const int lp = T * 16 + lq * 4 + r;
                            if (T < 2) {
                                int jr = lp + (lp >= e);
                                zreg[n] += (c2[r] + b2v[n]) * bf2f(zsb[jr * ZST + k]);
                            } else {
                                int jjc = (lp < 35) ? lp : 34;
                                int jr = jjc + (jjc >= e);
                                float val = (c2[r] + b2v[n]) * bf2f(zsb[jr * ZST + k]);
                                zreg[n] += (lp < 35) ? val : 0.f;
                            }
                        }
                    }
                    __builtin_amdgcn_sched_barrier(0);
                }
                // butterfly-reduce over lq (lanes ^16, ^32 share lm) + write
#pragma unroll
                for (int n = 0; n < 8; n++) {
                    float v = zreg[n];
                    v += __shfl_xor(v, 16, 64);
                    v += __shfl_xor(v, 32, 64);
                    zreg[n] = v;
                }
                if (lq == 0) {
#pragma unroll
                    for (int n = 0; n < 8; n++)
                        zaccb[e * AST + n * 16 + lm] = (u16)ftob(zreg[n]);
                }
            }
        }
        __syncthreads();

        // ---- D1: h2 = ssp(z . wo1^T + bo1)  (M=32,N=128,K=128), A from bf16 ----
        {
            bfrag wb[4];
#pragma unroll
            for (int ks = 0; ks < 4; ks++)
                wb[ks] = ldf_frag(wo1_g + (size_t)(t * HO + w * 16 + lm) * KD + ks * 32 + lq * 8);
            float bo1v = bo1_g[t * HO + w * 16 + lm];
            f32x4 c[2];
            c[0] = (f32x4){0.f, 0.f, 0.f, 0.f};
            c[1] = (f32x4){0.f, 0.f, 0.f, 0.f};
#pragma unroll
            for (int m = 0; m < 2; m++)
#pragma unroll
                for (int ks = 0; ks < 4; ks++) {
                    bfrag a = *(const bfrag*)&zaccb[(m * 16 + lm) * AST + ks * 32 + lq * 8];
                    c[m] = MFMA(a, wb[ks], c[m]);
                }
#pragma unroll
            for (int m = 0; m < 2; m++)
#pragma unroll
                for (int r = 0; r < 4; r++)
                    h2b[(m * 16 + lq * 4 + r) * AST + w * 16 + lm] =
                        (u16)ftob(ssp_f(c[m][r] + bo1v));
        }
        __syncthreads();

        // ---- D2: xs += h2 . wo2^T + bo2  (M=32,N=128,K=128), A from bf16 ----
        {
            bfrag wb[4];
#pragma unroll
            for (int ks = 0; ks < 4; ks++)
                wb[ks] = ldf_frag(wo2_g + (size_t)(t * ED + w * 16 + lm) * HO + ks * 32 + lq * 8);
            float bo2v = bo2_g[t * ED + w * 16 + lm];
            f32x4 c[2];
            c[0] = (f32x4){0.f, 0.f, 0.f, 0.f};
            c[1] = (f32x4){0.f, 0.f, 0.f, 0.f};
#pragma unroll
            for (int m = 0; m < 2; m++)
#pragma unroll
                for (int ks = 0; ks < 4; ks++) {
                    bfrag a = *(const bfrag*)&h2b[(m * 16 + lm) * AST + ks * 32 + lq * 8];
                    c[m] = MFMA(a, wb[ks], c[m]);
                }
#pragma unroll
            for (int m = 0; m < 2; m++)
#pragma unroll
                for (int r = 0; r < 4; r++) {
                    int row = m * 16 + lq * 4 + r, col = w * 16 + lm;
                    xs[row * XST + col] += c[m][r] + bo2v;
                }
        }
        __syncthreads();
    }

    // ---- write out (f32, coalesced float4) ----
#pragma unroll
    for (int ii = 0; ii < 2; ii++) {
        int idx = (ii * 512 + tid) * 4;
        int row = idx >> 7, col = idx & 127;
        *(float4*)&out_g[(size_t)b * (NE * ED) + idx] = *(const float4*)&xs[row * XST + col];
    }
}

extern "C" void kernel_launch(void* const* d_in, const int* in_sizes, int n_in,
                              void* d_out, int out_size, void* d_ws, size_t ws_size,
                              hipStream_t stream) {
    schnet_mfma<<<NBATCH, 512, 0, stream>>>(
        (const float*)d_in[0], (const float*)d_in[1], (const float*)d_in[2],
        (const float*)d_in[3], (const float*)d_in[4], (const float*)d_in[5],
        (const float*)d_in[6], (const float*)d_in[7], (const float*)d_in[8],
        (const float*)d_in[9], (const float*)d_in[10], (const float*)d_in[11],
        (float*)d_out);
}

// Round 5
// 281.215 us; speedup vs baseline: 4.7794x; 1.0580x over previous
//
#include <hip/hip_runtime.h>
#include <stdint.h>

#define NBATCH 512
#define NE 32
#define NA 36
#define BAS 32
#define KD 128
#define ED 128
#define HK 64
#define HO 128
#define NT 3

#define XST 132   // xs f32 stride: 4-bank row skew
#define AST 136   // xz (xs-mirror/zacc alias) + h2b stride (u16): 272B rows, 16B-aligned
#define ZJST 36   // zst[k][j] inner stride (u16): 72B rows -> 8B-aligned b64 slots
#define HBS 72    // per-wave H-transpose stride (u16)

typedef uint16_t u16;
typedef uint32_t u32;
using bfrag = __attribute__((ext_vector_type(8))) short;  // 8 bf16 = 4 VGPRs
using f32x4 = __attribute__((ext_vector_type(4))) float;
using u32x2 = __attribute__((ext_vector_type(2))) unsigned int;

#define MFMA(a, b, c) __builtin_amdgcn_mfma_f32_16x16x32_bf16(a, b, c, 0, 0, 0)

// R5: REVERTED to the R0-R3 harness-verified manual RNE conversion.
// R4 swapped these for inline-asm v_cvt_pk_bf16_f32 and failed absmax at
// full reference magnitude; the guide (m240) explicitly warns against
// hand-writing cvt_pk. No inline asm anywhere in this kernel.
__device__ __forceinline__ short ftob(float f) {
    u32 x = __float_as_uint(f);
    u32 r = x + 0x7fffu + ((x >> 16) & 1u); // RNE
    return (short)(r >> 16);
}
// pack two f32 -> (bf16 hi)<<16 | bf16 lo
__device__ __forceinline__ u32 pk2(float lo, float hi) {
    return ((u32)(u16)ftob(hi) << 16) | (u32)(u16)ftob(lo);
}
__device__ __forceinline__ float bf2f(u16 u) {
    return __uint_as_float(((u32)u) << 16);
}
__device__ __forceinline__ bfrag cvt8(float4 a, float4 c) {
    bfrag r;
    r[0] = ftob(a.x); r[1] = ftob(a.y); r[2] = ftob(a.z); r[3] = ftob(a.w);
    r[4] = ftob(c.x); r[5] = ftob(c.y); r[6] = ftob(c.z); r[7] = ftob(c.w);
    return r;
}
__device__ __forceinline__ bfrag ldf_frag(const float* p) {
    float4 a = *(const float4*)p;
    float4 c = *(const float4*)(p + 4);
    return cvt8(a, c);
}
// softplus(x) - log(2), numerically stable
__device__ __forceinline__ float ssp_f(float x) {
    float ax = fabsf(x);
    return fmaxf(x, 0.0f) + __logf(1.0f + __expf(-ax)) - 0.6931471805599453f;
}

// One block per batch element; 512 threads = 8 waves.
// Frag conventions (guide §3, m89/m91-verified):
//   A: lane&15 = m, (lane>>4)*8+j = k   |  B: lane&15 = n, (lane>>4)*8+j = k
//   C/D: col = lane&15 (n), row = (lane>>4)*4 + reg (m)
//
// Structure (R4, kept): zs stored TRANSPOSED zst[k][j] (dense j incl.
// diagonal); consume = one b64 read per n + AND-masks to zero j==e.
// Nuc contribution = ONE shared 16-row tile per wave (rows = 4e x 4j,
// p=lm <-> e=w*4+p/4, j=32+p%4; C row lq*4+r -> e=w*4+lq, j=32+r), so
// 9 tiles/wave instead of 12. Biases ride in MFMA C-in. bf16 xs mirror
// xz (aliased with zacc, disjoint lifetimes) feeds phase-A A-frags.
__global__ __launch_bounds__(512, 4) void schnet_mfma(
    const float* __restrict__ db_g,   // dists_basis (512,32,36,32)
    const float* __restrict__ ee_g,   // embedding_elec (32,128)
    const float* __restrict__ en_g,   // embedding_nuc (4,128)
    const float* __restrict__ w1_g,   // kernel_w1 (3,64,32)
    const float* __restrict__ b1_g,   // kernel_b1 (3,64)
    const float* __restrict__ w2_g,   // kernel_w2 (3,128,64)
    const float* __restrict__ b2_g,   // kernel_b2 (3,128)
    const float* __restrict__ win_g,  // embed_in_w (3,128,128)
    const float* __restrict__ wo1_g,  // embed_out_w1 (3,128,128)
    const float* __restrict__ bo1_g,  // embed_out_b1 (3,128)
    const float* __restrict__ wo2_g,  // embed_out_w2 (3,128,128)
    const float* __restrict__ bo2_g,  // embed_out_b2 (3,128)
    float* __restrict__ out_g)        // (512,32,128) f32
{
    __shared__ __align__(16) float xs[NE * XST];      // residual, f32 (16.9 KB)
    __shared__ __align__(16) u16 xz[NE * AST];        // xs bf16 mirror | zacc (8.7 KB)
    __shared__ __align__(16) u16 zst[KD * ZJST];      // zs TRANSPOSED [k][j] (9.2 KB)
    __shared__ __align__(16) u16 arena[8 * 16 * HBS]; // hb | h2b (18.4 KB)
    __shared__ __align__(16) u16 w2x[8 * 2 * 64 * 8]; // w2 frag-linear (16 KB)
    u16* h2b = arena;                                 // 32*AST = 8.7KB <= arena

    const int tid = threadIdx.x;
    const int b = blockIdx.x;
    const int w = tid >> 6;   // wave 0..7
    const int l = tid & 63;
    const int lm = l & 15;    // m/n lane index
    const int lq = l >> 4;    // quad 0..3

    // ---- init: xs/xz <- embedding_elec; zst nuc cols <- embedding_nuc ----
    {
        int idx = tid * 8;
        float4 v0 = *(const float4*)(ee_g + idx);
        float4 v1 = *(const float4*)(ee_g + idx + 4);
        int row = idx >> 7, col = idx & 127;
        *(float4*)&xs[row * XST + col] = v0;
        *(float4*)&xs[row * XST + col + 4] = v1;
        *(bfrag*)&xz[row * AST + col] = cvt8(v0, v1);
    }
    {
        int k = tid & 127, rr = tid >> 7;  // 512 threads = 128k x 4rr
        zst[k * ZJST + 32 + rr] = (u16)ftob(en_g[rr * 128 + k]);
    }
    __syncthreads();

    for (int t = 0; t < NT; t++) {
        // ---- stage w2 -> LDS frag-linear: unit u=(n,s,lane) holds
        //      w2[n*16+(u&15)][s*32+((u>>4)&3)*8 ..+7] as one 16B bfrag ----
#pragma unroll
        for (int uu = 0; uu < 2; uu++) {
            int u = tid + uu * 512;
            int n = u >> 7, s = (u >> 6) & 1, lane = u & 63;
            int lmm = lane & 15, lqq = lane >> 4;
            const float* p = w2_g + (size_t)(t * KD + n * 16 + lmm) * HK + s * 32 + lqq * 8;
            *(bfrag*)&w2x[u * 8] = ldf_frag(p);
        }

        // ---- per-t small weights (registers) ----
        bfrag w1f[4];
        float b1v[4], b2v[8];
#pragma unroll
        for (int n = 0; n < 4; n++) {
            w1f[n] = ldf_frag(w1_g + (size_t)(t * HK + n * 16 + lm) * BAS + lq * 8);
            b1v[n] = b1_g[t * HK + n * 16 + lm];
        }
#pragma unroll
        for (int n = 0; n < 8; n++) b2v[n] = b2_g[t * KD + n * 16 + lm];

        // ---- phase A: zst[k][e] = (xs . win^T)^T  (M=32,N=128,K=128) ----
        {
            bfrag wb[4];
#pragma unroll
            for (int ks = 0; ks < 4; ks++)
                wb[ks] = ldf_frag(win_g + (size_t)(t * KD + w * 16 + lm) * ED + ks * 32 + lq * 8);
            f32x4 c[2];
            c[0] = (f32x4){0.f, 0.f, 0.f, 0.f};
            c[1] = (f32x4){0.f, 0.f, 0.f, 0.f};
#pragma unroll
            for (int m = 0; m < 2; m++)
#pragma unroll
                for (int ks = 0; ks < 4; ks++) {
                    bfrag a = *(const bfrag*)&xz[(m * 16 + lm) * AST + ks * 32 + lq * 8];
                    c[m] = MFMA(a, wb[ks], c[m]);
                }
            // transposed pack: lane owns k=w*16+lm, rows m*16+lq*4..+3 -> b64
#pragma unroll
            for (int m = 0; m < 2; m++) {
                u32x2 dd;
                dd.x = pk2(c[m][0], c[m][1]);
                dd.y = pk2(c[m][2], c[m][3]);
                *(u32x2*)&zst[(w * 16 + lm) * ZJST + m * 16 + lq * 4] = dd;
            }
        }
        __syncthreads();

        // ---- pair loop: wave w owns e = 4w..4w+3 ----
        // tiles: 1 shared nuc tile (rows = 4e x 4j, j=32..35) + per-e 2 tiles
        {
            u16* hb = arena + w * (16 * HBS); // wave-private H transpose buffer
            float4 nxt0, nxt1;                // rotating distance-1 db prefetch

            // tile body: GEMM1 -> ssp -> transpose -> GEMM2 -> masked consume.
            // jc = this lane's zst column base (b64 covers 4 rows of this tile).
            // kmA/kmC mask r=0,2 (lo16<<16); kmB/kmD pre-ANDed with 0xFFFF0000.
            auto tile_g12 = [&](bfrag ad, int jc, u32 kmA, u32 kmB, u32 kmC,
                                u32 kmD, float* acc) {
                f32x4 c1[4];
#pragma unroll
                for (int n = 0; n < 4; n++) {
                    f32x4 ci = (f32x4){b1v[n], b1v[n], b1v[n], b1v[n]};
                    c1[n] = MFMA(ad, w1f[n], ci);
                }
#pragma unroll
                for (int n = 0; n < 4; n++) {
                    u32 p01 = pk2(ssp_f(c1[n][0]), ssp_f(c1[n][1]));
                    u32 p23 = pk2(ssp_f(c1[n][2]), ssp_f(c1[n][3]));
                    hb[(lq * 4 + 0) * HBS + n * 16 + lm] = (u16)p01;
                    hb[(lq * 4 + 1) * HBS + n * 16 + lm] = (u16)(p01 >> 16);
                    hb[(lq * 4 + 2) * HBS + n * 16 + lm] = (u16)p23;
                    hb[(lq * 4 + 3) * HBS + n * 16 + lm] = (u16)(p23 >> 16);
                }
                bfrag a20 = *(const bfrag*)&hb[lm * HBS + lq * 8];
                bfrag a21 = *(const bfrag*)&hb[lm * HBS + 32 + lq * 8];
                __builtin_amdgcn_sched_barrier(0);
#pragma unroll
                for (int n = 0; n < 4; n++) {
                    bfrag wf0 = *(const bfrag*)&w2x[(n * 128 + l) * 8];
                    bfrag wf1 = *(const bfrag*)&w2x[(n * 128 + 64 + l) * 8];
                    f32x4 c2 = (f32x4){b2v[n], b2v[n], b2v[n], b2v[n]};
                    c2 = MFMA(a20, wf0, c2);
                    c2 = MFMA(a21, wf1, c2);
                    u32x2 zd = *(const u32x2*)&zst[(n * 16 + lm) * ZJST + jc];
                    acc[n] = fmaf(c2[0], __uint_as_float((zd.x << 16) & kmA), acc[n]);
                    acc[n] = fmaf(c2[1], __uint_as_float(zd.x & kmB), acc[n]);
                    acc[n] = fmaf(c2[2], __uint_as_float((zd.y << 16) & kmC), acc[n]);
                    acc[n] = fmaf(c2[3], __uint_as_float(zd.y & kmD), acc[n]);
                }
                __builtin_amdgcn_sched_barrier(0);
#pragma unroll
                for (int n = 4; n < 8; n++) {
                    bfrag wf0 = *(const bfrag*)&w2x[(n * 128 + l) * 8];
                    bfrag wf1 = *(const bfrag*)&w2x[(n * 128 + 64 + l) * 8];
                    f32x4 c2 = (f32x4){b2v[n], b2v[n], b2v[n], b2v[n]};
                    c2 = MFMA(a20, wf0, c2);
                    c2 = MFMA(a21, wf1, c2);
                    u32x2 zd = *(const u32x2*)&zst[(n * 16 + lm) * ZJST + jc];
                    acc[n] = fmaf(c2[0], __uint_as_float((zd.x << 16) & kmA), acc[n]);
                    acc[n] = fmaf(c2[1], __uint_as_float(zd.x & kmB), acc[n]);
                    acc[n] = fmaf(c2[2], __uint_as_float((zd.y << 16) & kmC), acc[n]);
                    acc[n] = fmaf(c2[3], __uint_as_float(zd.y & kmD), acc[n]);
                }
                __builtin_amdgcn_sched_barrier(0);
            };

            // prologue: nuc-tile frag (rows = e:4w+(p>>2), j:32+(p&3))
            {
                int e0 = w * 4 + (lm >> 2), j0 = 32 + (lm & 3);
                const float* p = db_g + ((size_t)(b * NE + e0) * NA + j0) * BAS + lq * 8;
                nxt0 = *(const float4*)p;
                nxt1 = *(const float4*)(p + 4);
            }
            float znuc[8] = {0.f, 0.f, 0.f, 0.f, 0.f, 0.f, 0.f, 0.f};
            {
                float4 cur0 = nxt0, cur1 = nxt1;
                {   // prefetch (le=0, T=0): j = lm
                    const float* p = db_g + ((size_t)(b * NE + w * 4) * NA + lm) * BAS + lq * 8;
                    nxt0 = *(const float4*)p;
                    nxt1 = *(const float4*)(p + 4);
                }
                // consume cols 32..35 for ALL quads (row r <-> j=32+r); no diag
                tile_g12(cvt8(cur0, cur1), 32, ~0u, 0xFFFF0000u, ~0u, 0xFFFF0000u, znuc);
            }

#pragma unroll 1
            for (int le = 0; le < 4; le++) {
                const int e = w * 4 + le;
                float zreg[8] = {0.f, 0.f, 0.f, 0.f, 0.f, 0.f, 0.f, 0.f};
#pragma unroll
                for (int T = 0; T < 2; T++) {
                    float4 cur0 = nxt0, cur1 = nxt1;
                    {   // prefetch next tile in sequence (clamped dummy at end)
                        int nle = (T == 0) ? le : ((le < 3) ? le + 1 : 3);
                        int nT = (T == 0) ? 1 : 0;
                        const float* p = db_g +
                            ((size_t)(b * NE + w * 4 + nle) * NA + nT * 16 + lm) * BAS + lq * 8;
                        nxt0 = *(const float4*)p;
                        nxt1 = *(const float4*)(p + 4);
                    }
                    int lp0 = T * 16 + lq * 4;
                    u32 k0 = (lp0 + 0 == e) ? 0u : ~0u;
                    u32 k1 = (lp0 + 1 == e) ? 0u : ~0u;
                    u32 k2 = (lp0 + 2 == e) ? 0u : ~0u;
                    u32 k3 = (lp0 + 3 == e) ? 0u : ~0u;
                    tile_g12(cvt8(cur0, cur1), lp0, k0, k1 & 0xFFFF0000u,
                             k2, k3 & 0xFFFF0000u, zreg);
                }
                // butterfly over quads; lanes lq==le add their znuc and write
#pragma unroll
                for (int n = 0; n < 8; n++) {
                    float v = zreg[n];
                    v += __shfl_xor(v, 16, 64);
                    v += __shfl_xor(v, 32, 64);
                    zreg[n] = v;
                }
                if (lq == le) {
#pragma unroll
                    for (int n = 0; n < 8; n += 2) {
                        u32 pk = pk2(zreg[n] + znuc[n], zreg[n + 1] + znuc[n + 1]);
                        xz[e * AST + n * 16 + lm] = (u16)pk;
                        xz[e * AST + (n + 1) * 16 + lm] = (u16)(pk >> 16);
                    }
                }
            }
        }
        __syncthreads();

        // ---- D1: h2 = ssp(z . wo1^T + bo1)  (M=32,N=128,K=128) ----
        {
            bfrag wb[4];
#pragma unroll
            for (int ks = 0; ks < 4; ks++)
                wb[ks] = ldf_frag(wo1_g + (size_t)(t * HO + w * 16 + lm) * KD + ks * 32 + lq * 8);
            float bo1v = bo1_g[t * HO + w * 16 + lm];
            f32x4 c[2];
            c[0] = (f32x4){bo1v, bo1v, bo1v, bo1v};
            c[1] = (f32x4){bo1v, bo1v, bo1v, bo1v};
#pragma unroll
            for (int m = 0; m < 2; m++)
#pragma unroll
                for (int ks = 0; ks < 4; ks++) {
                    bfrag a = *(const bfrag*)&xz[(m * 16 + lm) * AST + ks * 32 + lq * 8];
                    c[m] = MFMA(a, wb[ks], c[m]);
                }
#pragma unroll
            for (int m = 0; m < 2; m++) {
                u32 p01 = pk2(ssp_f(c[m][0]), ssp_f(c[m][1]));
                u32 p23 = pk2(ssp_f(c[m][2]), ssp_f(c[m][3]));
                h2b[(m * 16 + lq * 4 + 0) * AST + w * 16 + lm] = (u16)p01;
                h2b[(m * 16 + lq * 4 + 1) * AST + w * 16 + lm] = (u16)(p01 >> 16);
                h2b[(m * 16 + lq * 4 + 2) * AST + w * 16 + lm] = (u16)p23;
                h2b[(m * 16 + lq * 4 + 3) * AST + w * 16 + lm] = (u16)(p23 >> 16);
            }
        }
        __syncthreads();

        // ---- D2: xs += h2 . wo2^T + bo2; refresh bf16 mirror xz ----
        {
            bfrag wb[4];
#pragma unroll
            for (int ks = 0; ks < 4; ks++)
                wb[ks] = ldf_frag(wo2_g + (size_t)(t * ED + w * 16 + lm) * HO + ks * 32 + lq * 8);
            float bo2v = bo2_g[t * ED + w * 16 + lm];
            f32x4 c[2];
            c[0] = (f32x4){bo2v, bo2v, bo2v, bo2v};
            c[1] = (f32x4){bo2v, bo2v, bo2v, bo2v};
#pragma unroll
            for (int m = 0; m < 2; m++)
#pragma unroll
                for (int ks = 0; ks < 4; ks++) {
                    bfrag a = *(const bfrag*)&h2b[(m * 16 + lm) * AST + ks * 32 + lq * 8];
                    c[m] = MFMA(a, wb[ks], c[m]);
                }
#pragma unroll
            for (int m = 0; m < 2; m++) {
                float nv[4];
#pragma unroll
                for (int r = 0; r < 4; r++) {
                    int row = m * 16 + lq * 4 + r, col = w * 16 + lm;
                    nv[r] = xs[row * XST + col] + c[m][r];
                    xs[row * XST + col] = nv[r];
                }
                u32 p01 = pk2(nv[0], nv[1]);
                u32 p23 = pk2(nv[2], nv[3]);
                xz[(m * 16 + lq * 4 + 0) * AST + w * 16 + lm] = (u16)p01;
                xz[(m * 16 + lq * 4 + 1) * AST + w * 16 + lm] = (u16)(p01 >> 16);
                xz[(m * 16 + lq * 4 + 2) * AST + w * 16 + lm] = (u16)p23;
                xz[(m * 16 + lq * 4 + 3) * AST + w * 16 + lm] = (u16)(p23 >> 16);
            }
        }
        __syncthreads();
    }

    // ---- write out (f32, coalesced float4) ----
#pragma unroll
    for (int ii = 0; ii < 2; ii++) {
        int idx = (ii * 512 + tid) * 4;
        int row = idx >> 7, col = idx & 127;
        *(float4*)&out_g[(size_t)b * (NE * ED) + idx] = *(const float4*)&xs[row * XST + col];
    }
}

extern "C" void kernel_launch(void* const* d_in, const int* in_sizes, int n_in,
                              void* d_out, int out_size, void* d_ws, size_t ws_size,
                              hipStream_t stream) {
    schnet_mfma<<<NBATCH, 512, 0, stream>>>(
        (const float*)d_in[0], (const float*)d_in[1], (const float*)d_in[2],
        (const float*)d_in[3], (const float*)d_in[4], (const float*)d_in[5],
        (const float*)d_in[6], (const float*)d_in[7], (const float*)d_in[8],
        (const float*)d_in[9], (const float*)d_in[10], (const float*)d_in[11],
        (float*)d_out);
}

// Round 6
// 254.554 us; speedup vs baseline: 5.2799x; 1.1047x over previous
//
#include <hip/hip_runtime.h>
#include <hip/hip_bf16.h>
#include <stdint.h>

#define NBATCH 512
#define NE 32
#define NA 36
#define BAS 32
#define KD 128
#define ED 128
#define HK 64
#define HO 128
#define NT 3

#define XST 132   // xs f32 stride: 4-bank row skew
#define AST 136   // xz (xs-mirror/zacc alias) + h2b stride (u16): 272B rows, 16B-aligned
#define ZJST 36   // zst[k][j] inner stride (u16): 72B rows -> 8B-aligned b64 slots
#define HBS 72    // per-wave H-transpose stride (u16)

typedef uint16_t u16;
typedef uint32_t u32;
using bfrag = __attribute__((ext_vector_type(8))) short;  // 8 bf16 = 4 VGPRs
using f32x4 = __attribute__((ext_vector_type(4))) float;
using u32x2 = __attribute__((ext_vector_type(2))) unsigned int;

#define MFMA(a, b, c) __builtin_amdgcn_mfma_f32_16x16x32_bf16(a, b, c, 0, 0, 0)

// f32 -> bf16 RNE via the compiler's cast path (emits HW cvt; m240: this is
// the FAST path, and numerics are RNE == the old manual shift/add sequence).
// NO inline asm anywhere (R4's hand-written cvt_pk asm was the corruption).
__device__ __forceinline__ short ftob(float f) {
    union { __hip_bfloat16 h; short s; } u;
    u.h = __float2bfloat16(f);
    return u.s;
}
// pack two f32 -> (bf16 hi)<<16 | bf16 lo
__device__ __forceinline__ u32 pk2(float lo, float hi) {
    return ((u32)(u16)ftob(hi) << 16) | (u32)(u16)ftob(lo);
}
__device__ __forceinline__ bfrag cvt8(float4 a, float4 c) {
    bfrag r;
    r[0] = ftob(a.x); r[1] = ftob(a.y); r[2] = ftob(a.z); r[3] = ftob(a.w);
    r[4] = ftob(c.x); r[5] = ftob(c.y); r[6] = ftob(c.z); r[7] = ftob(c.w);
    return r;
}
__device__ __forceinline__ bfrag ldf_frag(const float* p) {
    float4 a = *(const float4*)p;
    float4 c = *(const float4*)(p + 4);
    return cvt8(a, c);
}
// softplus(x) - log(2), numerically stable
__device__ __forceinline__ float ssp_f(float x) {
    float ax = fabsf(x);
    return fmaxf(x, 0.0f) + __logf(1.0f + __expf(-ax)) - 0.6931471805599453f;
}

// One block per batch element; 512 threads = 8 waves.
// Frag conventions (guide §3, m89/m91-verified):
//   A: lane&15 = m, (lane>>4)*8+j = k   |  B: lane&15 = n, (lane>>4)*8+j = k
//   C/D: col = lane&15 (n), row = (lane>>4)*4 + reg (m)
//
// Structure: zs TRANSPOSED zst[k][j] (dense j incl. diagonal); consume = one
// b64 read per n + AND-masks to zero j==e. Nuc contribution = ONE shared
// 16-row tile per wave (p=lm <-> e=w*4+p/4, j=32+p%4; C row lq*4+r ->
// e=w*4+lq, j=32+r) -> 9 tiles/wave. Biases ride in MFMA C-in. bf16 xs
// mirror xz (aliased with zacc, disjoint lifetimes) feeds phase-A A-frags.
//
// R6: (1) ftob via __float2bfloat16 (HW cvt, fewer VALU ops); (2) w1 moved
// regs -> LDS frag-linear w1x (16 persistent VGPRs freed -- R5's peak live
// set exceeded the 128-reg launch_bounds cap again: WRITE_SIZE 64 MB vs
// 8.4 MB of output = ~56 MB scratch spill threaded through the pair loop).
__global__ __launch_bounds__(512, 4) void schnet_mfma(
    const float* __restrict__ db_g,   // dists_basis (512,32,36,32)
    const float* __restrict__ ee_g,   // embedding_elec (32,128)
    const float* __restrict__ en_g,   // embedding_nuc (4,128)
    const float* __restrict__ w1_g,   // kernel_w1 (3,64,32)
    const float* __restrict__ b1_g,   // kernel_b1 (3,64)
    const float* __restrict__ w2_g,   // kernel_w2 (3,128,64)
    const float* __restrict__ b2_g,   // kernel_b2 (3,128)
    const float* __restrict__ win_g,  // embed_in_w (3,128,128)
    const float* __restrict__ wo1_g,  // embed_out_w1 (3,128,128)
    const float* __restrict__ bo1_g,  // embed_out_b1 (3,128)
    const float* __restrict__ wo2_g,  // embed_out_w2 (3,128,128)
    const float* __restrict__ bo2_g,  // embed_out_b2 (3,128)
    float* __restrict__ out_g)        // (512,32,128) f32
{
    __shared__ __align__(16) float xs[NE * XST];      // residual, f32 (16.9 KB)
    __shared__ __align__(16) u16 xz[NE * AST];        // xs bf16 mirror | zacc (8.7 KB)
    __shared__ __align__(16) u16 zst[KD * ZJST];      // zs TRANSPOSED [k][j] (9.2 KB)
    __shared__ __align__(16) u16 arena[8 * 16 * HBS]; // hb | h2b (18.4 KB)
    __shared__ __align__(16) u16 w2x[8 * 2 * 64 * 8]; // w2 frag-linear (16 KB)
    __shared__ __align__(16) u16 w1x[4 * 64 * 8];     // w1 frag-linear (4 KB)
    u16* h2b = arena;                                 // 32*AST = 8.7KB <= arena
    // total LDS = 73728 B -> 2 blocks/CU (<= 80 KB each)

    const int tid = threadIdx.x;
    const int b = blockIdx.x;
    const int w = tid >> 6;   // wave 0..7
    const int l = tid & 63;
    const int lm = l & 15;    // m/n lane index
    const int lq = l >> 4;    // quad 0..3

    // ---- init: xs/xz <- embedding_elec; zst nuc cols <- embedding_nuc ----
    {
        int idx = tid * 8;
        float4 v0 = *(const float4*)(ee_g + idx);
        float4 v1 = *(const float4*)(ee_g + idx + 4);
        int row = idx >> 7, col = idx & 127;
        *(float4*)&xs[row * XST + col] = v0;
        *(float4*)&xs[row * XST + col + 4] = v1;
        *(bfrag*)&xz[row * AST + col] = cvt8(v0, v1);
    }
    {
        int k = tid & 127, rr = tid >> 7;  // 512 threads = 128k x 4rr
        zst[k * ZJST + 32 + rr] = (u16)ftob(en_g[rr * 128 + k]);
    }
    __syncthreads();

    for (int t = 0; t < NT; t++) {
        // ---- stage w2 + w1 -> LDS frag-linear (consumed after next barrier)
        //      unit u=(n,lane): lane holds w[n*16+(u&15)][s*32+((u>>4)&3)*8..]
#pragma unroll
        for (int uu = 0; uu < 2; uu++) {
            int u = tid + uu * 512;
            int n = u >> 7, s = (u >> 6) & 1, lane = u & 63;
            int lmm = lane & 15, lqq = lane >> 4;
            const float* p = w2_g + (size_t)(t * KD + n * 16 + lmm) * HK + s * 32 + lqq * 8;
            *(bfrag*)&w2x[u * 8] = ldf_frag(p);
        }
        if (tid < 256) {
            int n = tid >> 6, lane = tid & 63;
            const float* p = w1_g + (size_t)(t * HK + n * 16 + (lane & 15)) * BAS
                             + ((lane >> 4) & 3) * 8;
            *(bfrag*)&w1x[tid * 8] = ldf_frag(p);
        }

        // ---- per-t small weights (registers) ----
        float b1v[4], b2v[8];
#pragma unroll
        for (int n = 0; n < 4; n++) b1v[n] = b1_g[t * HK + n * 16 + lm];
#pragma unroll
        for (int n = 0; n < 8; n++) b2v[n] = b2_g[t * KD + n * 16 + lm];

        // ---- phase A: zst[k][e] = (xs . win^T)^T  (M=32,N=128,K=128) ----
        {
            bfrag wb[4];
#pragma unroll
            for (int ks = 0; ks < 4; ks++)
                wb[ks] = ldf_frag(win_g + (size_t)(t * KD + w * 16 + lm) * ED + ks * 32 + lq * 8);
            f32x4 c[2];
            c[0] = (f32x4){0.f, 0.f, 0.f, 0.f};
            c[1] = (f32x4){0.f, 0.f, 0.f, 0.f};
#pragma unroll
            for (int m = 0; m < 2; m++)
#pragma unroll
                for (int ks = 0; ks < 4; ks++) {
                    bfrag a = *(const bfrag*)&xz[(m * 16 + lm) * AST + ks * 32 + lq * 8];
                    c[m] = MFMA(a, wb[ks], c[m]);
                }
            // transposed pack: lane owns k=w*16+lm, rows m*16+lq*4..+3 -> b64
#pragma unroll
            for (int m = 0; m < 2; m++) {
                u32x2 dd;
                dd.x = pk2(c[m][0], c[m][1]);
                dd.y = pk2(c[m][2], c[m][3]);
                *(u32x2*)&zst[(w * 16 + lm) * ZJST + m * 16 + lq * 4] = dd;
            }
        }
        __syncthreads();

        // ---- pair loop: wave w owns e = 4w..4w+3 ----
        // tiles: 1 shared nuc tile (rows = 4e x 4j, j=32..35) + per-e 2 tiles
        {
            u16* hb = arena + w * (16 * HBS); // wave-private H transpose buffer
            float4 nxt0, nxt1;                // rotating distance-1 db prefetch

            // tile body: GEMM1 -> ssp -> transpose -> GEMM2 -> masked consume.
            // jc = this lane's zst column base (b64 covers 4 rows of this tile).
            // kmA/kmC mask r=0,2 (lo16<<16); kmB/kmD pre-ANDed with 0xFFFF0000.
            auto tile_g12 = [&](bfrag ad, int jc, u32 kmA, u32 kmB, u32 kmC,
                                u32 kmD, float* acc) {
                f32x4 c1[4];
#pragma unroll
                for (int n = 0; n < 4; n++) {
                    bfrag w1f = *(const bfrag*)&w1x[(n * 64 + l) * 8];
                    f32x4 ci = (f32x4){b1v[n], b1v[n], b1v[n], b1v[n]};
                    c1[n] = MFMA(ad, w1f, ci);
                }
#pragma unroll
                for (int n = 0; n < 4; n++) {
                    u32 p01 = pk2(ssp_f(c1[n][0]), ssp_f(c1[n][1]));
                    u32 p23 = pk2(ssp_f(c1[n][2]), ssp_f(c1[n][3]));
                    hb[(lq * 4 + 0) * HBS + n * 16 + lm] = (u16)p01;
                    hb[(lq * 4 + 1) * HBS + n * 16 + lm] = (u16)(p01 >> 16);
                    hb[(lq * 4 + 2) * HBS + n * 16 + lm] = (u16)p23;
                    hb[(lq * 4 + 3) * HBS + n * 16 + lm] = (u16)(p23 >> 16);
                }
                bfrag a20 = *(const bfrag*)&hb[lm * HBS + lq * 8];
                bfrag a21 = *(const bfrag*)&hb[lm * HBS + 32 + lq * 8];
                __builtin_amdgcn_sched_barrier(0);
#pragma unroll
                for (int n = 0; n < 4; n++) {
                    bfrag wf0 = *(const bfrag*)&w2x[(n * 128 + l) * 8];
                    bfrag wf1 = *(const bfrag*)&w2x[(n * 128 + 64 + l) * 8];
                    f32x4 c2 = (f32x4){b2v[n], b2v[n], b2v[n], b2v[n]};
                    c2 = MFMA(a20, wf0, c2);
                    c2 = MFMA(a21, wf1, c2);
                    u32x2 zd = *(const u32x2*)&zst[(n * 16 + lm) * ZJST + jc];
                    acc[n] = fmaf(c2[0], __uint_as_float((zd.x << 16) & kmA), acc[n]);
                    acc[n] = fmaf(c2[1], __uint_as_float(zd.x & kmB), acc[n]);
                    acc[n] = fmaf(c2[2], __uint_as_float((zd.y << 16) & kmC), acc[n]);
                    acc[n] = fmaf(c2[3], __uint_as_float(zd.y & kmD), acc[n]);
                }
                __builtin_amdgcn_sched_barrier(0);
#pragma unroll
                for (int n = 4; n < 8; n++) {
                    bfrag wf0 = *(const bfrag*)&w2x[(n * 128 + l) * 8];
                    bfrag wf1 = *(const bfrag*)&w2x[(n * 128 + 64 + l) * 8];
                    f32x4 c2 = (f32x4){b2v[n], b2v[n], b2v[n], b2v[n]};
                    c2 = MFMA(a20, wf0, c2);
                    c2 = MFMA(a21, wf1, c2);
                    u32x2 zd = *(const u32x2*)&zst[(n * 16 + lm) * ZJST + jc];
                    acc[n] = fmaf(c2[0], __uint_as_float((zd.x << 16) & kmA), acc[n]);
                    acc[n] = fmaf(c2[1], __uint_as_float(zd.x & kmB), acc[n]);
                    acc[n] = fmaf(c2[2], __uint_as_float((zd.y << 16) & kmC), acc[n]);
                    acc[n] = fmaf(c2[3], __uint_as_float(zd.y & kmD), acc[n]);
                }
                __builtin_amdgcn_sched_barrier(0);
            };

            // prologue: nuc-tile frag (rows = e:4w+(p>>2), j:32+(p&3))
            {
                int e0 = w * 4 + (lm >> 2), j0 = 32 + (lm & 3);
                const float* p = db_g + ((size_t)(b * NE + e0) * NA + j0) * BAS + lq * 8;
                nxt0 = *(const float4*)p;
                nxt1 = *(const float4*)(p + 4);
            }
            float znuc[8] = {0.f, 0.f, 0.f, 0.f, 0.f, 0.f, 0.f, 0.f};
            {
                float4 cur0 = nxt0, cur1 = nxt1;
                {   // prefetch (le=0, T=0): j = lm
                    const float* p = db_g + ((size_t)(b * NE + w * 4) * NA + lm) * BAS + lq * 8;
                    nxt0 = *(const float4*)p;
                    nxt1 = *(const float4*)(p + 4);
                }
                // consume cols 32..35 for ALL quads (row r <-> j=32+r); no diag
                tile_g12(cvt8(cur0, cur1), 32, ~0u, 0xFFFF0000u, ~0u, 0xFFFF0000u, znuc);
            }

#pragma unroll 1
            for (int le = 0; le < 4; le++) {
                const int e = w * 4 + le;
                float zreg[8] = {0.f, 0.f, 0.f, 0.f, 0.f, 0.f, 0.f, 0.f};
#pragma unroll
                for (int T = 0; T < 2; T++) {
                    float4 cur0 = nxt0, cur1 = nxt1;
                    {   // prefetch next tile in sequence (clamped dummy at end)
                        int nle = (T == 0) ? le : ((le < 3) ? le + 1 : 3);
                        int nT = (T == 0) ? 1 : 0;
                        const float* p = db_g +
                            ((size_t)(b * NE + w * 4 + nle) * NA + nT * 16 + lm) * BAS + lq * 8;
                        nxt0 = *(const float4*)p;
                        nxt1 = *(const float4*)(p + 4);
                    }
                    int lp0 = T * 16 + lq * 4;
                    u32 k0 = (lp0 + 0 == e) ? 0u : ~0u;
                    u32 k1 = (lp0 + 1 == e) ? 0u : ~0u;
                    u32 k2 = (lp0 + 2 == e) ? 0u : ~0u;
                    u32 k3 = (lp0 + 3 == e) ? 0u : ~0u;
                    tile_g12(cvt8(cur0, cur1), lp0, k0, k1 & 0xFFFF0000u,
                             k2, k3 & 0xFFFF0000u, zreg);
                }
                // butterfly over quads; lanes lq==le add their znuc and write
#pragma unroll
                for (int n = 0; n < 8; n++) {
                    float v = zreg[n];
                    v += __shfl_xor(v, 16, 64);
                    v += __shfl_xor(v, 32, 64);
                    zreg[n] = v;
                }
                if (lq == le) {
#pragma unroll
                    for (int n = 0; n < 8; n += 2) {
                        u32 pk = pk2(zreg[n] + znuc[n], zreg[n + 1] + znuc[n + 1]);
                        xz[e * AST + n * 16 + lm] = (u16)pk;
                        xz[e * AST + (n + 1) * 16 + lm] = (u16)(pk >> 16);
                    }
                }
            }
        }
        __syncthreads();

        // ---- D1: h2 = ssp(z . wo1^T + bo1)  (M=32,N=128,K=128) ----
        {
            bfrag wb[4];
#pragma unroll
            for (int ks = 0; ks < 4; ks++)
                wb[ks] = ldf_frag(wo1_g + (size_t)(t * HO + w * 16 + lm) * KD + ks * 32 + lq * 8);
            float bo1v = bo1_g[t * HO + w * 16 + lm];
            f32x4 c[2];
            c[0] = (f32x4){bo1v, bo1v, bo1v, bo1v};
            c[1] = (f32x4){bo1v, bo1v, bo1v, bo1v};
#pragma unroll
            for (int m = 0; m < 2; m++)
#pragma unroll
                for (int ks = 0; ks < 4; ks++) {
                    bfrag a = *(const bfrag*)&xz[(m * 16 + lm) * AST + ks * 32 + lq * 8];
                    c[m] = MFMA(a, wb[ks], c[m]);
                }
#pragma unroll
            for (int m = 0; m < 2; m++) {
                u32 p01 = pk2(ssp_f(c[m][0]), ssp_f(c[m][1]));
                u32 p23 = pk2(ssp_f(c[m][2]), ssp_f(c[m][3]));
                h2b[(m * 16 + lq * 4 + 0) * AST + w * 16 + lm] = (u16)p01;
                h2b[(m * 16 + lq * 4 + 1) * AST + w * 16 + lm] = (u16)(p01 >> 16);
                h2b[(m * 16 + lq * 4 + 2) * AST + w * 16 + lm] = (u16)p23;
                h2b[(m * 16 + lq * 4 + 3) * AST + w * 16 + lm] = (u16)(p23 >> 16);
            }
        }
        __syncthreads();

        // ---- D2: xs += h2 . wo2^T + bo2; refresh bf16 mirror xz ----
        {
            bfrag wb[4];
#pragma unroll
            for (int ks = 0; ks < 4; ks++)
                wb[ks] = ldf_frag(wo2_g + (size_t)(t * ED + w * 16 + lm) * HO + ks * 32 + lq * 8);
            float bo2v = bo2_g[t * ED + w * 16 + lm];
            f32x4 c[2];
            c[0] = (f32x4){bo2v, bo2v, bo2v, bo2v};
            c[1] = (f32x4){bo2v, bo2v, bo2v, bo2v};
#pragma unroll
            for (int m = 0; m < 2; m++)
#pragma unroll
                for (int ks = 0; ks < 4; ks++) {
                    bfrag a = *(const bfrag*)&h2b[(m * 16 + lm) * AST + ks * 32 + lq * 8];
                    c[m] = MFMA(a, wb[ks], c[m]);
                }
#pragma unroll
            for (int m = 0; m < 2; m++) {
                float nv[4];
#pragma unroll
                for (int r = 0; r < 4; r++) {
                    int row = m * 16 + lq * 4 + r, col = w * 16 + lm;
                    nv[r] = xs[row * XST + col] + c[m][r];
                    xs[row * XST + col] = nv[r];
                }
                u32 p01 = pk2(nv[0], nv[1]);
                u32 p23 = pk2(nv[2], nv[3]);
                xz[(m * 16 + lq * 4 + 0) * AST + w * 16 + lm] = (u16)p01;
                xz[(m * 16 + lq * 4 + 1) * AST + w * 16 + lm] = (u16)(p01 >> 16);
                xz[(m * 16 + lq * 4 + 2) * AST + w * 16 + lm] = (u16)p23;
                xz[(m * 16 + lq * 4 + 3) * AST + w * 16 + lm] = (u16)(p23 >> 16);
            }
        }
        __syncthreads();
    }

    // ---- write out (f32, coalesced float4) ----
#pragma unroll
    for (int ii = 0; ii < 2; ii++) {
        int idx = (ii * 512 + tid) * 4;
        int row = idx >> 7, col = idx & 127;
        *(float4*)&out_g[(size_t)b * (NE * ED) + idx] = *(const float4*)&xs[row * XST + col];
    }
}

extern "C" void kernel_launch(void* const* d_in, const int* in_sizes, int n_in,
                              void* d_out, int out_size, void* d_ws, size_t ws_size,
                              hipStream_t stream) {
    schnet_mfma<<<NBATCH, 512, 0, stream>>>(
        (const float*)d_in[0], (const float*)d_in[1], (const float*)d_in[2],
        (const float*)d_in[3], (const float*)d_in[4], (const float*)d_in[5],
        (const float*)d_in[6], (const float*)d_in[7], (const float*)d_in[8],
        (const float*)d_in[9], (const float*)d_in[10], (const float*)d_in[11],
        (float*)d_out);
}

// Round 7
// 243.004 us; speedup vs baseline: 5.5309x; 1.0475x over previous
//
#include <hip/hip_runtime.h>
#include <hip/hip_bf16.h>
#include <stdint.h>

#define NBATCH 512
#define NE 32
#define NA 36
#define BAS 32
#define KD 128
#define ED 128
#define HK 64
#define HO 128
#define NT 3

#define XST 132   // xs f32 stride: 4-bank row skew
#define AST 136   // xz (xs-mirror/zacc alias) + h2b stride (u16): 272B rows, 16B-aligned
#define ZJST 36   // zst[k][j] inner stride (u16): 72B rows -> 8B-aligned b64 slots
#define HBS 72    // per-wave H-transpose stride (u16)

typedef uint16_t u16;
typedef uint32_t u32;
using bfrag = __attribute__((ext_vector_type(8))) short;  // 8 bf16 = 4 VGPRs
using f32x4 = __attribute__((ext_vector_type(4))) float;
using u32x2 = __attribute__((ext_vector_type(2))) unsigned int;

#define MFMA(a, b, c) __builtin_amdgcn_mfma_f32_16x16x32_bf16(a, b, c, 0, 0, 0)

// f32 -> bf16 RNE via the compiler's cast path (m240: the fast path).
// NO inline asm anywhere (R4's hand-written cvt_pk asm silently corrupted).
__device__ __forceinline__ short ftob(float f) {
    union { __hip_bfloat16 h; short s; } u;
    u.h = __float2bfloat16(f);
    return u.s;
}
// pack two f32 -> (bf16 hi)<<16 | bf16 lo
__device__ __forceinline__ u32 pk2(float lo, float hi) {
    return ((u32)(u16)ftob(hi) << 16) | (u32)(u16)ftob(lo);
}
__device__ __forceinline__ bfrag cvt8(float4 a, float4 c) {
    bfrag r;
    r[0] = ftob(a.x); r[1] = ftob(a.y); r[2] = ftob(a.z); r[3] = ftob(a.w);
    r[4] = ftob(c.x); r[5] = ftob(c.y); r[6] = ftob(c.z); r[7] = ftob(c.w);
    return r;
}
__device__ __forceinline__ bfrag ldf_frag(const float* p) {
    float4 a = *(const float4*)p;
    float4 c = *(const float4*)(p + 4);
    return cvt8(a, c);
}
// softplus(x) - log(2), numerically stable
__device__ __forceinline__ float ssp_f(float x) {
    float ax = fabsf(x);
    return fmaxf(x, 0.0f) + __logf(1.0f + __expf(-ax)) - 0.6931471805599453f;
}

// One block per batch element; 512 threads = 8 waves.
// Frag conventions (guide §3, m89/m91-verified):
//   A: lane&15 = m, (lane>>4)*8+j = k   |  B: lane&15 = n, (lane>>4)*8+j = k
//   C/D: col = lane&15 (n), row = (lane>>4)*4 + reg (m)
//
// Structure: zs TRANSPOSED zst[k][j]; consume = b64 read per n + AND-masks
// zeroing j==e. Nuc contribution = ONE shared 16-row tile per wave
// (p=lm <-> e=w*4+p/4, j=32+p%4) -> 9 tiles/wave. Biases ride in MFMA C-in.
// bf16 xs mirror xz (aliased with zacc, disjoint lifetimes).
//
// R7 (spill-kill round; R6 still had ~46 MB scratch in WRITE_SIZE):
//  - znuc folded to LDS right after the nuc tile (was 8 regs live across
//    the whole le loop); le-end does same-lane RMW on xz
//  - b2 biases in LDS bb2[128] (8 persistent regs -> 8 ds_read_b32/tile)
//  - parity double-buffer a/b for db prefetch (no cur=nxt copies)
//  - GEMM2 fenced every 2 n (transient peak ~28 regs, was ~56)
__global__ __launch_bounds__(512, 4) void schnet_mfma(
    const float* __restrict__ db_g,   // dists_basis (512,32,36,32)
    const float* __restrict__ ee_g,   // embedding_elec (32,128)
    const float* __restrict__ en_g,   // embedding_nuc (4,128)
    const float* __restrict__ w1_g,   // kernel_w1 (3,64,32)
    const float* __restrict__ b1_g,   // kernel_b1 (3,64)
    const float* __restrict__ w2_g,   // kernel_w2 (3,128,64)
    const float* __restrict__ b2_g,   // kernel_b2 (3,128)
    const float* __restrict__ win_g,  // embed_in_w (3,128,128)
    const float* __restrict__ wo1_g,  // embed_out_w1 (3,128,128)
    const float* __restrict__ bo1_g,  // embed_out_b1 (3,128)
    const float* __restrict__ wo2_g,  // embed_out_w2 (3,128,128)
    const float* __restrict__ bo2_g,  // embed_out_b2 (3,128)
    float* __restrict__ out_g)        // (512,32,128) f32
{
    __shared__ __align__(16) float xs[NE * XST];      // residual, f32 (16.9 KB)
    __shared__ __align__(16) u16 xz[NE * AST];        // xs bf16 mirror | zacc (8.7 KB)
    __shared__ __align__(16) u16 zst[KD * ZJST];      // zs TRANSPOSED [k][j] (9.2 KB)
    __shared__ __align__(16) u16 arena[8 * 16 * HBS]; // hb | h2b (18.4 KB)
    __shared__ __align__(16) u16 w2x[8 * 2 * 64 * 8]; // w2 frag-linear (16 KB)
    __shared__ __align__(16) u16 w1x[4 * 64 * 8];     // w1 frag-linear (4 KB)
    __shared__ __align__(16) float bb2[KD];           // b2 bias (512 B)
    u16* h2b = arena;                                 // 32*AST = 8.7KB <= arena
    // total LDS ~74.2 KB -> 2 blocks/CU

    const int tid = threadIdx.x;
    const int b = blockIdx.x;
    const int w = tid >> 6;   // wave 0..7
    const int l = tid & 63;
    const int lm = l & 15;    // m/n lane index
    const int lq = l >> 4;    // quad 0..3

    // ---- init: xs/xz <- embedding_elec; zst nuc cols <- embedding_nuc ----
    {
        int idx = tid * 8;
        float4 v0 = *(const float4*)(ee_g + idx);
        float4 v1 = *(const float4*)(ee_g + idx + 4);
        int row = idx >> 7, col = idx & 127;
        *(float4*)&xs[row * XST + col] = v0;
        *(float4*)&xs[row * XST + col + 4] = v1;
        *(bfrag*)&xz[row * AST + col] = cvt8(v0, v1);
    }
    {
        int k = tid & 127, rr = tid >> 7;  // 512 threads = 128k x 4rr
        zst[k * ZJST + 32 + rr] = (u16)ftob(en_g[rr * 128 + k]);
    }
    __syncthreads();

    for (int t = 0; t < NT; t++) {
        // ---- stage w2 + w1 + b2 -> LDS (consumed after next barrier) ----
#pragma unroll
        for (int uu = 0; uu < 2; uu++) {
            int u = tid + uu * 512;
            int n = u >> 7, s = (u >> 6) & 1, lane = u & 63;
            int lmm = lane & 15, lqq = lane >> 4;
            const float* p = w2_g + (size_t)(t * KD + n * 16 + lmm) * HK + s * 32 + lqq * 8;
            *(bfrag*)&w2x[u * 8] = ldf_frag(p);
        }
        if (tid < 256) {
            int n = tid >> 6, lane = tid & 63;
            const float* p = w1_g + (size_t)(t * HK + n * 16 + (lane & 15)) * BAS
                             + ((lane >> 4) & 3) * 8;
            *(bfrag*)&w1x[tid * 8] = ldf_frag(p);
        } else if (tid < 384) {
            bb2[tid - 256] = b2_g[t * KD + tid - 256];
        }

        // ---- per-t small weights (registers) ----
        float b1v[4];
#pragma unroll
        for (int n = 0; n < 4; n++) b1v[n] = b1_g[t * HK + n * 16 + lm];

        // ---- phase A: zst[k][e] = (xs . win^T)^T  (M=32,N=128,K=128) ----
        {
            bfrag wb[4];
#pragma unroll
            for (int ks = 0; ks < 4; ks++)
                wb[ks] = ldf_frag(win_g + (size_t)(t * KD + w * 16 + lm) * ED + ks * 32 + lq * 8);
            f32x4 c[2];
            c[0] = (f32x4){0.f, 0.f, 0.f, 0.f};
            c[1] = (f32x4){0.f, 0.f, 0.f, 0.f};
#pragma unroll
            for (int m = 0; m < 2; m++)
#pragma unroll
                for (int ks = 0; ks < 4; ks++) {
                    bfrag a = *(const bfrag*)&xz[(m * 16 + lm) * AST + ks * 32 + lq * 8];
                    c[m] = MFMA(a, wb[ks], c[m]);
                }
            // transposed pack: lane owns k=w*16+lm, rows m*16+lq*4..+3 -> b64
#pragma unroll
            for (int m = 0; m < 2; m++) {
                u32x2 dd;
                dd.x = pk2(c[m][0], c[m][1]);
                dd.y = pk2(c[m][2], c[m][3]);
                *(u32x2*)&zst[(w * 16 + lm) * ZJST + m * 16 + lq * 4] = dd;
            }
        }
        __syncthreads();

        // ---- pair loop: wave w owns e = 4w..4w+3 ----
        // tiles: 1 shared nuc tile (rows = 4e x 4j, j=32..35) + per-e 2 tiles
        {
            u16* hb = arena + w * (16 * HBS); // wave-private H transpose buffer
            float4 a0, a1, b0, b1;            // parity double-buffer (db)

            // tile body: GEMM1 -> ssp -> transpose -> GEMM2 -> masked consume.
            // jc = this lane's zst column base (b64 covers 4 rows of this tile).
            // kmA/kmC mask r=0,2 (lo16<<16); kmB/kmD pre-ANDed with 0xFFFF0000.
            auto tile_g12 = [&](bfrag ad, int jc, u32 kmA, u32 kmB, u32 kmC,
                                u32 kmD, float* acc) {
                f32x4 c1[4];
#pragma unroll
                for (int n = 0; n < 4; n++) {
                    bfrag w1f = *(const bfrag*)&w1x[(n * 64 + l) * 8];
                    f32x4 ci = (f32x4){b1v[n], b1v[n], b1v[n], b1v[n]};
                    c1[n] = MFMA(ad, w1f, ci);
                }
#pragma unroll
                for (int n = 0; n < 4; n++) {
                    u32 p01 = pk2(ssp_f(c1[n][0]), ssp_f(c1[n][1]));
                    u32 p23 = pk2(ssp_f(c1[n][2]), ssp_f(c1[n][3]));
                    hb[(lq * 4 + 0) * HBS + n * 16 + lm] = (u16)p01;
                    hb[(lq * 4 + 1) * HBS + n * 16 + lm] = (u16)(p01 >> 16);
                    hb[(lq * 4 + 2) * HBS + n * 16 + lm] = (u16)p23;
                    hb[(lq * 4 + 3) * HBS + n * 16 + lm] = (u16)(p23 >> 16);
                }
                bfrag a20 = *(const bfrag*)&hb[lm * HBS + lq * 8];
                bfrag a21 = *(const bfrag*)&hb[lm * HBS + 32 + lq * 8];
                __builtin_amdgcn_sched_barrier(0);
                // GEMM2 + consume, fenced every 2 n to bound live transients
#pragma unroll
                for (int g = 0; g < 4; g++) {
#pragma unroll
                    for (int nn = 0; nn < 2; nn++) {
                        const int n = g * 2 + nn;
                        bfrag wf0 = *(const bfrag*)&w2x[(n * 128 + l) * 8];
                        bfrag wf1 = *(const bfrag*)&w2x[(n * 128 + 64 + l) * 8];
                        float bv = bb2[n * 16 + lm];
                        f32x4 c2 = (f32x4){bv, bv, bv, bv};
                        c2 = MFMA(a20, wf0, c2);
                        c2 = MFMA(a21, wf1, c2);
                        u32x2 zd = *(const u32x2*)&zst[(n * 16 + lm) * ZJST + jc];
                        acc[n] = fmaf(c2[0], __uint_as_float((zd.x << 16) & kmA), acc[n]);
                        acc[n] = fmaf(c2[1], __uint_as_float(zd.x & kmB), acc[n]);
                        acc[n] = fmaf(c2[2], __uint_as_float((zd.y << 16) & kmC), acc[n]);
                        acc[n] = fmaf(c2[3], __uint_as_float(zd.y & kmD), acc[n]);
                    }
                    __builtin_amdgcn_sched_barrier(0);
                }
            };

            // ---- nuc tile: load -> a; prefetch (le0,T0) -> b; znuc -> xz ----
            {
                {
                    int e0 = w * 4 + (lm >> 2), j0 = 32 + (lm & 3);
                    const float* p = db_g + ((size_t)(b * NE + e0) * NA + j0) * BAS + lq * 8;
                    a0 = *(const float4*)p;
                    a1 = *(const float4*)(p + 4);
                }
                {
                    const float* p = db_g + ((size_t)(b * NE + w * 4) * NA + lm) * BAS + lq * 8;
                    b0 = *(const float4*)p;
                    b1 = *(const float4*)(p + 4);
                }
                float znuc[8] = {0.f, 0.f, 0.f, 0.f, 0.f, 0.f, 0.f, 0.f};
                // consume cols 32..35 for ALL quads (row r <-> j=32+r); no diag
                tile_g12(cvt8(a0, a1), 32, ~0u, 0xFFFF0000u, ~0u, 0xFFFF0000u, znuc);
                // lane (lq,lm) holds nuc-sum for e=w*4+lq, k=n*16+lm: park in xz
                int e0 = w * 4 + lq;
#pragma unroll
                for (int n = 0; n < 8; n += 2) {
                    u32 pk = pk2(znuc[n], znuc[n + 1]);
                    xz[e0 * AST + n * 16 + lm] = (u16)pk;
                    xz[e0 * AST + (n + 1) * 16 + lm] = (u16)(pk >> 16);
                }
            }

#pragma unroll 1
            for (int le = 0; le < 4; le++) {
                const int e = w * 4 + le;
                float zreg[8] = {0.f, 0.f, 0.f, 0.f, 0.f, 0.f, 0.f, 0.f};
                // T=0: prefetch (le,T=1) -> a; consume b
                {
                    const float* p = db_g + ((size_t)(b * NE + e) * NA + 16 + lm) * BAS + lq * 8;
                    a0 = *(const float4*)p;
                    a1 = *(const float4*)(p + 4);
                }
                {
                    int lp0 = lq * 4;
                    u32 k0 = (lp0 + 0 == e) ? 0u : ~0u;
                    u32 k1 = (lp0 + 1 == e) ? 0u : ~0u;
                    u32 k2 = (lp0 + 2 == e) ? 0u : ~0u;
                    u32 k3 = (lp0 + 3 == e) ? 0u : ~0u;
                    tile_g12(cvt8(b0, b1), lp0, k0, k1 & 0xFFFF0000u,
                             k2, k3 & 0xFFFF0000u, zreg);
                }
                // T=1: prefetch (le+1,T=0) -> b (clamped dummy at end); consume a
                {
                    int nle = (le < 3) ? le + 1 : 3;
                    const float* p = db_g + ((size_t)(b * NE + w * 4 + nle) * NA + lm) * BAS + lq * 8;
                    b0 = *(const float4*)p;
                    b1 = *(const float4*)(p + 4);
                }
                {
                    int lp0 = 16 + lq * 4;
                    u32 k0 = (lp0 + 0 == e) ? 0u : ~0u;
                    u32 k1 = (lp0 + 1 == e) ? 0u : ~0u;
                    u32 k2 = (lp0 + 2 == e) ? 0u : ~0u;
                    u32 k3 = (lp0 + 3 == e) ? 0u : ~0u;
                    tile_g12(cvt8(a0, a1), lp0, k0, k1 & 0xFFFF0000u,
                             k2, k3 & 0xFFFF0000u, zreg);
                }
                // butterfly over quads; lanes lq==le RMW nuc partial in xz
#pragma unroll
                for (int n = 0; n < 8; n++) {
                    float v = zreg[n];
                    v += __shfl_xor(v, 16, 64);
                    v += __shfl_xor(v, 32, 64);
                    zreg[n] = v;
                }
                if (lq == le) {
#pragma unroll
                    for (int n = 0; n < 8; n += 2) {
                        float o0 = __uint_as_float((u32)xz[e * AST + n * 16 + lm] << 16);
                        float o1 = __uint_as_float((u32)xz[e * AST + (n + 1) * 16 + lm] << 16);
                        u32 pk = pk2(zreg[n] + o0, zreg[n + 1] + o1);
                        xz[e * AST + n * 16 + lm] = (u16)pk;
                        xz[e * AST + (n + 1) * 16 + lm] = (u16)(pk >> 16);
                    }
                }
            }
        }
        __syncthreads();

        // ---- D1: h2 = ssp(z . wo1^T + bo1)  (M=32,N=128,K=128) ----
        {
            bfrag wb[4];
#pragma unroll
            for (int ks = 0; ks < 4; ks++)
                wb[ks] = ldf_frag(wo1_g + (size_t)(t * HO + w * 16 + lm) * KD + ks * 32 + lq * 8);
            float bo1v = bo1_g[t * HO + w * 16 + lm];
            f32x4 c[2];
            c[0] = (f32x4){bo1v, bo1v, bo1v, bo1v};
            c[1] = (f32x4){bo1v, bo1v, bo1v, bo1v};
#pragma unroll
            for (int m = 0; m < 2; m++)
#pragma unroll
                for (int ks = 0; ks < 4; ks++) {
                    bfrag a = *(const bfrag*)&xz[(m * 16 + lm) * AST + ks * 32 + lq * 8];
                    c[m] = MFMA(a, wb[ks], c[m]);
                }
#pragma unroll
            for (int m = 0; m < 2; m++) {
                u32 p01 = pk2(ssp_f(c[m][0]), ssp_f(c[m][1]));
                u32 p23 = pk2(ssp_f(c[m][2]), ssp_f(c[m][3]));
                h2b[(m * 16 + lq * 4 + 0) * AST + w * 16 + lm] = (u16)p01;
                h2b[(m * 16 + lq * 4 + 1) * AST + w * 16 + lm] = (u16)(p01 >> 16);
                h2b[(m * 16 + lq * 4 + 2) * AST + w * 16 + lm] = (u16)p23;
                h2b[(m * 16 + lq * 4 + 3) * AST + w * 16 + lm] = (u16)(p23 >> 16);
            }
        }
        __syncthreads();

        // ---- D2: xs += h2 . wo2^T + bo2; refresh bf16 mirror xz ----
        {
            bfrag wb[4];
#pragma unroll
            for (int ks = 0; ks < 4; ks++)
                wb[ks] = ldf_frag(wo2_g + (size_t)(t * ED + w * 16 + lm) * HO + ks * 32 + lq * 8);
            float bo2v = bo2_g[t * ED + w * 16 + lm];
            f32x4 c[2];
            c[0] = (f32x4){bo2v, bo2v, bo2v, bo2v};
            c[1] = (f32x4){bo2v, bo2v, bo2v, bo2v};
#pragma unroll
            for (int m = 0; m < 2; m++)
#pragma unroll
                for (int ks = 0; ks < 4; ks++) {
                    bfrag a = *(const bfrag*)&h2b[(m * 16 + lm) * AST + ks * 32 + lq * 8];
                    c[m] = MFMA(a, wb[ks], c[m]);
                }
#pragma unroll
            for (int m = 0; m < 2; m++) {
                float nv[4];
#pragma unroll
                for (int r = 0; r < 4; r++) {
                    int row = m * 16 + lq * 4 + r, col = w * 16 + lm;
                    nv[r] = xs[row * XST + col] + c[m][r];
                    xs[row * XST + col] = nv[r];
                }
                u32 p01 = pk2(nv[0], nv[1]);
                u32 p23 = pk2(nv[2], nv[3]);
                xz[(m * 16 + lq * 4 + 0) * AST + w * 16 + lm] = (u16)p01;
                xz[(m * 16 + lq * 4 + 1) * AST + w * 16 + lm] = (u16)(p01 >> 16);
                xz[(m * 16 + lq * 4 + 2) * AST + w * 16 + lm] = (u16)p23;
                xz[(m * 16 + lq * 4 + 3) * AST + w * 16 + lm] = (u16)(p23 >> 16);
            }
        }
        __syncthreads();
    }

    // ---- write out (f32, coalesced float4) ----
#pragma unroll
    for (int ii = 0; ii < 2; ii++) {
        int idx = (ii * 512 + tid) * 4;
        int row = idx >> 7, col = idx & 127;
        *(float4*)&out_g[(size_t)b * (NE * ED) + idx] = *(const float4*)&xs[row * XST + col];
    }
}

extern "C" void kernel_launch(void* const* d_in, const int* in_sizes, int n_in,
                              void* d_out, int out_size, void* d_ws, size_t ws_size,
                              hipStream_t stream) {
    schnet_mfma<<<NBATCH, 512, 0, stream>>>(
        (const float*)d_in[0], (const float*)d_in[1], (const float*)d_in[2],
        (const float*)d_in[3], (const float*)d_in[4], (const float*)d_in[5],
        (const float*)d_in[6], (const float*)d_in[7], (const float*)d_in[8],
        (const float*)d_in[9], (const float*)d_in[10], (const float*)d_in[11],
        (float*)d_out);
}

// Round 8
// 242.460 us; speedup vs baseline: 5.5433x; 1.0022x over previous
//
#include <hip/hip_runtime.h>
#include <hip/hip_bf16.h>
#include <stdint.h>

#define NBATCH 512
#define NE 32
#define NA 36
#define BAS 32
#define KD 128
#define ED 128
#define HK 64
#define HO 128
#define NT 3

#define XST 132   // xs f32 stride: 4-bank row skew
#define AST 136   // xz (xs-mirror/zacc alias) + h2b stride (u16): 272B rows, 16B-aligned
#define ZJST 36   // zst[k][j] inner stride (u16): 72B rows -> 8B-aligned b64 slots
#define HBS 72    // per-wave H-transpose stride (u16)

typedef uint16_t u16;
typedef uint32_t u32;
using bfrag = __attribute__((ext_vector_type(8))) short;  // 8 bf16 = 4 VGPRs
using f32x4 = __attribute__((ext_vector_type(4))) float;
using u32x2 = __attribute__((ext_vector_type(2))) unsigned int;

#define MFMA(a, b, c) __builtin_amdgcn_mfma_f32_16x16x32_bf16(a, b, c, 0, 0, 0)

// f32 -> bf16 RNE via the compiler's cast path (m240: the fast path).
// NO inline asm anywhere (R4's hand-written cvt_pk asm silently corrupted).
__device__ __forceinline__ short ftob(float f) {
    union { __hip_bfloat16 h; short s; } u;
    u.h = __float2bfloat16(f);
    return u.s;
}
// pack two f32 -> (bf16 hi)<<16 | bf16 lo
__device__ __forceinline__ u32 pk2(float lo, float hi) {
    return ((u32)(u16)ftob(hi) << 16) | (u32)(u16)ftob(lo);
}
__device__ __forceinline__ float bf2f(u16 u) {
    return __uint_as_float(((u32)u) << 16);
}
__device__ __forceinline__ bfrag cvt8(float4 a, float4 c) {
    bfrag r;
    r[0] = ftob(a.x); r[1] = ftob(a.y); r[2] = ftob(a.z); r[3] = ftob(a.w);
    r[4] = ftob(c.x); r[5] = ftob(c.y); r[6] = ftob(c.z); r[7] = ftob(c.w);
    return r;
}
__device__ __forceinline__ bfrag ldf_frag(const float* p) {
    float4 a = *(const float4*)p;
    float4 c = *(const float4*)(p + 4);
    return cvt8(a, c);
}
// softplus(x) - log(2), numerically stable
__device__ __forceinline__ float ssp_f(float x) {
    float ax = fabsf(x);
    return fmaxf(x, 0.0f) + __logf(1.0f + __expf(-ax)) - 0.6931471805599453f;
}

// One block per batch element; 512 threads = 8 waves.
// Frag conventions (guide §3, m89/m91-verified):
//   A: lane&15 = m, (lane>>4)*8+j = k   |  B: lane&15 = n, (lane>>4)*8+j = k
//   C/D: col = lane&15 (n), row = (lane>>4)*4 + reg (m)
//
// Structure: zs TRANSPOSED zst[k][j]; consume = b64 read per n + AND-masks
// zeroing j==e. Nuc contribution = ONE shared 16-row tile per wave
// (p=lm <-> e=w*4+p/4, j=32+p%4) -> 9 tiles/wave. bf16 xs mirror xz
// (aliased with zacc, disjoint lifetimes).
//
// R8 (VALU-volume cut; R7 showed spill removal = no gain -> issue-bound):
//  - BIAS-SUM TRICK: sum_{j!=e}(Ws+b2)*zs = sum Ws*zs + b2*(S_all - zs[e]).
//    S_all[k] computed ONCE in phase A from the PACKED bf16 values (exact
//    cancellation with what consume reads); GEMM2 C-in = shared zero quad.
//    Deletes per-tile: 8 bb2 reads + 32 bias-splat movs.
//  - GEMM2 fence relaxed to every-4n (spill is gone; more ILP per region).
//    Guard: WRITE_SIZE must stay <= ~22 MB, else revert.
__global__ __launch_bounds__(512, 4) void schnet_mfma(
    const float* __restrict__ db_g,   // dists_basis (512,32,36,32)
    const float* __restrict__ ee_g,   // embedding_elec (32,128)
    const float* __restrict__ en_g,   // embedding_nuc (4,128)
    const float* __restrict__ w1_g,   // kernel_w1 (3,64,32)
    const float* __restrict__ b1_g,   // kernel_b1 (3,64)
    const float* __restrict__ w2_g,   // kernel_w2 (3,128,64)
    const float* __restrict__ b2_g,   // kernel_b2 (3,128)
    const float* __restrict__ win_g,  // embed_in_w (3,128,128)
    const float* __restrict__ wo1_g,  // embed_out_w1 (3,128,128)
    const float* __restrict__ bo1_g,  // embed_out_b1 (3,128)
    const float* __restrict__ wo2_g,  // embed_out_w2 (3,128,128)
    const float* __restrict__ bo2_g,  // embed_out_b2 (3,128)
    float* __restrict__ out_g)        // (512,32,128) f32
{
    __shared__ __align__(16) float xs[NE * XST];      // residual, f32 (16.9 KB)
    __shared__ __align__(16) u16 xz[NE * AST];        // xs bf16 mirror | zacc (8.7 KB)
    __shared__ __align__(16) u16 zst[KD * ZJST];      // zs TRANSPOSED [k][j] (9.2 KB)
    __shared__ __align__(16) u16 arena[8 * 16 * HBS]; // hb | h2b (18.4 KB)
    __shared__ __align__(16) u16 w2x[8 * 2 * 64 * 8]; // w2 frag-linear (16 KB)
    __shared__ __align__(16) u16 w1x[4 * 64 * 8];     // w1 frag-linear (4 KB)
    __shared__ __align__(16) float bb2[KD];           // b2 bias (512 B)
    __shared__ __align__(16) float sall[KD];          // S_all[k] (512 B)
    u16* h2b = arena;                                 // 32*AST = 8.7KB <= arena
    // total LDS ~74.7 KB -> 2 blocks/CU

    const int tid = threadIdx.x;
    const int b = blockIdx.x;
    const int w = tid >> 6;   // wave 0..7
    const int l = tid & 63;
    const int lm = l & 15;    // m/n lane index
    const int lq = l >> 4;    // quad 0..3

    // ---- init: xs/xz <- embedding_elec; zst nuc cols <- embedding_nuc ----
    {
        int idx = tid * 8;
        float4 v0 = *(const float4*)(ee_g + idx);
        float4 v1 = *(const float4*)(ee_g + idx + 4);
        int row = idx >> 7, col = idx & 127;
        *(float4*)&xs[row * XST + col] = v0;
        *(float4*)&xs[row * XST + col + 4] = v1;
        *(bfrag*)&xz[row * AST + col] = cvt8(v0, v1);
    }
    {
        int k = tid & 127, rr = tid >> 7;  // 512 threads = 128k x 4rr
        zst[k * ZJST + 32 + rr] = (u16)ftob(en_g[rr * 128 + k]);
    }
    __syncthreads();

    for (int t = 0; t < NT; t++) {
        // ---- stage w2 + w1 + b2 -> LDS (consumed after next barrier) ----
#pragma unroll
        for (int uu = 0; uu < 2; uu++) {
            int u = tid + uu * 512;
            int n = u >> 7, s = (u >> 6) & 1, lane = u & 63;
            int lmm = lane & 15, lqq = lane >> 4;
            const float* p = w2_g + (size_t)(t * KD + n * 16 + lmm) * HK + s * 32 + lqq * 8;
            *(bfrag*)&w2x[u * 8] = ldf_frag(p);
        }
        if (tid < 256) {
            int n = tid >> 6, lane = tid & 63;
            const float* p = w1_g + (size_t)(t * HK + n * 16 + (lane & 15)) * BAS
                             + ((lane >> 4) & 3) * 8;
            *(bfrag*)&w1x[tid * 8] = ldf_frag(p);
        } else if (tid < 384) {
            bb2[tid - 256] = b2_g[t * KD + tid - 256];
        }

        // ---- per-t small weights (registers) ----
        float b1v[4];
#pragma unroll
        for (int n = 0; n < 4; n++) b1v[n] = b1_g[t * HK + n * 16 + lm];

        // ---- phase A: zst[k][e] = (xs . win^T)^T; also S_all[k] ----
        {
            bfrag wb[4];
#pragma unroll
            for (int ks = 0; ks < 4; ks++)
                wb[ks] = ldf_frag(win_g + (size_t)(t * KD + w * 16 + lm) * ED + ks * 32 + lq * 8);
            f32x4 c[2];
            c[0] = (f32x4){0.f, 0.f, 0.f, 0.f};
            c[1] = (f32x4){0.f, 0.f, 0.f, 0.f};
#pragma unroll
            for (int m = 0; m < 2; m++)
#pragma unroll
                for (int ks = 0; ks < 4; ks++) {
                    bfrag a = *(const bfrag*)&xz[(m * 16 + lm) * AST + ks * 32 + lq * 8];
                    c[m] = MFMA(a, wb[ks], c[m]);
                }
            // transposed pack: lane owns k=w*16+lm, rows m*16+lq*4..+3 -> b64
            u32x2 dd0, dd1;
            dd0.x = pk2(c[0][0], c[0][1]);
            dd0.y = pk2(c[0][2], c[0][3]);
            dd1.x = pk2(c[1][0], c[1][1]);
            dd1.y = pk2(c[1][2], c[1][3]);
            *(u32x2*)&zst[(w * 16 + lm) * ZJST + lq * 4] = dd0;
            *(u32x2*)&zst[(w * 16 + lm) * ZJST + 16 + lq * 4] = dd1;
            // S_all[k]: sum of the PACKED (rounded) values -> exact match with
            // what the consume step reads; butterfly over quads; + nuc cols.
            float s = __uint_as_float(dd0.x << 16) + __uint_as_float(dd0.x & 0xffff0000u)
                    + __uint_as_float(dd0.y << 16) + __uint_as_float(dd0.y & 0xffff0000u)
                    + __uint_as_float(dd1.x << 16) + __uint_as_float(dd1.x & 0xffff0000u)
                    + __uint_as_float(dd1.y << 16) + __uint_as_float(dd1.y & 0xffff0000u);
            s += __shfl_xor(s, 16, 64);
            s += __shfl_xor(s, 32, 64);
            u32x2 nd = *(const u32x2*)&zst[(w * 16 + lm) * ZJST + 32]; // nuc, init-stable
            s += __uint_as_float(nd.x << 16) + __uint_as_float(nd.x & 0xffff0000u)
               + __uint_as_float(nd.y << 16) + __uint_as_float(nd.y & 0xffff0000u);
            if (lq == 0) sall[w * 16 + lm] = s;
        }
        __syncthreads();

        // ---- pair loop: wave w owns e = 4w..4w+3 ----
        // tiles: 1 shared nuc tile (rows = 4e x 4j, j=32..35) + per-e 2 tiles
        {
            u16* hb = arena + w * (16 * HBS); // wave-private H transpose buffer
            float4 a0, a1, b0, b1;            // parity double-buffer (db)
            const f32x4 zq = (f32x4){0.f, 0.f, 0.f, 0.f}; // shared GEMM2 C-in

            // tile body: GEMM1 -> ssp -> transpose -> GEMM2 -> masked consume.
            // jc = this lane's zst column base (b64 covers 4 rows of this tile).
            // kmA/kmC mask r=0,2 (lo16<<16); kmB/kmD pre-ANDed with 0xFFFF0000.
            // NO bias here: b2*(S_all - zs[e]) is added in the le-epilogue.
            auto tile_g12 = [&](bfrag ad, int jc, u32 kmA, u32 kmB, u32 kmC,
                                u32 kmD, float* acc) {
                f32x4 c1[4];
#pragma unroll
                for (int n = 0; n < 4; n++) {
                    bfrag w1f = *(const bfrag*)&w1x[(n * 64 + l) * 8];
                    f32x4 ci = (f32x4){b1v[n], b1v[n], b1v[n], b1v[n]};
                    c1[n] = MFMA(ad, w1f, ci);
                }
#pragma unroll
                for (int n = 0; n < 4; n++) {
                    u32 p01 = pk2(ssp_f(c1[n][0]), ssp_f(c1[n][1]));
                    u32 p23 = pk2(ssp_f(c1[n][2]), ssp_f(c1[n][3]));
                    hb[(lq * 4 + 0) * HBS + n * 16 + lm] = (u16)p01;
                    hb[(lq * 4 + 1) * HBS + n * 16 + lm] = (u16)(p01 >> 16);
                    hb[(lq * 4 + 2) * HBS + n * 16 + lm] = (u16)p23;
                    hb[(lq * 4 + 3) * HBS + n * 16 + lm] = (u16)(p23 >> 16);
                }
                bfrag a20 = *(const bfrag*)&hb[lm * HBS + lq * 8];
                bfrag a21 = *(const bfrag*)&hb[lm * HBS + 32 + lq * 8];
                __builtin_amdgcn_sched_barrier(0);
                // GEMM2 + consume, fenced every 4 n (spill-free regime)
#pragma unroll
                for (int g = 0; g < 2; g++) {
#pragma unroll
                    for (int nn = 0; nn < 4; nn++) {
                        const int n = g * 4 + nn;
                        bfrag wf0 = *(const bfrag*)&w2x[(n * 128 + l) * 8];
                        bfrag wf1 = *(const bfrag*)&w2x[(n * 128 + 64 + l) * 8];
                        f32x4 c2 = MFMA(a20, wf0, zq);
                        c2 = MFMA(a21, wf1, c2);
                        u32x2 zd = *(const u32x2*)&zst[(n * 16 + lm) * ZJST + jc];
                        acc[n] = fmaf(c2[0], __uint_as_float((zd.x << 16) & kmA), acc[n]);
                        acc[n] = fmaf(c2[1], __uint_as_float(zd.x & kmB), acc[n]);
                        acc[n] = fmaf(c2[2], __uint_as_float((zd.y << 16) & kmC), acc[n]);
                        acc[n] = fmaf(c2[3], __uint_as_float(zd.y & kmD), acc[n]);
                    }
                    __builtin_amdgcn_sched_barrier(0);
                }
            };

            // ---- nuc tile: load -> a; prefetch (le0,T0) -> b; znuc -> xz ----
            {
                {
                    int e0 = w * 4 + (lm >> 2), j0 = 32 + (lm & 3);
                    const float* p = db_g + ((size_t)(b * NE + e0) * NA + j0) * BAS + lq * 8;
                    a0 = *(const float4*)p;
                    a1 = *(const float4*)(p + 4);
                }
                {
                    const float* p = db_g + ((size_t)(b * NE + w * 4) * NA + lm) * BAS + lq * 8;
                    b0 = *(const float4*)p;
                    b1 = *(const float4*)(p + 4);
                }
                float znuc[8] = {0.f, 0.f, 0.f, 0.f, 0.f, 0.f, 0.f, 0.f};
                // consume cols 32..35 for ALL quads (row r <-> j=32+r); no diag
                tile_g12(cvt8(a0, a1), 32, ~0u, 0xFFFF0000u, ~0u, 0xFFFF0000u, znuc);
                // lane (lq,lm) holds nuc-sum for e=w*4+lq, k=n*16+lm: park in xz
                int e0 = w * 4 + lq;
#pragma unroll
                for (int n = 0; n < 8; n += 2) {
                    u32 pk = pk2(znuc[n], znuc[n + 1]);
                    xz[e0 * AST + n * 16 + lm] = (u16)pk;
                    xz[e0 * AST + (n + 1) * 16 + lm] = (u16)(pk >> 16);
                }
            }

#pragma unroll 1
            for (int le = 0; le < 4; le++) {
                const int e = w * 4 + le;
                float zreg[8] = {0.f, 0.f, 0.f, 0.f, 0.f, 0.f, 0.f, 0.f};
                // T=0: prefetch (le,T=1) -> a; consume b
                {
                    const float* p = db_g + ((size_t)(b * NE + e) * NA + 16 + lm) * BAS + lq * 8;
                    a0 = *(const float4*)p;
                    a1 = *(const float4*)(p + 4);
                }
                {
                    int lp0 = lq * 4;
                    u32 k0 = (lp0 + 0 == e) ? 0u : ~0u;
                    u32 k1 = (lp0 + 1 == e) ? 0u : ~0u;
                    u32 k2 = (lp0 + 2 == e) ? 0u : ~0u;
                    u32 k3 = (lp0 + 3 == e) ? 0u : ~0u;
                    tile_g12(cvt8(b0, b1), lp0, k0, k1 & 0xFFFF0000u,
                             k2, k3 & 0xFFFF0000u, zreg);
                }
                // T=1: prefetch (le+1,T=0) -> b (clamped dummy at end); consume a
                {
                    int nle = (le < 3) ? le + 1 : 3;
                    const float* p = db_g + ((size_t)(b * NE + w * 4 + nle) * NA + lm) * BAS + lq * 8;
                    b0 = *(const float4*)p;
                    b1 = *(const float4*)(p + 4);
                }
                {
                    int lp0 = 16 + lq * 4;
                    u32 k0 = (lp0 + 0 == e) ? 0u : ~0u;
                    u32 k1 = (lp0 + 1 == e) ? 0u : ~0u;
                    u32 k2 = (lp0 + 2 == e) ? 0u : ~0u;
                    u32 k3 = (lp0 + 3 == e) ? 0u : ~0u;
                    tile_g12(cvt8(a0, a1), lp0, k0, k1 & 0xFFFF0000u,
                             k2, k3 & 0xFFFF0000u, zreg);
                }
                // butterfly over quads; lanes lq==le add parked nuc + bias term
#pragma unroll
                for (int n = 0; n < 8; n++) {
                    float v = zreg[n];
                    v += __shfl_xor(v, 16, 64);
                    v += __shfl_xor(v, 32, 64);
                    zreg[n] = v;
                }
                if (lq == le) {
#pragma unroll
                    for (int n = 0; n < 8; n += 2) {
                        int k0 = n * 16 + lm, k1 = (n + 1) * 16 + lm;
                        float o0 = bf2f(xz[e * AST + k0]);            // parked nuc
                        float o1 = bf2f(xz[e * AST + k1]);
                        float ze0 = bf2f(zst[k0 * ZJST + e]);         // zs[e][k]
                        float ze1 = bf2f(zst[k1 * ZJST + e]);
                        float t0 = zreg[n] + o0 + bb2[k0] * (sall[k0] - ze0);
                        float t1 = zreg[n + 1] + o1 + bb2[k1] * (sall[k1] - ze1);
                        u32 pk = pk2(t0, t1);
                        xz[e * AST + k0] = (u16)pk;
                        xz[e * AST + k1] = (u16)(pk >> 16);
                    }
                }
            }
        }
        __syncthreads();

        // ---- D1: h2 = ssp(z . wo1^T + bo1)  (M=32,N=128,K=128) ----
        {
            bfrag wb[4];
#pragma unroll
            for (int ks = 0; ks < 4; ks++)
                wb[ks] = ldf_frag(wo1_g + (size_t)(t * HO + w * 16 + lm) * KD + ks * 32 + lq * 8);
            float bo1v = bo1_g[t * HO + w * 16 + lm];
            f32x4 c[2];
            c[0] = (f32x4){bo1v, bo1v, bo1v, bo1v};
            c[1] = (f32x4){bo1v, bo1v, bo1v, bo1v};
#pragma unroll
            for (int m = 0; m < 2; m++)
#pragma unroll
                for (int ks = 0; ks < 4; ks++) {
                    bfrag a = *(const bfrag*)&xz[(m * 16 + lm) * AST + ks * 32 + lq * 8];
                    c[m] = MFMA(a, wb[ks], c[m]);
                }
#pragma unroll
            for (int m = 0; m < 2; m++) {
                u32 p01 = pk2(ssp_f(c[m][0]), ssp_f(c[m][1]));
                u32 p23 = pk2(ssp_f(c[m][2]), ssp_f(c[m][3]));
                h2b[(m * 16 + lq * 4 + 0) * AST + w * 16 + lm] = (u16)p01;
                h2b[(m * 16 + lq * 4 + 1) * AST + w * 16 + lm] = (u16)(p01 >> 16);
                h2b[(m * 16 + lq * 4 + 2) * AST + w * 16 + lm] = (u16)p23;
                h2b[(m * 16 + lq * 4 + 3) * AST + w * 16 + lm] = (u16)(p23 >> 16);
            }
        }
        __syncthreads();

        // ---- D2: xs += h2 . wo2^T + bo2; refresh bf16 mirror xz ----
        {
            bfrag wb[4];
#pragma unroll
            for (int ks = 0; ks < 4; ks++)
                wb[ks] = ldf_frag(wo2_g + (size_t)(t * ED + w * 16 + lm) * HO + ks * 32 + lq * 8);
            float bo2v = bo2_g[t * ED + w * 16 + lm];
            f32x4 c[2];
            c[0] = (f32x4){bo2v, bo2v, bo2v, bo2v};
            c[1] = (f32x4){bo2v, bo2v, bo2v, bo2v};
#pragma unroll
            for (int m = 0; m < 2; m++)
#pragma unroll
                for (int ks = 0; ks < 4; ks++) {
                    bfrag a = *(const bfrag*)&h2b[(m * 16 + lm) * AST + ks * 32 + lq * 8];
                    c[m] = MFMA(a, wb[ks], c[m]);
                }
#pragma unroll
            for (int m = 0; m < 2; m++) {
                float nv[4];
#pragma unroll
                for (int r = 0; r < 4; r++) {
                    int row = m * 16 + lq * 4 + r, col = w * 16 + lm;
                    nv[r] = xs[row * XST + col] + c[m][r];
                    xs[row * XST + col] = nv[r];
                }
                u32 p01 = pk2(nv[0], nv[1]);
                u32 p23 = pk2(nv[2], nv[3]);
                xz[(m * 16 + lq * 4 + 0) * AST + w * 16 + lm] = (u16)p01;
                xz[(m * 16 + lq * 4 + 1) * AST + w * 16 + lm] = (u16)(p01 >> 16);
                xz[(m * 16 + lq * 4 + 2) * AST + w * 16 + lm] = (u16)p23;
                xz[(m * 16 + lq * 4 + 3) * AST + w * 16 + lm] = (u16)(p23 >> 16);
            }
        }
        __syncthreads();
    }

    // ---- write out (f32, coalesced float4) ----
#pragma unroll
    for (int ii = 0; ii < 2; ii++) {
        int idx = (ii * 512 + tid) * 4;
        int row = idx >> 7, col = idx & 127;
        *(float4*)&out_g[(size_t)b * (NE * ED) + idx] = *(const float4*)&xs[row * XST + col];
    }
}

extern "C" void kernel_launch(void* const* d_in, const int* in_sizes, int n_in,
                              void* d_out, int out_size, void* d_ws, size_t ws_size,
                              hipStream_t stream) {
    schnet_mfma<<<NBATCH, 512, 0, stream>>>(
        (const float*)d_in[0], (const float*)d_in[1], (const float*)d_in[2],
        (const float*)d_in[3], (const float*)d_in[4], (const float*)d_in[5],
        (const float*)d_in[6], (const float*)d_in[7], (const float*)d_in[8],
        (const float*)d_in[9], (const float*)d_in[10], (const float*)d_in[11],
        (float*)d_out);
}

// Round 10
// 236.098 us; speedup vs baseline: 5.6927x; 1.0269x over previous
//
#include <hip/hip_runtime.h>
#include <hip/hip_bf16.h>
#include <stdint.h>

#define NBATCH 512
#define NE 32
#define NA 36
#define BAS 32
#define KD 128
#define ED 128
#define HK 64
#define HO 128
#define NT 3

#define XST 132   // xs f32 stride: 4-bank row skew
#define AST 136   // xz (xs-mirror/zacc alias) + h2b stride (u16): 272B rows, 16B-aligned
#define ZJST 36   // zst[k][j] inner stride (u16): 72B rows -> 8B-aligned b64 slots
#define HBS 72    // per-wave H-transpose stride (u16)

typedef uint16_t u16;
typedef uint32_t u32;
using bfrag = __attribute__((ext_vector_type(8))) short;  // 8 bf16 = 4 VGPRs
using f32x4 = __attribute__((ext_vector_type(4))) float;
using u32x2 = __attribute__((ext_vector_type(2))) unsigned int;

#define MFMA(a, b, c) __builtin_amdgcn_mfma_f32_16x16x32_bf16(a, b, c, 0, 0, 0)

// f32 -> bf16 RNE via the compiler's cast path (m240: the fast path).
// NO inline asm anywhere (R4's hand-written cvt_pk asm silently corrupted).
__device__ __forceinline__ short ftob(float f) {
    union { __hip_bfloat16 h; short s; } u;
    u.h = __float2bfloat16(f);
    return u.s;
}
// pack two f32 -> (bf16 hi)<<16 | bf16 lo
__device__ __forceinline__ u32 pk2(float lo, float hi) {
    return ((u32)(u16)ftob(hi) << 16) | (u32)(u16)ftob(lo);
}
__device__ __forceinline__ float bf2f(u16 u) {
    return __uint_as_float(((u32)u) << 16);
}
__device__ __forceinline__ bfrag cvt8(float4 a, float4 c) {
    bfrag r;
    r[0] = ftob(a.x); r[1] = ftob(a.y); r[2] = ftob(a.z); r[3] = ftob(a.w);
    r[4] = ftob(c.x); r[5] = ftob(c.y); r[6] = ftob(c.z); r[7] = ftob(c.w);
    return r;
}
__device__ __forceinline__ bfrag ldf_frag(const float* p) {
    float4 a = *(const float4*)p;
    float4 c = *(const float4*)(p + 4);
    return cvt8(a, c);
}
// softplus(x) - log(2) = log((1+e^x)/2), 5 VALU ops (kept from R9; pure math,
// deterministic, verified on R9's first-launch check).
// Overflow only at x > 88 (pre-activations are ~|30| max). x->-inf: log(0.5) ok.
__device__ __forceinline__ float sspv(float x) {
    return __logf(fmaf(__expf(x), 0.5f, 0.5f));
}

// One block per batch element; 512 threads = 8 waves.
// Frag conventions (guide §3, m89/m91-verified):
//   A: lane&15 = m, (lane>>4)*8+j = k   |  B: lane&15 = n, (lane>>4)*8+j = k
//   C/D: col = lane&15 (n), row = (lane>>4)*4 + reg (m)
//
// Structure (R8, proven): zs TRANSPOSED zst[k][j]; consume = b64 read per n +
// AND-masks zeroing j==e. Nuc contribution = ONE shared 16-row tile per wave
// (p=lm <-> e=w*4+p/4, j=32+p%4) -> 9 tiles/wave. Bias-sum trick: GEMM2 bias
// applied as b2*(S_all - zs[e]) in the le-epilogue. GEMM2 C-in = zero quad.
//
// R10: REVERTED R9's swapped-GEMM1 + u32-packed hbw transpose. R9 passed the
// first-launch check but DIVERGED after warm-up replays (post-timing absmax
// 0.469): timing-dependent behavior traced to the only changed barrier-free
// LDS dataflow -- u32x2 stores read back as short8 (TBAA-incompatible types;
// compiler may reorder). R8's u16-store/short8-load transpose (signed/unsigned
// same width = compatible) was stable for 4 rounds; restored verbatim.
// Kept from R9: 5-op sspv only.
__global__ __launch_bounds__(512, 4) void schnet_mfma(
    const float* __restrict__ db_g,   // dists_basis (512,32,36,32)
    const float* __restrict__ ee_g,   // embedding_elec (32,128)
    const float* __restrict__ en_g,   // embedding_nuc (4,128)
    const float* __restrict__ w1_g,   // kernel_w1 (3,64,32)
    const float* __restrict__ b1_g,   // kernel_b1 (3,64)
    const float* __restrict__ w2_g,   // kernel_w2 (3,128,64)
    const float* __restrict__ b2_g,   // kernel_b2 (3,128)
    const float* __restrict__ win_g,  // embed_in_w (3,128,128)
    const float* __restrict__ wo1_g,  // embed_out_w1 (3,128,128)
    const float* __restrict__ bo1_g,  // embed_out_b1 (3,128)
    const float* __restrict__ wo2_g,  // embed_out_w2 (3,128,128)
    const float* __restrict__ bo2_g,  // embed_out_b2 (3,128)
    float* __restrict__ out_g)        // (512,32,128) f32
{
    __shared__ __align__(16) float xs[NE * XST];      // residual, f32 (16.9 KB)
    __shared__ __align__(16) u16 xz[NE * AST];        // xs bf16 mirror | zacc (8.7 KB)
    __shared__ __align__(16) u16 zst[KD * ZJST];      // zs TRANSPOSED [k][j] (9.2 KB)
    __shared__ __align__(16) u16 arena[8 * 16 * HBS]; // hb | h2b (18.4 KB)
    __shared__ __align__(16) u16 w2x[8 * 2 * 64 * 8]; // w2 frag-linear (16 KB)
    __shared__ __align__(16) u16 w1x[4 * 64 * 8];     // w1 frag-linear (4 KB)
    __shared__ __align__(16) float bb2[KD];           // b2 bias (512 B)
    __shared__ __align__(16) float sall[KD];          // S_all[k] (512 B)
    u16* h2b = arena;                                 // 32*AST = 8.7KB <= arena
    // total LDS ~74.7 KB -> 2 blocks/CU

    const int tid = threadIdx.x;
    const int b = blockIdx.x;
    const int w = tid >> 6;   // wave 0..7
    const int l = tid & 63;
    const int lm = l & 15;    // m/n lane index
    const int lq = l >> 4;    // quad 0..3

    // ---- init: xs/xz <- embedding_elec; zst nuc cols <- embedding_nuc ----
    {
        int idx = tid * 8;
        float4 v0 = *(const float4*)(ee_g + idx);
        float4 v1 = *(const float4*)(ee_g + idx + 4);
        int row = idx >> 7, col = idx & 127;
        *(float4*)&xs[row * XST + col] = v0;
        *(float4*)&xs[row * XST + col + 4] = v1;
        *(bfrag*)&xz[row * AST + col] = cvt8(v0, v1);
    }
    {
        int k = tid & 127, rr = tid >> 7;  // 512 threads = 128k x 4rr
        zst[k * ZJST + 32 + rr] = (u16)ftob(en_g[rr * 128 + k]);
    }
    __syncthreads();

    for (int t = 0; t < NT; t++) {
        // ---- stage w2 + w1 + b2 -> LDS (consumed after next barrier) ----
#pragma unroll
        for (int uu = 0; uu < 2; uu++) {
            int u = tid + uu * 512;
            int n = u >> 7, s = (u >> 6) & 1, lane = u & 63;
            int lmm = lane & 15, lqq = lane >> 4;
            const float* p = w2_g + (size_t)(t * KD + n * 16 + lmm) * HK + s * 32 + lqq * 8;
            *(bfrag*)&w2x[u * 8] = ldf_frag(p);
        }
        if (tid < 256) {
            int n = tid >> 6, lane = tid & 63;
            const float* p = w1_g + (size_t)(t * HK + n * 16 + (lane & 15)) * BAS
                             + ((lane >> 4) & 3) * 8;
            *(bfrag*)&w1x[tid * 8] = ldf_frag(p);
        } else if (tid < 384) {
            bb2[tid - 256] = b2_g[t * KD + tid - 256];
        }

        // ---- per-t small weights (registers) ----
        float b1v[4];
#pragma unroll
        for (int n = 0; n < 4; n++) b1v[n] = b1_g[t * HK + n * 16 + lm];

        // ---- phase A: zst[k][e] = (xs . win^T)^T; also S_all[k] ----
        {
            bfrag wb[4];
#pragma unroll
            for (int ks = 0; ks < 4; ks++)
                wb[ks] = ldf_frag(win_g + (size_t)(t * KD + w * 16 + lm) * ED + ks * 32 + lq * 8);
            f32x4 c[2];
            c[0] = (f32x4){0.f, 0.f, 0.f, 0.f};
            c[1] = (f32x4){0.f, 0.f, 0.f, 0.f};
#pragma unroll
            for (int m = 0; m < 2; m++)
#pragma unroll
                for (int ks = 0; ks < 4; ks++) {
                    bfrag a = *(const bfrag*)&xz[(m * 16 + lm) * AST + ks * 32 + lq * 8];
                    c[m] = MFMA(a, wb[ks], c[m]);
                }
            // transposed pack: lane owns k=w*16+lm, rows m*16+lq*4..+3 -> b64
            u32x2 dd0, dd1;
            dd0.x = pk2(c[0][0], c[0][1]);
            dd0.y = pk2(c[0][2], c[0][3]);
            dd1.x = pk2(c[1][0], c[1][1]);
            dd1.y = pk2(c[1][2], c[1][3]);
            *(u32x2*)&zst[(w * 16 + lm) * ZJST + lq * 4] = dd0;
            *(u32x2*)&zst[(w * 16 + lm) * ZJST + 16 + lq * 4] = dd1;
            // S_all[k]: sum of the PACKED (rounded) values -> exact match with
            // what the consume step reads; butterfly over quads; + nuc cols.
            float s = __uint_as_float(dd0.x << 16) + __uint_as_float(dd0.x & 0xffff0000u)
                    + __uint_as_float(dd0.y << 16) + __uint_as_float(dd0.y & 0xffff0000u)
                    + __uint_as_float(dd1.x << 16) + __uint_as_float(dd1.x & 0xffff0000u)
                    + __uint_as_float(dd1.y << 16) + __uint_as_float(dd1.y & 0xffff0000u);
            s += __shfl_xor(s, 16, 64);
            s += __shfl_xor(s, 32, 64);
            u32x2 nd = *(const u32x2*)&zst[(w * 16 + lm) * ZJST + 32]; // nuc, init-stable
            s += __uint_as_float(nd.x << 16) + __uint_as_float(nd.x & 0xffff0000u)
               + __uint_as_float(nd.y << 16) + __uint_as_float(nd.y & 0xffff0000u);
            if (lq == 0) sall[w * 16 + lm] = s;
        }
        __syncthreads();

        // ---- pair loop: wave w owns e = 4w..4w+3 ----
        // tiles: 1 shared nuc tile (rows = 4e x 4j, j=32..35) + per-e 2 tiles
        {
            u16* hb = arena + w * (16 * HBS); // wave-private H transpose buffer
            float4 a0, a1, b0, b1;            // parity double-buffer (db)
            const f32x4 zq = (f32x4){0.f, 0.f, 0.f, 0.f}; // shared GEMM2 C-in

            // tile body: GEMM1 -> ssp -> transpose -> GEMM2 -> masked consume.
            // jc = this lane's zst column base (b64 covers 4 rows of this tile).
            // kmA/kmC mask r=0,2 (lo16<<16); kmB/kmD pre-ANDed with 0xFFFF0000.
            // NO bias here: b2*(S_all - zs[e]) is added in the le-epilogue.
            auto tile_g12 = [&](bfrag ad, int jc, u32 kmA, u32 kmB, u32 kmC,
                                u32 kmD, float* acc) {
                f32x4 c1[4];
#pragma unroll
                for (int n = 0; n < 4; n++) {
                    bfrag w1f = *(const bfrag*)&w1x[(n * 64 + l) * 8];
                    f32x4 ci = (f32x4){b1v[n], b1v[n], b1v[n], b1v[n]};
                    c1[n] = MFMA(ad, w1f, ci);
                }
#pragma unroll
                for (int n = 0; n < 4; n++) {
                    u32 p01 = pk2(sspv(c1[n][0]), sspv(c1[n][1]));
                    u32 p23 = pk2(sspv(c1[n][2]), sspv(c1[n][3]));
                    hb[(lq * 4 + 0) * HBS + n * 16 + lm] = (u16)p01;
                    hb[(lq * 4 + 1) * HBS + n * 16 + lm] = (u16)(p01 >> 16);
                    hb[(lq * 4 + 2) * HBS + n * 16 + lm] = (u16)p23;
                    hb[(lq * 4 + 3) * HBS + n * 16 + lm] = (u16)(p23 >> 16);
                }
                bfrag a20 = *(const bfrag*)&hb[lm * HBS + lq * 8];
                bfrag a21 = *(const bfrag*)&hb[lm * HBS + 32 + lq * 8];
                __builtin_amdgcn_sched_barrier(0);
                // GEMM2 + consume, fenced every 4 n (spill-free regime)
#pragma unroll
                for (int g = 0; g < 2; g++) {
#pragma unroll
                    for (int nn = 0; nn < 4; nn++) {
                        const int n = g * 4 + nn;
                        bfrag wf0 = *(const bfrag*)&w2x[(n * 128 + l) * 8];
                        bfrag wf1 = *(const bfrag*)&w2x[(n * 128 + 64 + l) * 8];
                        f32x4 c2 = MFMA(a20, wf0, zq);
                        c2 = MFMA(a21, wf1, c2);
                        u32x2 zd = *(const u32x2*)&zst[(n * 16 + lm) * ZJST + jc];
                        acc[n] = fmaf(c2[0], __uint_as_float((zd.x << 16) & kmA), acc[n]);
                        acc[n] = fmaf(c2[1], __uint_as_float(zd.x & kmB), acc[n]);
                        acc[n] = fmaf(c2[2], __uint_as_float((zd.y << 16) & kmC), acc[n]);
                        acc[n] = fmaf(c2[3], __uint_as_float(zd.y & kmD), acc[n]);
                    }
                    __builtin_amdgcn_sched_barrier(0);
                }
            };

            // ---- nuc tile: load -> a; prefetch (le0,T0) -> b; znuc -> xz ----
            {
                {
                    int e0 = w * 4 + (lm >> 2), j0 = 32 + (lm & 3);
                    const float* p = db_g + ((size_t)(b * NE + e0) * NA + j0) * BAS + lq * 8;
                    a0 = *(const float4*)p;
                    a1 = *(const float4*)(p + 4);
                }
                {
                    const float* p = db_g + ((size_t)(b * NE + w * 4) * NA + lm) * BAS + lq * 8;
                    b0 = *(const float4*)p;
                    b1 = *(const float4*)(p + 4);
                }
                float znuc[8] = {0.f, 0.f, 0.f, 0.f, 0.f, 0.f, 0.f, 0.f};
                // consume cols 32..35 for ALL quads (row r <-> j=32+r); no diag
                tile_g12(cvt8(a0, a1), 32, ~0u, 0xFFFF0000u, ~0u, 0xFFFF0000u, znuc);
                // lane (lq,lm) holds nuc-sum for e=w*4+lq, k=n*16+lm: park in xz
                int e0 = w * 4 + lq;
#pragma unroll
                for (int n = 0; n < 8; n += 2) {
                    u32 pk = pk2(znuc[n], znuc[n + 1]);
                    xz[e0 * AST + n * 16 + lm] = (u16)pk;
                    xz[e0 * AST + (n + 1) * 16 + lm] = (u16)(pk >> 16);
                }
            }

#pragma unroll 1
            for (int le = 0; le < 4; le++) {
                const int e = w * 4 + le;
                float zreg[8] = {0.f, 0.f, 0.f, 0.f, 0.f, 0.f, 0.f, 0.f};
                // T=0: prefetch (le,T=1) -> a; consume b
                {
                    const float* p = db_g + ((size_t)(b * NE + e) * NA + 16 + lm) * BAS + lq * 8;
                    a0 = *(const float4*)p;
                    a1 = *(const float4*)(p + 4);
                }
                {
                    int lp0 = lq * 4;
                    u32 k0 = (lp0 + 0 == e) ? 0u : ~0u;
                    u32 k1 = (lp0 + 1 == e) ? 0u : ~0u;
                    u32 k2 = (lp0 + 2 == e) ? 0u : ~0u;
                    u32 k3 = (lp0 + 3 == e) ? 0u : ~0u;
                    tile_g12(cvt8(b0, b1), lp0, k0, k1 & 0xFFFF0000u,
                             k2, k3 & 0xFFFF0000u, zreg);
                }
                // T=1: prefetch (le+1,T=0) -> b (clamped dummy at end); consume a
                {
                    int nle = (le < 3) ? le + 1 : 3;
                    const float* p = db_g + ((size_t)(b * NE + w * 4 + nle) * NA + lm) * BAS + lq * 8;
                    b0 = *(const float4*)p;
                    b1 = *(const float4*)(p + 4);
                }
                {
                    int lp0 = 16 + lq * 4;
                    u32 k0 = (lp0 + 0 == e) ? 0u : ~0u;
                    u32 k1 = (lp0 + 1 == e) ? 0u : ~0u;
                    u32 k2 = (lp0 + 2 == e) ? 0u : ~0u;
                    u32 k3 = (lp0 + 3 == e) ? 0u : ~0u;
                    tile_g12(cvt8(a0, a1), lp0, k0, k1 & 0xFFFF0000u,
                             k2, k3 & 0xFFFF0000u, zreg);
                }
                // butterfly over quads; lanes lq==le add parked nuc + bias term
#pragma unroll
                for (int n = 0; n < 8; n++) {
                    float v = zreg[n];
                    v += __shfl_xor(v, 16, 64);
                    v += __shfl_xor(v, 32, 64);
                    zreg[n] = v;
                }
                if (lq == le) {
#pragma unroll
                    for (int n = 0; n < 8; n += 2) {
                        int k0 = n * 16 + lm, k1 = (n + 1) * 16 + lm;
                        float o0 = bf2f(xz[e * AST + k0]);            // parked nuc
                        float o1 = bf2f(xz[e * AST + k1]);
                        float ze0 = bf2f(zst[k0 * ZJST + e]);         // zs[e][k]
                        float ze1 = bf2f(zst[k1 * ZJST + e]);
                        float t0 = zreg[n] + o0 + bb2[k0] * (sall[k0] - ze0);
                        float t1 = zreg[n + 1] + o1 + bb2[k1] * (sall[k1] - ze1);
                        u32 pk = pk2(t0, t1);
                        xz[e * AST + k0] = (u16)pk;
                        xz[e * AST + k1] = (u16)(pk >> 16);
                    }
                }
            }
        }
        __syncthreads();

        // ---- D1: h2 = ssp(z . wo1^T + bo1)  (M=32,N=128,K=128) ----
        {
            bfrag wb[4];
#pragma unroll
            for (int ks = 0; ks < 4; ks++)
                wb[ks] = ldf_frag(wo1_g + (size_t)(t * HO + w * 16 + lm) * KD + ks * 32 + lq * 8);
            float bo1v = bo1_g[t * HO + w * 16 + lm];
            f32x4 c[2];
            c[0] = (f32x4){bo1v, bo1v, bo1v, bo1v};
            c[1] = (f32x4){bo1v, bo1v, bo1v, bo1v};
#pragma unroll
            for (int m = 0; m < 2; m++)
#pragma unroll
                for (int ks = 0; ks < 4; ks++) {
                    bfrag a = *(const bfrag*)&xz[(m * 16 + lm) * AST + ks * 32 + lq * 8];
                    c[m] = MFMA(a, wb[ks], c[m]);
                }
#pragma unroll
            for (int m = 0; m < 2; m++) {
                u32 p01 = pk2(sspv(c[m][0]), sspv(c[m][1]));
                u32 p23 = pk2(sspv(c[m][2]), sspv(c[m][3]));
                h2b[(m * 16 + lq * 4 + 0) * AST + w * 16 + lm] = (u16)p01;
                h2b[(m * 16 + lq * 4 + 1) * AST + w * 16 + lm] = (u16)(p01 >> 16);
                h2b[(m * 16 + lq * 4 + 2) * AST + w * 16 + lm] = (u16)p23;
                h2b[(m * 16 + lq * 4 + 3) * AST + w * 16 + lm] = (u16)(p23 >> 16);
            }
        }
        __syncthreads();

        // ---- D2: xs += h2 . wo2^T + bo2; refresh bf16 mirror xz ----
        {
            bfrag wb[4];
#pragma unroll
            for (int ks = 0; ks < 4; ks++)
                wb[ks] = ldf_frag(wo2_g + (size_t)(t * ED + w * 16 + lm) * HO + ks * 32 + lq * 8);
            float bo2v = bo2_g[t * ED + w * 16 + lm];
            f32x4 c[2];
            c[0] = (f32x4){bo2v, bo2v, bo2v, bo2v};
            c[1] = (f32x4){bo2v, bo2v, bo2v, bo2v};
#pragma unroll
            for (int m = 0; m < 2; m++)
#pragma unroll
                for (int ks = 0; ks < 4; ks++) {
                    bfrag a = *(const bfrag*)&h2b[(m * 16 + lm) * AST + ks * 32 + lq * 8];
                    c[m] = MFMA(a, wb[ks], c[m]);
                }
#pragma unroll
            for (int m = 0; m < 2; m++) {
                float nv[4];
#pragma unroll
                for (int r = 0; r < 4; r++) {
                    int row = m * 16 + lq * 4 + r, col = w * 16 + lm;
                    nv[r] = xs[row * XST + col] + c[m][r];
                    xs[row * XST + col] = nv[r];
                }
                u32 p01 = pk2(nv[0], nv[1]);
                u32 p23 = pk2(nv[2], nv[3]);
                xz[(m * 16 + lq * 4 + 0) * AST + w * 16 + lm] = (u16)p01;
                xz[(m * 16 + lq * 4 + 1) * AST + w * 16 + lm] = (u16)(p01 >> 16);
                xz[(m * 16 + lq * 4 + 2) * AST + w * 16 + lm] = (u16)p23;
                xz[(m * 16 + lq * 4 + 3) * AST + w * 16 + lm] = (u16)(p23 >> 16);
            }
        }
        __syncthreads();
    }

    // ---- write out (f32, coalesced float4) ----
#pragma unroll
    for (int ii = 0; ii < 2; ii++) {
        int idx = (ii * 512 + tid) * 4;
        int row = idx >> 7, col = idx & 127;
        *(float4*)&out_g[(size_t)b * (NE * ED) + idx] = *(const float4*)&xs[row * XST + col];
    }
}

extern "C" void kernel_launch(void* const* d_in, const int* in_sizes, int n_in,
                              void* d_out, int out_size, void* d_ws, size_t ws_size,
                              hipStream_t stream) {
    schnet_mfma<<<NBATCH, 512, 0, stream>>>(
        (const float*)d_in[0], (const float*)d_in[1], (const float*)d_in[2],
        (const float*)d_in[3], (const float*)d_in[4], (const float*)d_in[5],
        (const float*)d_in[6], (const float*)d_in[7], (const float*)d_in[8],
        (const float*)d_in[9], (const float*)d_in[10], (const float*)d_in[11],
        (float*)d_out);
}

// Round 11
// 232.211 us; speedup vs baseline: 5.7880x; 1.0167x over previous
//
#include <hip/hip_runtime.h>
#include <hip/hip_bf16.h>
#include <stdint.h>

#define NBATCH 512
#define NE 32
#define NA 36
#define BAS 32
#define KD 128
#define ED 128
#define HK 64
#define HO 128
#define NT 3

#define XST 132   // xs f32 stride: 4-bank row skew
#define AST 136   // xz (xs-mirror/zacc alias) + h2b stride (u16): 272B rows, 16B-aligned
#define ZJST 36   // zst[k][j] inner stride (u16): 72B rows -> 8B-aligned b64 slots
#define HB2 44    // hbw stride (u32): 176B rows, 16B-aligned b128; bank walk 12*lm

typedef uint16_t u16;
typedef uint32_t u32;
using bfrag = __attribute__((ext_vector_type(8))) short;  // 8 bf16 = 4 VGPRs
using f32x4 = __attribute__((ext_vector_type(4))) float;
using u32x2 = __attribute__((ext_vector_type(2))) unsigned int;
using u32x4 = __attribute__((ext_vector_type(4))) unsigned int;

#define MFMA(a, b, c) __builtin_amdgcn_mfma_f32_16x16x32_bf16(a, b, c, 0, 0, 0)

// f32 -> bf16 RNE via the compiler's cast path (m240: the fast path).
// NO inline asm anywhere (R4's hand-written cvt_pk asm silently corrupted).
__device__ __forceinline__ short ftob(float f) {
    union { __hip_bfloat16 h; short s; } u;
    u.h = __float2bfloat16(f);
    return u.s;
}
// pack two f32 -> (bf16 hi)<<16 | bf16 lo
__device__ __forceinline__ u32 pk2(float lo, float hi) {
    return ((u32)(u16)ftob(hi) << 16) | (u32)(u16)ftob(lo);
}
__device__ __forceinline__ float bf2f(u16 u) {
    return __uint_as_float(((u32)u) << 16);
}
__device__ __forceinline__ bfrag cvt8(float4 a, float4 c) {
    bfrag r;
    r[0] = ftob(a.x); r[1] = ftob(a.y); r[2] = ftob(a.z); r[3] = ftob(a.w);
    r[4] = ftob(c.x); r[5] = ftob(c.y); r[6] = ftob(c.z); r[7] = ftob(c.w);
    return r;
}
__device__ __forceinline__ bfrag ldf_frag(const float* p) {
    float4 a = *(const float4*)p;
    float4 c = *(const float4*)(p + 4);
    return cvt8(a, c);
}
// softplus(x) - log(2) = log((1+e^x)/2), 5 VALU ops.
__device__ __forceinline__ float sspv(float x) {
    return __logf(fmaf(__expf(x), 0.5f, 0.5f));
}

// One block per batch element; 512 threads = 8 waves.
// Frag conventions (guide §3, m89/m91-verified):
//   A: lane&15 = m, (lane>>4)*8+j = k   |  B: lane&15 = n, (lane>>4)*8+j = k
//   C/D: col = lane&15 (n), row = (lane>>4)*4 + reg (m)
//
// Structure: zs TRANSPOSED zst[k][j]; consume = b64 read per n + AND-masks
// zeroing j==e. Nuc contribution = ONE shared 16-row tile per wave -> 9
// tiles/wave. Bias-sum trick: GEMM2 bias = b2*(S_all - zs[e]) in le-epilogue.
//
// R11: swapped-GEMM1 RETRY with the R9 divergence root-caused and fixed.
// R9 evidence: first-launch absmax identical to R8 (math correct); only warm
// replays diverged => ordering hazard. R9's hbw used u32x2 STORES read back
// as short8 (TBAA-incompatible: alias analysis may hoist the loads above the
// stores). Fix: (a) type-consistent u32x2 store / u32x4 read + in-register
// union bitcast to bfrag (no cross-type LDS access); (b) sched_barrier(0)
// between stores and loads. Gains vs R10: 16 ds_write_u16 (4-way conflicted)
// -> 4 ds_write_b64 (~2-way); no hi/lo split shifts; GEMM1 C-in = broadcast
// f32x4 read from bb1 (deletes per-n splat movs).
__global__ __launch_bounds__(512, 4) void schnet_mfma(
    const float* __restrict__ db_g,   // dists_basis (512,32,36,32)
    const float* __restrict__ ee_g,   // embedding_elec (32,128)
    const float* __restrict__ en_g,   // embedding_nuc (4,128)
    const float* __restrict__ w1_g,   // kernel_w1 (3,64,32)
    const float* __restrict__ b1_g,   // kernel_b1 (3,64)
    const float* __restrict__ w2_g,   // kernel_w2 (3,128,64)
    const float* __restrict__ b2_g,   // kernel_b2 (3,128)
    const float* __restrict__ win_g,  // embed_in_w (3,128,128)
    const float* __restrict__ wo1_g,  // embed_out_w1 (3,128,128)
    const float* __restrict__ bo1_g,  // embed_out_b1 (3,128)
    const float* __restrict__ wo2_g,  // embed_out_w2 (3,128,128)
    const float* __restrict__ bo2_g,  // embed_out_b2 (3,128)
    float* __restrict__ out_g)        // (512,32,128) f32
{
    __shared__ __align__(16) float xs[NE * XST];        // residual, f32 (16.9 KB)
    __shared__ __align__(16) u16 xz[NE * AST];          // xs bf16 mirror | zacc (8.7 KB)
    __shared__ __align__(16) u16 zst[KD * ZJST];        // zs TRANSPOSED [k][j] (9.2 KB)
    __shared__ __align__(16) u32 arena32[8 * 16 * HB2]; // hbw | h2b (22.5 KB)
    __shared__ __align__(16) u16 w2x[8 * 2 * 64 * 8];   // w2 frag-linear (16 KB)
    __shared__ __align__(16) u16 w1x[4 * 64 * 8];       // w1 frag-linear (4 KB)
    __shared__ __align__(16) float bb2[KD];             // b2 bias (512 B)
    __shared__ __align__(16) float sall[KD];            // S_all[k] (512 B)
    __shared__ __align__(16) float bb1[HK];             // b1 bias (256 B)
    u16* h2b = (u16*)arena32;                           // 32*AST*2 = 8.7KB <= arena
    // total LDS = 79104 B -> 2 blocks/CU (158.2 KB <= 160 KB)

    const int tid = threadIdx.x;
    const int b = blockIdx.x;
    const int w = tid >> 6;   // wave 0..7
    const int l = tid & 63;
    const int lm = l & 15;    // m/n lane index
    const int lq = l >> 4;    // quad 0..3

    // ---- init: xs/xz <- embedding_elec; zst nuc cols <- embedding_nuc ----
    {
        int idx = tid * 8;
        float4 v0 = *(const float4*)(ee_g + idx);
        float4 v1 = *(const float4*)(ee_g + idx + 4);
        int row = idx >> 7, col = idx & 127;
        *(float4*)&xs[row * XST + col] = v0;
        *(float4*)&xs[row * XST + col + 4] = v1;
        *(bfrag*)&xz[row * AST + col] = cvt8(v0, v1);
    }
    {
        int k = tid & 127, rr = tid >> 7;  // 512 threads = 128k x 4rr
        zst[k * ZJST + 32 + rr] = (u16)ftob(en_g[rr * 128 + k]);
    }
    __syncthreads();

    for (int t = 0; t < NT; t++) {
        // ---- stage w2 + w1 + b2 + b1 -> LDS (consumed after next barrier) ----
#pragma unroll
        for (int uu = 0; uu < 2; uu++) {
            int u = tid + uu * 512;
            int n = u >> 7, s = (u >> 6) & 1, lane = u & 63;
            int lmm = lane & 15, lqq = lane >> 4;
            const float* p = w2_g + (size_t)(t * KD + n * 16 + lmm) * HK + s * 32 + lqq * 8;
            *(bfrag*)&w2x[u * 8] = ldf_frag(p);
        }
        if (tid < 256) {
            int n = tid >> 6, lane = tid & 63;
            const float* p = w1_g + (size_t)(t * HK + n * 16 + (lane & 15)) * BAS
                             + ((lane >> 4) & 3) * 8;
            *(bfrag*)&w1x[tid * 8] = ldf_frag(p);
        } else if (tid < 384) {
            bb2[tid - 256] = b2_g[t * KD + tid - 256];
        } else if (tid < 448) {
            bb1[tid - 384] = b1_g[t * HK + tid - 384];
        }

        // ---- phase A: zst[k][e] = (xs . win^T)^T; also S_all[k] ----
        {
            bfrag wb[4];
#pragma unroll
            for (int ks = 0; ks < 4; ks++)
                wb[ks] = ldf_frag(win_g + (size_t)(t * KD + w * 16 + lm) * ED + ks * 32 + lq * 8);
            f32x4 c[2];
            c[0] = (f32x4){0.f, 0.f, 0.f, 0.f};
            c[1] = (f32x4){0.f, 0.f, 0.f, 0.f};
#pragma unroll
            for (int m = 0; m < 2; m++)
#pragma unroll
                for (int ks = 0; ks < 4; ks++) {
                    bfrag a = *(const bfrag*)&xz[(m * 16 + lm) * AST + ks * 32 + lq * 8];
                    c[m] = MFMA(a, wb[ks], c[m]);
                }
            // transposed pack: lane owns k=w*16+lm, rows m*16+lq*4..+3 -> b64
            u32x2 dd0, dd1;
            dd0.x = pk2(c[0][0], c[0][1]);
            dd0.y = pk2(c[0][2], c[0][3]);
            dd1.x = pk2(c[1][0], c[1][1]);
            dd1.y = pk2(c[1][2], c[1][3]);
            *(u32x2*)&zst[(w * 16 + lm) * ZJST + lq * 4] = dd0;
            *(u32x2*)&zst[(w * 16 + lm) * ZJST + 16 + lq * 4] = dd1;
            // S_all[k]: sum of the PACKED (rounded) values -> exact match with
            // what the consume step reads; butterfly over quads; + nuc cols.
            float s = __uint_as_float(dd0.x << 16) + __uint_as_float(dd0.x & 0xffff0000u)
                    + __uint_as_float(dd0.y << 16) + __uint_as_float(dd0.y & 0xffff0000u)
                    + __uint_as_float(dd1.x << 16) + __uint_as_float(dd1.x & 0xffff0000u)
                    + __uint_as_float(dd1.y << 16) + __uint_as_float(dd1.y & 0xffff0000u);
            s += __shfl_xor(s, 16, 64);
            s += __shfl_xor(s, 32, 64);
            u32x2 nd = *(const u32x2*)&zst[(w * 16 + lm) * ZJST + 32]; // nuc, init-stable
            s += __uint_as_float(nd.x << 16) + __uint_as_float(nd.x & 0xffff0000u)
               + __uint_as_float(nd.y << 16) + __uint_as_float(nd.y & 0xffff0000u);
            if (lq == 0) sall[w * 16 + lm] = s;
        }
        __syncthreads();

        // ---- pair loop: wave w owns e = 4w..4w+3 ----
        // tiles: 1 shared nuc tile (rows = 4e x 4j, j=32..35) + per-e 2 tiles
        {
            u32* hbw = arena32 + w * (16 * HB2); // wave-private H^T buffer (u32)
            float4 a0, a1, b0, b1;               // parity double-buffer (db)
            const f32x4 zq = (f32x4){0.f, 0.f, 0.f, 0.f}; // shared GEMM2 C-in

            // tile body: swapped GEMM1 -> ssp -> packed u32 store -> u32x4
            // read (type-consistent) -> GEMM2 -> masked consume.
            // jc = lane's zst column base. kmA/kmC mask r=0,2 (lo16<<16);
            // kmB/kmD pre-ANDed with 0xFFFF0000.
            auto tile_g12 = [&](bfrag ad, int jc, u32 kmA, u32 kmB, u32 kmC,
                                u32 kmD, float* acc) {
                // GEMM1 swapped: D[row=h=lq*4+r (+16n)][col=p=lm]
                f32x4 c1[4];
#pragma unroll
                for (int n = 0; n < 4; n++) {
                    f32x4 ci = *(const f32x4*)&bb1[n * 16 + lq * 4]; // broadcast quad
                    bfrag w1f = *(const bfrag*)&w1x[(n * 64 + l) * 8];
                    c1[n] = MFMA(w1f, ad, ci);
                }
                // ssp + pack h-pairs: hbw[p=lm][pair idx n*8+lq*2 +0/1]
#pragma unroll
                for (int n = 0; n < 4; n++) {
                    u32x2 pp;
                    pp.x = pk2(sspv(c1[n][0]), sspv(c1[n][1]));
                    pp.y = pk2(sspv(c1[n][2]), sspv(c1[n][3]));
                    *(u32x2*)&hbw[lm * HB2 + n * 8 + lq * 2] = pp;
                }
                __builtin_amdgcn_sched_barrier(0); // loads below must not hoist
                // A2-frags: lane lm=p, k=h=s*32+lq*8+j -> u32x4 at pair s*16+lq*4
                union { u32x4 u; bfrag f; } ua, ub;
                ua.u = *(const u32x4*)&hbw[lm * HB2 + lq * 4];
                ub.u = *(const u32x4*)&hbw[lm * HB2 + 16 + lq * 4];
                bfrag a20 = ua.f;
                bfrag a21 = ub.f;
                __builtin_amdgcn_sched_barrier(0);
                // GEMM2 + consume, fenced every 4 n (spill-free regime)
#pragma unroll
                for (int g = 0; g < 2; g++) {
#pragma unroll
                    for (int nn = 0; nn < 4; nn++) {
                        const int n = g * 4 + nn;
                        bfrag wf0 = *(const bfrag*)&w2x[(n * 128 + l) * 8];
                        bfrag wf1 = *(const bfrag*)&w2x[(n * 128 + 64 + l) * 8];
                        f32x4 c2 = MFMA(a20, wf0, zq);
                        c2 = MFMA(a21, wf1, c2);
                        u32x2 zd = *(const u32x2*)&zst[(n * 16 + lm) * ZJST + jc];
                        acc[n] = fmaf(c2[0], __uint_as_float((zd.x << 16) & kmA), acc[n]);
                        acc[n] = fmaf(c2[1], __uint_as_float(zd.x & kmB), acc[n]);
                        acc[n] = fmaf(c2[2], __uint_as_float((zd.y << 16) & kmC), acc[n]);
                        acc[n] = fmaf(c2[3], __uint_as_float(zd.y & kmD), acc[n]);
                    }
                    __builtin_amdgcn_sched_barrier(0);
                }
            };

            // ---- nuc tile: load -> a; prefetch (le0,T0) -> b; znuc -> xz ----
            {
                {
                    int e0 = w * 4 + (lm >> 2), j0 = 32 + (lm & 3);
                    const float* p = db_g + ((size_t)(b * NE + e0) * NA + j0) * BAS + lq * 8;
                    a0 = *(const float4*)p;
                    a1 = *(const float4*)(p + 4);
                }
                {
                    const float* p = db_g + ((size_t)(b * NE + w * 4) * NA + lm) * BAS + lq * 8;
                    b0 = *(const float4*)p;
                    b1 = *(const float4*)(p + 4);
                }
                float znuc[8] = {0.f, 0.f, 0.f, 0.f, 0.f, 0.f, 0.f, 0.f};
                // consume cols 32..35 for ALL quads (row r <-> j=32+r); no diag
                tile_g12(cvt8(a0, a1), 32, ~0u, 0xFFFF0000u, ~0u, 0xFFFF0000u, znuc);
                // lane (lq,lm) holds nuc-sum for e=w*4+lq, k=n*16+lm: park in xz
                int e0 = w * 4 + lq;
#pragma unroll
                for (int n = 0; n < 8; n += 2) {
                    u32 pk = pk2(znuc[n], znuc[n + 1]);
                    xz[e0 * AST + n * 16 + lm] = (u16)pk;
                    xz[e0 * AST + (n + 1) * 16 + lm] = (u16)(pk >> 16);
                }
            }

#pragma unroll 1
            for (int le = 0; le < 4; le++) {
                const int e = w * 4 + le;
                float zreg[8] = {0.f, 0.f, 0.f, 0.f, 0.f, 0.f, 0.f, 0.f};
                // T=0: prefetch (le,T=1) -> a; consume b
                {
                    const float* p = db_g + ((size_t)(b * NE + e) * NA + 16 + lm) * BAS + lq * 8;
                    a0 = *(const float4*)p;
                    a1 = *(const float4*)(p + 4);
                }
                {
                    int lp0 = lq * 4;
                    u32 k0 = (lp0 + 0 == e) ? 0u : ~0u;
                    u32 k1 = (lp0 + 1 == e) ? 0u : ~0u;
                    u32 k2 = (lp0 + 2 == e) ? 0u : ~0u;
                    u32 k3 = (lp0 + 3 == e) ? 0u : ~0u;
                    tile_g12(cvt8(b0, b1), lp0, k0, k1 & 0xFFFF0000u,
                             k2, k3 & 0xFFFF0000u, zreg);
                }
                // T=1: prefetch (le+1,T=0) -> b (clamped dummy at end); consume a
                {
                    int nle = (le < 3) ? le + 1 : 3;
                    const float* p = db_g + ((size_t)(b * NE + w * 4 + nle) * NA + lm) * BAS + lq * 8;
                    b0 = *(const float4*)p;
                    b1 = *(const float4*)(p + 4);
                }
                {
                    int lp0 = 16 + lq * 4;
                    u32 k0 = (lp0 + 0 == e) ? 0u : ~0u;
                    u32 k1 = (lp0 + 1 == e) ? 0u : ~0u;
                    u32 k2 = (lp0 + 2 == e) ? 0u : ~0u;
                    u32 k3 = (lp0 + 3 == e) ? 0u : ~0u;
                    tile_g12(cvt8(a0, a1), lp0, k0, k1 & 0xFFFF0000u,
                             k2, k3 & 0xFFFF0000u, zreg);
                }
                // butterfly over quads; lanes lq==le add parked nuc + bias term
#pragma unroll
                for (int n = 0; n < 8; n++) {
                    float v = zreg[n];
                    v += __shfl_xor(v, 16, 64);
                    v += __shfl_xor(v, 32, 64);
                    zreg[n] = v;
                }
                if (lq == le) {
#pragma unroll
                    for (int n = 0; n < 8; n += 2) {
                        int k0 = n * 16 + lm, k1 = (n + 1) * 16 + lm;
                        float o0 = bf2f(xz[e * AST + k0]);            // parked nuc
                        float o1 = bf2f(xz[e * AST + k1]);
                        float ze0 = bf2f(zst[k0 * ZJST + e]);         // zs[e][k]
                        float ze1 = bf2f(zst[k1 * ZJST + e]);
                        float t0 = zreg[n] + o0 + bb2[k0] * (sall[k0] - ze0);
                        float t1 = zreg[n + 1] + o1 + bb2[k1] * (sall[k1] - ze1);
                        u32 pk = pk2(t0, t1);
                        xz[e * AST + k0] = (u16)pk;
                        xz[e * AST + k1] = (u16)(pk >> 16);
                    }
                }
            }
        }
        __syncthreads();

        // ---- D1: h2 = ssp(z . wo1^T + bo1)  (M=32,N=128,K=128) ----
        {
            bfrag wb[4];
#pragma unroll
            for (int ks = 0; ks < 4; ks++)
                wb[ks] = ldf_frag(wo1_g + (size_t)(t * HO + w * 16 + lm) * KD + ks * 32 + lq * 8);
            float bo1v = bo1_g[t * HO + w * 16 + lm];
            f32x4 c[2];
            c[0] = (f32x4){bo1v, bo1v, bo1v, bo1v};
            c[1] = (f32x4){bo1v, bo1v, bo1v, bo1v};
#pragma unroll
            for (int m = 0; m < 2; m++)
#pragma unroll
                for (int ks = 0; ks < 4; ks++) {
                    bfrag a = *(const bfrag*)&xz[(m * 16 + lm) * AST + ks * 32 + lq * 8];
                    c[m] = MFMA(a, wb[ks], c[m]);
                }
#pragma unroll
            for (int m = 0; m < 2; m++) {
                u32 p01 = pk2(sspv(c[m][0]), sspv(c[m][1]));
                u32 p23 = pk2(sspv(c[m][2]), sspv(c[m][3]));
                h2b[(m * 16 + lq * 4 + 0) * AST + w * 16 + lm] = (u16)p01;
                h2b[(m * 16 + lq * 4 + 1) * AST + w * 16 + lm] = (u16)(p01 >> 16);
                h2b[(m * 16 + lq * 4 + 2) * AST + w * 16 + lm] = (u16)p23;
                h2b[(m * 16 + lq * 4 + 3) * AST + w * 16 + lm] = (u16)(p23 >> 16);
            }
        }
        __syncthreads();

        // ---- D2: xs += h2 . wo2^T + bo2; refresh bf16 mirror xz ----
        {
            bfrag wb[4];
#pragma unroll
            for (int ks = 0; ks < 4; ks++)
                wb[ks] = ldf_frag(wo2_g + (size_t)(t * ED + w * 16 + lm) * HO + ks * 32 + lq * 8);
            float bo2v = bo2_g[t * ED + w * 16 + lm];
            f32x4 c[2];
            c[0] = (f32x4){bo2v, bo2v, bo2v, bo2v};
            c[1] = (f32x4){bo2v, bo2v, bo2v, bo2v};
#pragma unroll
            for (int m = 0; m < 2; m++)
#pragma unroll
                for (int ks = 0; ks < 4; ks++) {
                    bfrag a = *(const bfrag*)&h2b[(m * 16 + lm) * AST + ks * 32 + lq * 8];
                    c[m] = MFMA(a, wb[ks], c[m]);
                }
#pragma unroll
            for (int m = 0; m < 2; m++) {
                float nv[4];
#pragma unroll
                for (int r = 0; r < 4; r++) {
                    int row = m * 16 + lq * 4 + r, col = w * 16 + lm;
                    nv[r] = xs[row * XST + col] + c[m][r];
                    xs[row * XST + col] = nv[r];
                }
                u32 p01 = pk2(nv[0], nv[1]);
                u32 p23 = pk2(nv[2], nv[3]);
                xz[(m * 16 + lq * 4 + 0) * AST + w * 16 + lm] = (u16)p01;
                xz[(m * 16 + lq * 4 + 1) * AST + w * 16 + lm] = (u16)(p01 >> 16);
                xz[(m * 16 + lq * 4 + 2) * AST + w * 16 + lm] = (u16)p23;
                xz[(m * 16 + lq * 4 + 3) * AST + w * 16 + lm] = (u16)(p23 >> 16);
            }
        }
        __syncthreads();
    }

    // ---- write out (f32, coalesced float4) ----
#pragma unroll
    for (int ii = 0; ii < 2; ii++) {
        int idx = (ii * 512 + tid) * 4;
        int row = idx >> 7, col = idx & 127;
        *(float4*)&out_g[(size_t)b * (NE * ED) + idx] = *(const float4*)&xs[row * XST + col];
    }
}

extern "C" void kernel_launch(void* const* d_in, const int* in_sizes, int n_in,
                              void* d_out, int out_size, void* d_ws, size_t ws_size,
                              hipStream_t stream) {
    schnet_mfma<<<NBATCH, 512, 0, stream>>>(
        (const float*)d_in[0], (const float*)d_in[1], (const float*)d_in[2],
        (const float*)d_in[3], (const float*)d_in[4], (const float*)d_in[5],
        (const float*)d_in[6], (const float*)d_in[7], (const float*)d_in[8],
        (const float*)d_in[9], (const float*)d_in[10], (const float*)d_in[11],
        (float*)d_out);
}

// Round 12
// 228.944 us; speedup vs baseline: 5.8705x; 1.0143x over previous
//
#include <hip/hip_runtime.h>
#include <hip/hip_bf16.h>
#include <stdint.h>

#define NBATCH 512
#define NE 32
#define NA 36
#define BAS 32
#define KD 128
#define ED 128
#define HK 64
#define HO 128
#define NT 3

#define AST 136   // xz (zacc/mirror) + h2b stride (u16): 272B rows, 16B-aligned
#define ZJ32 36   // zst32[k][j] inner stride (u32): 144B rows, 16B-aligned b128
#define HB2 44    // hbw stride (u32): 176B rows, 16B-aligned b128

typedef uint16_t u16;
typedef uint32_t u32;
using bfrag = __attribute__((ext_vector_type(8))) short;  // 8 bf16 = 4 VGPRs
using f32x4 = __attribute__((ext_vector_type(4))) float;
using u32x2 = __attribute__((ext_vector_type(2))) unsigned int;
using u32x4 = __attribute__((ext_vector_type(4))) unsigned int;

#define MFMA(a, b, c) __builtin_amdgcn_mfma_f32_16x16x32_bf16(a, b, c, 0, 0, 0)

// f32 -> bf16 RNE via the compiler's cast path (m240: the fast path).
// NO inline asm anywhere (R4's hand-written cvt_pk asm silently corrupted).
__device__ __forceinline__ short ftob(float f) {
    union { __hip_bfloat16 h; short s; } u;
    u.h = __float2bfloat16(f);
    return u.s;
}
// pack two f32 -> (bf16 hi)<<16 | bf16 lo
__device__ __forceinline__ u32 pk2(float lo, float hi) {
    return ((u32)(u16)ftob(hi) << 16) | (u32)(u16)ftob(lo);
}
// f32 -> "bf16 as f32 bits": hi16 = bf16, lo16 = 0 (directly as_float-able)
__device__ __forceinline__ u32 fb32(float f) {
    return ((u32)(u16)ftob(f)) << 16;
}
__device__ __forceinline__ float bf2f(u16 u) {
    return __uint_as_float(((u32)u) << 16);
}
__device__ __forceinline__ bfrag cvt8(float4 a, float4 c) {
    bfrag r;
    r[0] = ftob(a.x); r[1] = ftob(a.y); r[2] = ftob(a.z); r[3] = ftob(a.w);
    r[4] = ftob(c.x); r[5] = ftob(c.y); r[6] = ftob(c.z); r[7] = ftob(c.w);
    return r;
}
__device__ __forceinline__ bfrag ldf_frag(const float* p) {
    float4 a = *(const float4*)p;
    float4 c = *(const float4*)(p + 4);
    return cvt8(a, c);
}
// softplus(x) - log(2) = log((1+e^x)/2), 5 VALU ops.
__device__ __forceinline__ float sspv(float x) {
    return __logf(fmaf(__expf(x), 0.5f, 0.5f));
}

// One block per batch element; 512 threads = 8 waves.
// Frag conventions (guide §3, m89/m91-verified):
//   A: lane&15 = m, (lane>>4)*8+j = k   |  B: lane&15 = n, (lane>>4)*8+j = k
//   C/D: col = lane&15 (n), row = (lane>>4)*4 + reg (m)
//
// Structure: zs TRANSPOSED zst32[k][j] stored as u32 (bf16 in hi16, lo16=0:
// values are directly __uint_as_float-able). Consume = one b128 read per n;
// bit-ops ONLY in the diagonal-bearing tile (wave-uniform dg branch, 4 ANDs).
// Nuc contribution = ONE shared 16-row tile per wave -> 9 tiles/wave.
// Bias-sum trick: GEMM2 bias = b2*(S_all - zs[e]) in le-epilogue.
// Swapped GEMM1 (R11, replay-stable): type-consistent u32 hbw transpose.
//
// R12: (a) zst u16 -> pre-shifted u32 (kills 6 bit-ops/n/tile in consume +
// 8 unpacks in S_all + 4 in epilogue; bit-identical numerics); (b) xs f32
// residual LDS -> 8 per-thread registers xr[] (lane owns exactly its D2
// C-fragment elements); deletes the 16.9 KB xs array + 16 LDS ops/lane/t.
// LDS 79.4 -> ~70 KB (2 blocks/CU held). Guard: WRITE_SIZE <= ~16 MB.
__global__ __launch_bounds__(512, 4) void schnet_mfma(
    const float* __restrict__ db_g,   // dists_basis (512,32,36,32)
    const float* __restrict__ ee_g,   // embedding_elec (32,128)
    const float* __restrict__ en_g,   // embedding_nuc (4,128)
    const float* __restrict__ w1_g,   // kernel_w1 (3,64,32)
    const float* __restrict__ b1_g,   // kernel_b1 (3,64)
    const float* __restrict__ w2_g,   // kernel_w2 (3,128,64)
    const float* __restrict__ b2_g,   // kernel_b2 (3,128)
    const float* __restrict__ win_g,  // embed_in_w (3,128,128)
    const float* __restrict__ wo1_g,  // embed_out_w1 (3,128,128)
    const float* __restrict__ bo1_g,  // embed_out_b1 (3,128)
    const float* __restrict__ wo2_g,  // embed_out_w2 (3,128,128)
    const float* __restrict__ bo2_g,  // embed_out_b2 (3,128)
    float* __restrict__ out_g)        // (512,32,128) f32
{
    __shared__ __align__(16) u16 xz[NE * AST];          // zacc | bf16 mirror (8.7 KB)
    __shared__ __align__(16) u32 zst32[KD * ZJ32];      // zs^T, u32 hi16 (18.4 KB)
    __shared__ __align__(16) u32 arena32[8 * 16 * HB2]; // hbw | h2b (22.5 KB)
    __shared__ __align__(16) u16 w2x[8 * 2 * 64 * 8];   // w2 frag-linear (16 KB)
    __shared__ __align__(16) u16 w1x[4 * 64 * 8];       // w1 frag-linear (4 KB)
    __shared__ __align__(16) float bb2[KD];             // b2 bias (512 B)
    __shared__ __align__(16) float sall[KD];            // S_all[k] (512 B)
    __shared__ __align__(16) float bb1[HK];             // b1 bias (256 B)
    u16* h2b = (u16*)arena32;                           // 32*AST*2 = 8.7KB <= arena
    // total LDS ~71.4 KB -> 2 blocks/CU

    const int tid = threadIdx.x;
    const int b = blockIdx.x;
    const int w = tid >> 6;   // wave 0..7
    const int l = tid & 63;
    const int lm = l & 15;    // m/n lane index
    const int lq = l >> 4;    // quad 0..3

    // ---- xs residual in REGISTERS: xr[m*4+r] = xs[m*16+lq*4+r][w*16+lm] ----
    float xr[8];
#pragma unroll
    for (int m = 0; m < 2; m++)
#pragma unroll
        for (int r = 0; r < 4; r++)
            xr[m * 4 + r] = ee_g[(m * 16 + lq * 4 + r) * ED + w * 16 + lm];

    // ---- init: xz <- embedding_elec (bf16); zst32 nuc cols <- embedding_nuc ----
    {
        int idx = tid * 8;
        float4 v0 = *(const float4*)(ee_g + idx);
        float4 v1 = *(const float4*)(ee_g + idx + 4);
        int row = idx >> 7, col = idx & 127;
        *(bfrag*)&xz[row * AST + col] = cvt8(v0, v1);
    }
    {
        int k = tid & 127, rr = tid >> 7;  // 512 threads = 128k x 4rr
        zst32[k * ZJ32 + 32 + rr] = fb32(en_g[rr * 128 + k]);
    }
    __syncthreads();

    for (int t = 0; t < NT; t++) {
        // ---- stage w2 + w1 + b2 + b1 -> LDS (consumed after next barrier) ----
#pragma unroll
        for (int uu = 0; uu < 2; uu++) {
            int u = tid + uu * 512;
            int n = u >> 7, s = (u >> 6) & 1, lane = u & 63;
            int lmm = lane & 15, lqq = lane >> 4;
            const float* p = w2_g + (size_t)(t * KD + n * 16 + lmm) * HK + s * 32 + lqq * 8;
            *(bfrag*)&w2x[u * 8] = ldf_frag(p);
        }
        if (tid < 256) {
            int n = tid >> 6, lane = tid & 63;
            const float* p = w1_g + (size_t)(t * HK + n * 16 + (lane & 15)) * BAS
                             + ((lane >> 4) & 3) * 8;
            *(bfrag*)&w1x[tid * 8] = ldf_frag(p);
        } else if (tid < 384) {
            bb2[tid - 256] = b2_g[t * KD + tid - 256];
        } else if (tid < 448) {
            bb1[tid - 384] = b1_g[t * HK + tid - 384];
        }

        // ---- phase A: zst32[k][e] = (xz . win^T)^T; also S_all[k] ----
        {
            bfrag wb[4];
#pragma unroll
            for (int ks = 0; ks < 4; ks++)
                wb[ks] = ldf_frag(win_g + (size_t)(t * KD + w * 16 + lm) * ED + ks * 32 + lq * 8);
            f32x4 c[2];
            c[0] = (f32x4){0.f, 0.f, 0.f, 0.f};
            c[1] = (f32x4){0.f, 0.f, 0.f, 0.f};
#pragma unroll
            for (int m = 0; m < 2; m++)
#pragma unroll
                for (int ks = 0; ks < 4; ks++) {
                    bfrag a = *(const bfrag*)&xz[(m * 16 + lm) * AST + ks * 32 + lq * 8];
                    c[m] = MFMA(a, wb[ks], c[m]);
                }
            // transposed pack: lane owns k=w*16+lm, rows m*16+lq*4..+3 -> b128
            u32x4 q0, q1;
            q0[0] = fb32(c[0][0]); q0[1] = fb32(c[0][1]);
            q0[2] = fb32(c[0][2]); q0[3] = fb32(c[0][3]);
            q1[0] = fb32(c[1][0]); q1[1] = fb32(c[1][1]);
            q1[2] = fb32(c[1][2]); q1[3] = fb32(c[1][3]);
            *(u32x4*)&zst32[(w * 16 + lm) * ZJ32 + lq * 4] = q0;
            *(u32x4*)&zst32[(w * 16 + lm) * ZJ32 + 16 + lq * 4] = q1;
            // S_all[k]: sum of the PACKED (rounded) values (same order as the
            // consume reads); butterfly over quads; + nuc cols (init-stable).
            float s = __uint_as_float(q0[0]) + __uint_as_float(q0[1])
                    + __uint_as_float(q0[2]) + __uint_as_float(q0[3])
                    + __uint_as_float(q1[0]) + __uint_as_float(q1[1])
                    + __uint_as_float(q1[2]) + __uint_as_float(q1[3]);
            s += __shfl_xor(s, 16, 64);
            s += __shfl_xor(s, 32, 64);
            u32x4 nd = *(const u32x4*)&zst32[(w * 16 + lm) * ZJ32 + 32];
            s += __uint_as_float(nd[0]) + __uint_as_float(nd[1])
               + __uint_as_float(nd[2]) + __uint_as_float(nd[3]);
            if (lq == 0) sall[w * 16 + lm] = s;
        }
        __syncthreads();

        // ---- pair loop: wave w owns e = 4w..4w+3 ----
        // tiles: 1 shared nuc tile (rows = 4e x 4j, j=32..35) + per-e 2 tiles
        {
            u32* hbw = arena32 + w * (16 * HB2); // wave-private H^T buffer (u32)
            float4 a0, a1, b0, b1;               // parity double-buffer (db)
            const f32x4 zq = (f32x4){0.f, 0.f, 0.f, 0.f}; // shared GEMM2 C-in

            // tile body: swapped GEMM1 -> ssp -> u32 pack store -> u32x4 read
            // (type-consistent) -> GEMM2 -> consume. dg (wave-uniform): this
            // tile contains row j==e -> apply full-word AND masks m0..m3.
            auto tile_g12 = [&](bfrag ad, int jc, bool dg, u32 m0, u32 m1,
                                u32 m2, u32 m3, float* acc) {
                // GEMM1 swapped: D[row=h=lq*4+r (+16n)][col=p=lm]
                f32x4 c1[4];
#pragma unroll
                for (int n = 0; n < 4; n++) {
                    f32x4 ci = *(const f32x4*)&bb1[n * 16 + lq * 4]; // broadcast quad
                    bfrag w1f = *(const bfrag*)&w1x[(n * 64 + l) * 8];
                    c1[n] = MFMA(w1f, ad, ci);
                }
                // ssp + pack h-pairs: hbw[p=lm][pair idx n*8+lq*2 +0/1]
#pragma unroll
                for (int n = 0; n < 4; n++) {
                    u32x2 pp;
                    pp.x = pk2(sspv(c1[n][0]), sspv(c1[n][1]));
                    pp.y = pk2(sspv(c1[n][2]), sspv(c1[n][3]));
                    *(u32x2*)&hbw[lm * HB2 + n * 8 + lq * 2] = pp;
                }
                __builtin_amdgcn_sched_barrier(0); // loads below must not hoist
                // A2-frags: lane lm=p, k=h=s*32+lq*8+j -> u32x4 at pair s*16+lq*4
                union { u32x4 u; bfrag f; } ua, ub;
                ua.u = *(const u32x4*)&hbw[lm * HB2 + lq * 4];
                ub.u = *(const u32x4*)&hbw[lm * HB2 + 16 + lq * 4];
                bfrag a20 = ua.f;
                bfrag a21 = ub.f;
                __builtin_amdgcn_sched_barrier(0);
                // GEMM2 + consume, fenced every 4 n (spill-free regime)
#pragma unroll
                for (int g = 0; g < 2; g++) {
#pragma unroll
                    for (int nn = 0; nn < 4; nn++) {
                        const int n = g * 4 + nn;
                        bfrag wf0 = *(const bfrag*)&w2x[(n * 128 + l) * 8];
                        bfrag wf1 = *(const bfrag*)&w2x[(n * 128 + 64 + l) * 8];
                        f32x4 c2 = MFMA(a20, wf0, zq);
                        c2 = MFMA(a21, wf1, c2);
                        u32x4 zd = *(const u32x4*)&zst32[(n * 16 + lm) * ZJ32 + jc];
                        if (dg) {   // wave-uniform branch: diagonal tile only
                            acc[n] = fmaf(c2[0], __uint_as_float(zd[0] & m0), acc[n]);
                            acc[n] = fmaf(c2[1], __uint_as_float(zd[1] & m1), acc[n]);
                            acc[n] = fmaf(c2[2], __uint_as_float(zd[2] & m2), acc[n]);
                            acc[n] = fmaf(c2[3], __uint_as_float(zd[3] & m3), acc[n]);
                        } else {
                            acc[n] = fmaf(c2[0], __uint_as_float(zd[0]), acc[n]);
                            acc[n] = fmaf(c2[1], __uint_as_float(zd[1]), acc[n]);
                            acc[n] = fmaf(c2[2], __uint_as_float(zd[2]), acc[n]);
                            acc[n] = fmaf(c2[3], __uint_as_float(zd[3]), acc[n]);
                        }
                    }
                    __builtin_amdgcn_sched_barrier(0);
                }
            };

            // ---- nuc tile: load -> a; prefetch (le0,T0) -> b; znuc -> xz ----
            {
                {
                    int e0 = w * 4 + (lm >> 2), j0 = 32 + (lm & 3);
                    const float* p = db_g + ((size_t)(b * NE + e0) * NA + j0) * BAS + lq * 8;
                    a0 = *(const float4*)p;
                    a1 = *(const float4*)(p + 4);
                }
                {
                    const float* p = db_g + ((size_t)(b * NE + w * 4) * NA + lm) * BAS + lq * 8;
                    b0 = *(const float4*)p;
                    b1 = *(const float4*)(p + 4);
                }
                float znuc[8] = {0.f, 0.f, 0.f, 0.f, 0.f, 0.f, 0.f, 0.f};
                // consume cols 32..35 for ALL quads (row r <-> j=32+r); no diag
                tile_g12(cvt8(a0, a1), 32, false, 0u, 0u, 0u, 0u, znuc);
                // lane (lq,lm) holds nuc-sum for e=w*4+lq, k=n*16+lm: park in xz
                int e0 = w * 4 + lq;
#pragma unroll
                for (int n = 0; n < 8; n += 2) {
                    u32 pk = pk2(znuc[n], znuc[n + 1]);
                    xz[e0 * AST + n * 16 + lm] = (u16)pk;
                    xz[e0 * AST + (n + 1) * 16 + lm] = (u16)(pk >> 16);
                }
            }

#pragma unroll 1
            for (int le = 0; le < 4; le++) {
                const int e = w * 4 + le;
                float zreg[8] = {0.f, 0.f, 0.f, 0.f, 0.f, 0.f, 0.f, 0.f};
                // T=0: prefetch (le,T=1) -> a; consume b
                {
                    const float* p = db_g + ((size_t)(b * NE + e) * NA + 16 + lm) * BAS + lq * 8;
                    a0 = *(const float4*)p;
                    a1 = *(const float4*)(p + 4);
                }
                {
                    int lp0 = lq * 4;
                    u32 m0 = (lp0 + 0 == e) ? 0u : ~0u;
                    u32 m1 = (lp0 + 1 == e) ? 0u : ~0u;
                    u32 m2 = (lp0 + 2 == e) ? 0u : ~0u;
                    u32 m3 = (lp0 + 3 == e) ? 0u : ~0u;
                    tile_g12(cvt8(b0, b1), lp0, e < 16, m0, m1, m2, m3, zreg);
                }
                // T=1: prefetch (le+1,T=0) -> b (clamped dummy at end); consume a
                {
                    int nle = (le < 3) ? le + 1 : 3;
                    const float* p = db_g + ((size_t)(b * NE + w * 4 + nle) * NA + lm) * BAS + lq * 8;
                    b0 = *(const float4*)p;
                    b1 = *(const float4*)(p + 4);
                }
                {
                    int lp0 = 16 + lq * 4;
                    u32 m0 = (lp0 + 0 == e) ? 0u : ~0u;
                    u32 m1 = (lp0 + 1 == e) ? 0u : ~0u;
                    u32 m2 = (lp0 + 2 == e) ? 0u : ~0u;
                    u32 m3 = (lp0 + 3 == e) ? 0u : ~0u;
                    tile_g12(cvt8(a0, a1), lp0, e >= 16, m0, m1, m2, m3, zreg);
                }
                // butterfly over quads; lanes lq==le add parked nuc + bias term
#pragma unroll
                for (int n = 0; n < 8; n++) {
                    float v = zreg[n];
                    v += __shfl_xor(v, 16, 64);
                    v += __shfl_xor(v, 32, 64);
                    zreg[n] = v;
                }
                if (lq == le) {
#pragma unroll
                    for (int n = 0; n < 8; n += 2) {
                        int k0 = n * 16 + lm, k1 = (n + 1) * 16 + lm;
                        float o0 = bf2f(xz[e * AST + k0]);            // parked nuc
                        float o1 = bf2f(xz[e * AST + k1]);
                        float ze0 = __uint_as_float(zst32[k0 * ZJ32 + e]);
                        float ze1 = __uint_as_float(zst32[k1 * ZJ32 + e]);
                        float t0 = zreg[n] + o0 + bb2[k0] * (sall[k0] - ze0);
                        float t1 = zreg[n + 1] + o1 + bb2[k1] * (sall[k1] - ze1);
                        u32 pk = pk2(t0, t1);
                        xz[e * AST + k0] = (u16)pk;
                        xz[e * AST + k1] = (u16)(pk >> 16);
                    }
                }
            }
        }
        __syncthreads();

        // ---- D1: h2 = ssp(z . wo1^T + bo1)  (M=32,N=128,K=128) ----
        {
            bfrag wb[4];
#pragma unroll
            for (int ks = 0; ks < 4; ks++)
                wb[ks] = ldf_frag(wo1_g + (size_t)(t * HO + w * 16 + lm) * KD + ks * 32 + lq * 8);
            float bo1v = bo1_g[t * HO + w * 16 + lm];
            f32x4 c[2];
            c[0] = (f32x4){bo1v, bo1v, bo1v, bo1v};
            c[1] = (f32x4){bo1v, bo1v, bo1v, bo1v};
#pragma unroll
            for (int m = 0; m < 2; m++)
#pragma unroll
                for (int ks = 0; ks < 4; ks++) {
                    bfrag a = *(const bfrag*)&xz[(m * 16 + lm) * AST + ks * 32 + lq * 8];
                    c[m] = MFMA(a, wb[ks], c[m]);
                }
#pragma unroll
            for (int m = 0; m < 2; m++) {
                u32 p01 = pk2(sspv(c[m][0]), sspv(c[m][1]));
                u32 p23 = pk2(sspv(c[m][2]), sspv(c[m][3]));
                h2b[(m * 16 + lq * 4 + 0) * AST + w * 16 + lm] = (u16)p01;
                h2b[(m * 16 + lq * 4 + 1) * AST + w * 16 + lm] = (u16)(p01 >> 16);
                h2b[(m * 16 + lq * 4 + 2) * AST + w * 16 + lm] = (u16)p23;
                h2b[(m * 16 + lq * 4 + 3) * AST + w * 16 + lm] = (u16)(p23 >> 16);
            }
        }
        __syncthreads();

        // ---- D2: xr += h2 . wo2^T + bo2 (registers); refresh bf16 mirror xz ----
        {
            bfrag wb[4];
#pragma unroll
            for (int ks = 0; ks < 4; ks++)
                wb[ks] = ldf_frag(wo2_g + (size_t)(t * ED + w * 16 + lm) * HO + ks * 32 + lq * 8);
            float bo2v = bo2_g[t * ED + w * 16 + lm];
            f32x4 c[2];
            c[0] = (f32x4){bo2v, bo2v, bo2v, bo2v};
            c[1] = (f32x4){bo2v, bo2v, bo2v, bo2v};
#pragma unroll
            for (int m = 0; m < 2; m++)
#pragma unroll
                for (int ks = 0; ks < 4; ks++) {
                    bfrag a = *(const bfrag*)&h2b[(m * 16 + lm) * AST + ks * 32 + lq * 8];
                    c[m] = MFMA(a, wb[ks], c[m]);
                }
#pragma unroll
            for (int m = 0; m < 2; m++) {
#pragma unroll
                for (int r = 0; r < 4; r++)
                    xr[m * 4 + r] += c[m][r];
                u32 p01 = pk2(xr[m * 4 + 0], xr[m * 4 + 1]);
                u32 p23 = pk2(xr[m * 4 + 2], xr[m * 4 + 3]);
                xz[(m * 16 + lq * 4 + 0) * AST + w * 16 + lm] = (u16)p01;
                xz[(m * 16 + lq * 4 + 1) * AST + w * 16 + lm] = (u16)(p01 >> 16);
                xz[(m * 16 + lq * 4 + 2) * AST + w * 16 + lm] = (u16)p23;
                xz[(m * 16 + lq * 4 + 3) * AST + w * 16 + lm] = (u16)(p23 >> 16);
            }
        }
        __syncthreads();
    }

    // ---- write out from registers (16-lane 64B segments, one-time) ----
#pragma unroll
    for (int m = 0; m < 2; m++)
#pragma unroll
        for (int r = 0; r < 4; r++)
            out_g[(size_t)b * (NE * ED) + (m * 16 + lq * 4 + r) * ED + w * 16 + lm] =
                xr[m * 4 + r];
}

extern "C" void kernel_launch(void* const* d_in, const int* in_sizes, int n_in,
                              void* d_out, int out_size, void* d_ws, size_t ws_size,
                              hipStream_t stream) {
    schnet_mfma<<<NBATCH, 512, 0, stream>>>(
        (const float*)d_in[0], (const float*)d_in[1], (const float*)d_in[2],
        (const float*)d_in[3], (const float*)d_in[4], (const float*)d_in[5],
        (const float*)d_in[6], (const float*)d_in[7], (const float*)d_in[8],
        (const float*)d_in[9], (const float*)d_in[10], (const float*)d_in[11],
        (float*)d_out);
}